// Round 1
// baseline (5421.129 us; speedup 1.0000x reference)
//
#include <hip/hip_runtime.h>
#include <math.h>

#define NN     4096
#define NE     32768
#define NCAND  64
#define IND    128
#define HDM    256
#define NHEAD  4
#define HD     64
#define NL     2
#define MAXDEG 96

__device__ __forceinline__ float sigf(float x) { return 1.0f / (1.0f + __expf(-x)); }
__device__ __forceinline__ float tanh_fast(float x) {
  float e = __expf(-2.0f * fabsf(x));
  float r = (1.0f - e) / (1.0f + e);
  return x < 0.0f ? -r : r;
}

// ---------------- build per-dst ordered edge lists ----------------
__global__ __launch_bounds__(256) void build_lists(const int* __restrict__ edges,
                                                   int* __restrict__ cnt,
                                                   int* __restrict__ lists) {
  const int n = blockIdx.x * 256 + threadIdx.x;
  __shared__ int dst[1024];
  int c = 0;
  for (int base = 0; base < NE; base += 1024) {
    __syncthreads();
#pragma unroll
    for (int j = 0; j < 4; j++)
      dst[threadIdx.x + 256 * j] = edges[2 * (base + threadIdx.x + 256 * j) + 1];
    __syncthreads();
    for (int j = 0; j < 1024; j++) {
      if (dst[j] == n) {
        if (c < MAXDEG) lists[n * MAXDEG + c] = base + j;
        c++;
      }
    }
  }
  cnt[n] = c < MAXDEG ? c : MAXDEG;
}

// ---------------- GRU chains: 4 nodes per block, 256 threads ----------------
// thread t computes output element t (rows t, t+256, t+512 of the 3H gates)
__global__ __launch_bounds__(256) void gru_quad(
    const float* __restrict__ nf, const int* __restrict__ edges,
    const int* __restrict__ cnt, const int* __restrict__ lists,
    const float* __restrict__ w_ih, const float* __restrict__ w_hh,
    const float* __restrict__ b_ih, const float* __restrict__ b_hh,
    float* __restrict__ mem) {
  const int t = threadIdx.x;
  const int nb = blockIdx.x * 4;
  __shared__ float hs[4][HDM];
  __shared__ float xs[4][IND];
#pragma unroll
  for (int u = 0; u < 4; u++) hs[u][t] = 0.0f;
  int c[4];
  int cm = 0;
#pragma unroll
  for (int u = 0; u < 4; u++) {
    c[u] = cnt[nb + u];
    cm = c[u] > cm ? c[u] : cm;
  }
  const float bi0 = b_ih[t], bi1 = b_ih[t + 256], bi2 = b_ih[t + 512];
  const float bh0 = b_hh[t], bh1 = b_hh[t + 256], bh2 = b_hh[t + 512];
  const float4* wi0 = (const float4*)(w_ih + (size_t)t * IND);
  const float4* wi1 = (const float4*)(w_ih + (size_t)(t + 256) * IND);
  const float4* wi2 = (const float4*)(w_ih + (size_t)(t + 512) * IND);
  const float4* wh0 = (const float4*)(w_hh + (size_t)t * HDM);
  const float4* wh1 = (const float4*)(w_hh + (size_t)(t + 256) * HDM);
  const float4* wh2 = (const float4*)(w_hh + (size_t)(t + 512) * HDM);

  for (int s = 0; s < cm; s++) {
    __syncthreads();
    if (t < IND) {
#pragma unroll
      for (int u = 0; u < 4; u++) {
        if (s < c[u]) {
          const int e = lists[(nb + u) * MAXDEG + s];
          const int src = edges[2 * e];
          xs[u][t] = nf[(size_t)src * IND + t];
        }
      }
    }
    __syncthreads();
    float gi0[4], gi1[4], gi2[4], gh0[4], gh1[4], gh2[4];
#pragma unroll
    for (int u = 0; u < 4; u++) {
      gi0[u] = bi0; gi1[u] = bi1; gi2[u] = bi2;
      gh0[u] = bh0; gh1[u] = bh1; gh2[u] = bh2;
    }
    for (int k = 0; k < IND / 4; k++) {
      const float4 a = wi0[k], b = wi1[k], d = wi2[k];
#pragma unroll
      for (int u = 0; u < 4; u++) {
        const float4 x4 = ((const float4*)xs[u])[k];
        gi0[u] += a.x * x4.x + a.y * x4.y + a.z * x4.z + a.w * x4.w;
        gi1[u] += b.x * x4.x + b.y * x4.y + b.z * x4.z + b.w * x4.w;
        gi2[u] += d.x * x4.x + d.y * x4.y + d.z * x4.z + d.w * x4.w;
      }
    }
    for (int k = 0; k < HDM / 4; k++) {
      const float4 a = wh0[k], b = wh1[k], d = wh2[k];
#pragma unroll
      for (int u = 0; u < 4; u++) {
        const float4 h4 = ((const float4*)hs[u])[k];
        gh0[u] += a.x * h4.x + a.y * h4.y + a.z * h4.z + a.w * h4.w;
        gh1[u] += b.x * h4.x + b.y * h4.y + b.z * h4.z + b.w * h4.w;
        gh2[u] += d.x * h4.x + d.y * h4.y + d.z * h4.z + d.w * h4.w;
      }
    }
    float hnew[4];
#pragma unroll
    for (int u = 0; u < 4; u++) {
      const float r = sigf(gi0[u] + gh0[u]);
      const float z = sigf(gi1[u] + gh1[u]);
      const float nn2 = tanh_fast(gi2[u] + r * gh2[u]);
      hnew[u] = (1.0f - z) * nn2 + z * hs[u][t];
    }
    __syncthreads();
#pragma unroll
    for (int u = 0; u < 4; u++)
      if (s < c[u]) hs[u][t] = hnew[u];
  }
  __syncthreads();
#pragma unroll
  for (int u = 0; u < 4; u++) mem[(size_t)(nb + u) * HDM + t] = hs[u][t];
}

// ---------------- generic fp32 GEMM: C[M,NCo] = act(A[M,K] @ W[NCo,K]^T + bias)
// 64x64 tile, 256 threads, 4x4 per thread. M%64==0 (or M==64), NCo%64==0, K%16==0.
template <int ACT>
__global__ __launch_bounds__(256) void gemm_bias(const float* __restrict__ A,
                                                 const float* __restrict__ W,
                                                 const float* __restrict__ bias,
                                                 float* __restrict__ C, int M, int NCo, int K) {
  __shared__ float As[16][65];
  __shared__ float Ws[16][65];
  const int bm = blockIdx.y * 64, bn = blockIdx.x * 64;
  const int tid = threadIdx.x;
  const int tx = tid & 15, ty = tid >> 4;
  const int lr = tid >> 2;
  const int lk = (tid & 3) * 4;
  float acc[4][4] = {{0.0f}};
  for (int k0 = 0; k0 < K; k0 += 16) {
    __syncthreads();
    {
      const float4 a4 = *(const float4*)(A + (size_t)(bm + lr) * K + k0 + lk);
      As[lk + 0][lr] = a4.x; As[lk + 1][lr] = a4.y; As[lk + 2][lr] = a4.z; As[lk + 3][lr] = a4.w;
      const float4 w4 = *(const float4*)(W + (size_t)(bn + lr) * K + k0 + lk);
      Ws[lk + 0][lr] = w4.x; Ws[lk + 1][lr] = w4.y; Ws[lk + 2][lr] = w4.z; Ws[lk + 3][lr] = w4.w;
    }
    __syncthreads();
#pragma unroll
    for (int k = 0; k < 16; k++) {
      const float a0 = As[k][ty * 4 + 0], a1 = As[k][ty * 4 + 1];
      const float a2 = As[k][ty * 4 + 2], a3 = As[k][ty * 4 + 3];
      const float w0 = Ws[k][tx * 4 + 0], w1 = Ws[k][tx * 4 + 1];
      const float w2 = Ws[k][tx * 4 + 2], w3 = Ws[k][tx * 4 + 3];
      acc[0][0] += a0 * w0; acc[0][1] += a0 * w1; acc[0][2] += a0 * w2; acc[0][3] += a0 * w3;
      acc[1][0] += a1 * w0; acc[1][1] += a1 * w1; acc[1][2] += a1 * w2; acc[1][3] += a1 * w3;
      acc[2][0] += a2 * w0; acc[2][1] += a2 * w1; acc[2][2] += a2 * w2; acc[2][3] += a2 * w3;
      acc[3][0] += a3 * w0; acc[3][1] += a3 * w1; acc[3][2] += a3 * w2; acc[3][3] += a3 * w3;
    }
  }
  const float b0 = bias[bn + tx * 4 + 0], b1 = bias[bn + tx * 4 + 1];
  const float b2 = bias[bn + tx * 4 + 2], b3 = bias[bn + tx * 4 + 3];
#pragma unroll
  for (int i = 0; i < 4; i++) {
    float4 o;
    o.x = acc[i][0] + b0; o.y = acc[i][1] + b1; o.z = acc[i][2] + b2; o.w = acc[i][3] + b3;
    if (ACT == 1) {
      o.x = fmaxf(o.x, 0.0f); o.y = fmaxf(o.y, 0.0f);
      o.z = fmaxf(o.z, 0.0f); o.w = fmaxf(o.w, 0.0f);
    }
    *(float4*)(C + (size_t)(bm + ty * 4 + i) * NCo + bn + tx * 4) = o;
  }
}

// ---------------- flash attention, fp32; qkv[N,768], out[N,256] ----------------
// grid: (64 qblocks, 4 heads); 256 threads; thread = (row tq 0..63, slot ts 0..3)
__global__ __launch_bounds__(256) void flash_attn(const float* __restrict__ qkv,
                                                  float* __restrict__ out) {
  const int h = blockIdx.y;
  const int qb = blockIdx.x * 64;
  const int tid = threadIdx.x;
  const int tq = tid >> 2, ts = tid & 3;
  __shared__ float Ks[64][68];
  __shared__ float Vs[64][68];
  __shared__ float Ps[64][68];

  float q[64];
  {
    const float4* qp = (const float4*)(qkv + (size_t)(qb + tq) * 768 + h * 64);
#pragma unroll
    for (int u = 0; u < 16; u++) {
      const float4 v = qp[u];
      q[4 * u + 0] = v.x; q[4 * u + 1] = v.y; q[4 * u + 2] = v.z; q[4 * u + 3] = v.w;
    }
  }
  float m_run = -1e30f, l_run = 0.0f;
  float acc[16];
#pragma unroll
  for (int j = 0; j < 16; j++) acc[j] = 0.0f;

  for (int kb = 0; kb < 64; kb++) {
    __syncthreads();
    {
      const int r = tid >> 2;
      const int c4 = (tid & 3) * 16;
      const float4* kp = (const float4*)(qkv + (size_t)(kb * 64 + r) * 768 + 256 + h * 64 + c4);
      const float4* vp = (const float4*)(qkv + (size_t)(kb * 64 + r) * 768 + 512 + h * 64 + c4);
#pragma unroll
      for (int u = 0; u < 4; u++) {
        const float4 kv = kp[u];
        Ks[r][c4 + 4 * u + 0] = kv.x; Ks[r][c4 + 4 * u + 1] = kv.y;
        Ks[r][c4 + 4 * u + 2] = kv.z; Ks[r][c4 + 4 * u + 3] = kv.w;
        const float4 vv = vp[u];
        Vs[r][c4 + 4 * u + 0] = vv.x; Vs[r][c4 + 4 * u + 1] = vv.y;
        Vs[r][c4 + 4 * u + 2] = vv.z; Vs[r][c4 + 4 * u + 3] = vv.w;
      }
    }
    __syncthreads();
    // scores for 16 keys (staggered: kk = ts + 4i → conflict-free b128 reads)
    float s[16];
#pragma unroll
    for (int i = 0; i < 16; i++) {
      const int kk = ts + 4 * i;
      const float4* krow = (const float4*)(&Ks[kk][0]);
      float a0 = 0.0f, a1 = 0.0f, a2 = 0.0f, a3 = 0.0f;
#pragma unroll
      for (int u = 0; u < 16; u++) {
        const float4 k4 = krow[u];
        a0 += q[4 * u + 0] * k4.x; a1 += q[4 * u + 1] * k4.y;
        a2 += q[4 * u + 2] * k4.z; a3 += q[4 * u + 3] * k4.w;
      }
      s[i] = 0.125f * ((a0 + a1) + (a2 + a3));
    }
    float mb = s[0];
#pragma unroll
    for (int i = 1; i < 16; i++) mb = fmaxf(mb, s[i]);
    mb = fmaxf(mb, __shfl_xor(mb, 1));
    mb = fmaxf(mb, __shfl_xor(mb, 2));
    const float m_new = fmaxf(m_run, mb);
    const float alpha = __expf(m_run - m_new);
    float psum = 0.0f;
#pragma unroll
    for (int i = 0; i < 16; i++) {
      const float p = __expf(s[i] - m_new);
      Ps[tq][ts + 4 * i] = p;
      psum += p;
    }
    psum += __shfl_xor(psum, 1);
    psum += __shfl_xor(psum, 2);
    l_run = l_run * alpha + psum;
    m_run = m_new;
    __syncthreads();
#pragma unroll
    for (int j = 0; j < 16; j++) acc[j] *= alpha;
    for (int k = 0; k < 64; k++) {
      const float p = Ps[tq][k];
      const float4* vrow = (const float4*)(&Vs[k][ts * 16]);
#pragma unroll
      for (int j2 = 0; j2 < 4; j2++) {
        const float4 v4 = vrow[j2];
        acc[4 * j2 + 0] += p * v4.x; acc[4 * j2 + 1] += p * v4.y;
        acc[4 * j2 + 2] += p * v4.z; acc[4 * j2 + 3] += p * v4.w;
      }
    }
  }
  const float inv_l = 1.0f / l_run;
  float* op = out + (size_t)(qb + tq) * HDM + h * 64 + ts * 16;
#pragma unroll
  for (int j2 = 0; j2 < 4; j2++) {
    float4 o;
    o.x = acc[4 * j2 + 0] * inv_l; o.y = acc[4 * j2 + 1] * inv_l;
    o.z = acc[4 * j2 + 2] * inv_l; o.w = acc[4 * j2 + 3] * inv_l;
    *(float4*)(op + 4 * j2) = o;
  }
}

// ---------------- x = LN(x + a) per row; one wave per row ----------------
__global__ __launch_bounds__(256) void ln_residual(float* __restrict__ x,
                                                   const float* __restrict__ a,
                                                   const float* __restrict__ g,
                                                   const float* __restrict__ b) {
  const int lane = threadIdx.x & 63;
  const int row = blockIdx.x * 4 + (threadIdx.x >> 6);
  float v[4];
  float s = 0.0f;
#pragma unroll
  for (int j = 0; j < 4; j++) {
    const int col = j * 64 + lane;
    v[j] = x[(size_t)row * HDM + col] + a[(size_t)row * HDM + col];
    s += v[j];
  }
#pragma unroll
  for (int off = 32; off > 0; off >>= 1) s += __shfl_xor(s, off);
  const float mu = s * (1.0f / HDM);
  float vs = 0.0f;
#pragma unroll
  for (int j = 0; j < 4; j++) {
    const float d = v[j] - mu;
    vs += d * d;
  }
#pragma unroll
  for (int off = 32; off > 0; off >>= 1) vs += __shfl_xor(vs, off);
  const float rinv = 1.0f / sqrtf(vs * (1.0f / HDM) + 1e-5f);
#pragma unroll
  for (int j = 0; j < 4; j++) {
    const int col = j * 64 + lane;
    x[(size_t)row * HDM + col] = g[col] * (v[j] - mu) * rinv + b[col];
  }
}

// ---------------- edge predictor helpers ----------------
__global__ void gather_cat(const float* __restrict__ refined, const int* __restrict__ cand,
                           float* __restrict__ hcat) {
  const int c = blockIdx.x;
  const int t = threadIdx.x;  // 512
  const int n0 = cand[2 * c], n1 = cand[2 * c + 1];
  hcat[(size_t)c * 512 + t] = (t < 256) ? refined[(size_t)n0 * HDM + t]
                                        : refined[(size_t)n1 * HDM + (t - 256)];
}

__global__ void ep_final(const float* __restrict__ eph, const float* __restrict__ w2,
                         const float* __restrict__ b2, float* __restrict__ out) {
  const int c = blockIdx.x;
  const int lane = threadIdx.x;  // 64
  float s = 0.0f;
#pragma unroll
  for (int j = 0; j < 4; j++) s += eph[(size_t)c * HDM + j * 64 + lane] * w2[j * 64 + lane];
#pragma unroll
  for (int off = 32; off > 0; off >>= 1) s += __shfl_xor(s, off);
  if (lane == 0) out[c] = 1.0f / (1.0f + __expf(-(s + b2[0])));
}

extern "C" void kernel_launch(void* const* d_in, const int* in_sizes, int n_in,
                              void* d_out, int out_size, void* d_ws, size_t ws_size,
                              hipStream_t stream) {
  (void)in_sizes; (void)n_in; (void)out_size; (void)ws_size;
  const float* nf    = (const float*)d_in[0];
  const int*   edges = (const int*)d_in[1];
  const int*   cand  = (const int*)d_in[2];
  const float* w_ih  = (const float*)d_in[3];
  const float* w_hh  = (const float*)d_in[4];
  const float* b_ih  = (const float*)d_in[5];
  const float* b_hh  = (const float*)d_in[6];
  const float* ain_w = (const float*)d_in[7];
  const float* ain_b = (const float*)d_in[8];
  const float* aout_w = (const float*)d_in[9];
  const float* aout_b = (const float*)d_in[10];
  const float* ln1g = (const float*)d_in[11];
  const float* ln1b = (const float*)d_in[12];
  const float* f1w  = (const float*)d_in[13];
  const float* f1b  = (const float*)d_in[14];
  const float* f2w  = (const float*)d_in[15];
  const float* f2b  = (const float*)d_in[16];
  const float* ln2g = (const float*)d_in[17];
  const float* ln2b = (const float*)d_in[18];
  const float* s1w  = (const float*)d_in[19];
  const float* s1b  = (const float*)d_in[20];
  const float* s2w  = (const float*)d_in[21];
  const float* s2b  = (const float*)d_in[22];
  const float* e1w  = (const float*)d_in[23];
  const float* e1b  = (const float*)d_in[24];
  const float* e2w  = (const float*)d_in[25];
  const float* e2b  = (const float*)d_in[26];
  float* out = (float*)d_out;

  char* w = (char*)d_ws;
  float* x       = (float*)w; w += (size_t)NN * HDM * 4;
  float* qkv     = (float*)w; w += (size_t)NN * 3 * HDM * 4;
  float* abuf    = (float*)w; w += (size_t)NN * HDM * 4;
  float* fbuf    = (float*)w; w += (size_t)NN * 4 * HDM * 4;
  float* refined = (float*)w; w += (size_t)NN * HDM * 4;
  float* hcat    = (float*)w; w += (size_t)NCAND * 2 * HDM * 4;
  float* eph     = (float*)w; w += (size_t)NCAND * HDM * 4;
  int* cnt       = (int*)w;   w += (size_t)NN * 4;
  int* lists     = (int*)w;   w += (size_t)NN * MAXDEG * 4;

  build_lists<<<NN / 256, 256, 0, stream>>>(edges, cnt, lists);
  gru_quad<<<NN / 4, 256, 0, stream>>>(nf, edges, cnt, lists, w_ih, w_hh, b_ih, b_hh, x);

  for (int l = 0; l < NL; l++) {
    gemm_bias<0><<<dim3(12, 64), 256, 0, stream>>>(x, ain_w + (size_t)l * 768 * 256,
                                                   ain_b + l * 768, qkv, NN, 768, 256);
    flash_attn<<<dim3(64, 4), 256, 0, stream>>>(qkv, abuf);
    gemm_bias<0><<<dim3(4, 64), 256, 0, stream>>>(abuf, aout_w + (size_t)l * 256 * 256,
                                                  aout_b + l * 256, fbuf, NN, 256, 256);
    ln_residual<<<NN / 4, 256, 0, stream>>>(x, fbuf, ln1g + l * 256, ln1b + l * 256);
    gemm_bias<1><<<dim3(16, 64), 256, 0, stream>>>(x, f1w + (size_t)l * 1024 * 256,
                                                   f1b + l * 1024, fbuf, NN, 1024, 256);
    gemm_bias<0><<<dim3(4, 64), 256, 0, stream>>>(fbuf, f2w + (size_t)l * 256 * 1024,
                                                  f2b + l * 256, abuf, NN, 256, 1024);
    ln_residual<<<NN / 4, 256, 0, stream>>>(x, abuf, ln2g + l * 256, ln2b + l * 256);
  }

  gemm_bias<1><<<dim3(4, 64), 256, 0, stream>>>(x, s1w, s1b, abuf, NN, 256, 256);
  gemm_bias<0><<<dim3(4, 64), 256, 0, stream>>>(abuf, s2w, s2b, refined, NN, 256, 256);
  gather_cat<<<NCAND, 512, 0, stream>>>(refined, cand, hcat);
  gemm_bias<1><<<dim3(4, 1), 256, 0, stream>>>(hcat, e1w, e1b, eph, NCAND, 256, 512);
  ep_final<<<NCAND, 64, 0, stream>>>(eph, e2w, e2b, out);
}

// Round 2
// 3694.062 us; speedup vs baseline: 1.4675x; 1.4675x over previous
//
#include <hip/hip_runtime.h>
#include <hip/hip_cooperative_groups.h>
#include <math.h>

#define NN     4096
#define NE     32768
#define NCAND  64
#define IND    128
#define HDM    256
#define NHEAD  4
#define HD     64
#define NL     2
#define MAXD   64

typedef __attribute__((ext_vector_type(8))) short short8;
typedef __attribute__((ext_vector_type(4))) float f32x4;

__device__ __forceinline__ float sigf(float x) { return 1.0f / (1.0f + __expf(-x)); }
__device__ __forceinline__ float tanh_fast(float x) {
  float e = __expf(-2.0f * fabsf(x));
  float r = (1.0f - e) / (1.0f + e);
  return x < 0.0f ? -r : r;
}
__device__ __forceinline__ unsigned short f2bf(float f) {
  unsigned int x = __float_as_uint(f);
  x += 0x7fffu + ((x >> 16) & 1u);   // RNE
  return (unsigned short)(x >> 16);
}

// ================= GRU preprocessing =================
__global__ __launch_bounds__(256) void build_pos(const int* __restrict__ edges,
                                                 int* __restrict__ cnt, int* __restrict__ lists) {
  const int e = blockIdx.x * 256 + threadIdx.x;
  const int d = edges[2 * e + 1];
  const int slot = atomicAdd(&cnt[d], 1);
  if (slot < MAXD) lists[(size_t)d * MAXD + slot] = e;
}

__global__ __launch_bounds__(256) void sort_hist(int* __restrict__ cnt, int* __restrict__ lists,
                                                 int* __restrict__ hist) {
  const int d = blockIdx.x * 256 + threadIdx.x;
  int c = cnt[d]; if (c > MAXD) c = MAXD; cnt[d] = c;
  int* L = lists + (size_t)d * MAXD;
  for (int i = 1; i < c; ++i) {   // insertion sort ascending by edge id
    const int key = L[i];
    int j = i - 1;
    while (j >= 0 && L[j] > key) { L[j + 1] = L[j]; --j; }
    L[j + 1] = key;
  }
  atomicAdd(&hist[c], 1);
}

__global__ void scan_prep(const int* __restrict__ hist, int* __restrict__ rcnt,
                          int* __restrict__ cursor, int* __restrict__ maxd) {
  const int t = threadIdx.x;  // 128
  if (t <= MAXD) {
    int ss = 0;
    for (int dd = t + 1; dd <= MAXD; ++dd) ss += hist[dd];
    cursor[t] = ss;           // rank base for degree t (descending order)
    if (t < MAXD) rcnt[t] = ss;  // #nodes active in round t (deg > t)
  }
  if (t == 0) {
    int mx = 0;
    for (int dd = 1; dd <= MAXD; ++dd) if (hist[dd] > 0) mx = dd;
    maxd[0] = mx;
  }
}

__global__ __launch_bounds__(256) void perm_scatter(const int* __restrict__ cnt,
                                                    int* __restrict__ cursor, int* __restrict__ perm) {
  const int d = blockIdx.x * 256 + threadIdx.x;
  const int rank = atomicAdd(&cursor[cnt[d]], 1);
  perm[rank] = d;
}

// ================= persistent round-synchronous GRU =================
// 512 blocks x 128 threads: block = (slice s = bid&15 -> hidden cols [16s,16s+16),
// m-group mg = bid>>4). Weight slice (48 rows hh + 48 rows ih, bf16, swizzled) lives
// in LDS for all rounds. Per round: tiles of 32 nodes (ranks are degree-sorted so
// active set = prefix [0, rcnt[r])); gh+gx via mfma_f32_16x16x32_bf16; fused GRU
// elementwise; double-buffered h (fp32 global); inactive ranks bulk-copied.
#define GRW 48
#define MT  32

__global__ __launch_bounds__(128) void gru_rounds(
    const float* __restrict__ nf, const int* __restrict__ edges,
    const int* __restrict__ lists, const int* __restrict__ perm,
    const int* __restrict__ rcnt, const int* __restrict__ maxd,
    const float* __restrict__ w_ih, const float* __restrict__ w_hh,
    const float* __restrict__ b_ih, const float* __restrict__ b_hh,
    float* __restrict__ h0, float* __restrict__ h1) {
  namespace cg = cooperative_groups;
  cg::grid_group grid = cg::this_grid();
  const int bid = blockIdx.x;
  const int s = bid & 15;
  const int mg = bid >> 4;
  const int tid = threadIdx.x;
  const int ln = tid & 63;
  const int wm = tid >> 6;          // wave = m-frag (16 nodes)
  const int jc = ln & 15;

  __shared__ unsigned short Whh[GRW * 256];  // row stride 512B, XOR-swizzled
  __shared__ unsigned short Wih[GRW * 128];  // row stride 256B, XOR-swizzled
  __shared__ unsigned short Ah[MT * 256];
  __shared__ unsigned short Ax[MT * 128];
  __shared__ int tileE[MT];

  // ---- stage weight slice once (global row = gate*256 + s*16 + j) ----
  for (int idx = tid; idx < GRW * 32; idx += 128) {      // 8-col chunks of Whh
    const int u = idx >> 5, cb = (idx & 31) << 3;
    const int gr = ((u >> 4) << 8) + (s << 4) + (u & 15);
    const float* src = w_hh + (size_t)gr * 256 + cb;
    short8 v;
#pragma unroll
    for (int j = 0; j < 8; j++) v[j] = (short)f2bf(src[j]);
    *(short8*)((char*)Whh + u * 512 + ((cb * 2) ^ ((u & 7) << 4))) = v;
  }
  for (int idx = tid; idx < GRW * 16; idx += 128) {      // 8-col chunks of Wih
    const int u = idx >> 4, cb = (idx & 15) << 3;
    const int gr = ((u >> 4) << 8) + (s << 4) + (u & 15);
    const float* src = w_ih + (size_t)gr * 128 + cb;
    short8 v;
#pragma unroll
    for (int j = 0; j < 8; j++) v[j] = (short)f2bf(src[j]);
    *(short8*)((char*)Wih + u * 256 + ((cb * 2) ^ ((u & 7) << 4))) = v;
  }
  __syncthreads();

  const int col = (s << 4) + jc;
  const float biR = b_ih[col], biZ = b_ih[256 + col], biN = b_ih[512 + col];
  const float bhR = b_hh[col], bhZ = b_hh[256 + col], bhN = b_hh[512 + col];
  const int kb = (ln >> 4) << 4;      // per-lane K byte offset within 64B k-step
  const int r0 = jc, r1 = 16 + jc, r2 = 32 + jc;

  const int R = maxd[0];
  int p = 0;
  for (int r = 0; r < R; ++r) {
    const float* hs = p ? h1 : h0;
    float* hd = p ? h0 : h1;
    const int nr = rcnt[r];
    const int ntiles = (nr + MT - 1) >> 5;
    for (int t = mg; t < ntiles; t += 32) {
      const int t0 = t << 5;
      __syncthreads();
      if (tid < MT) {
        const int rank = t0 + tid;
        tileE[tid] = (rank < nr) ? lists[(size_t)perm[rank] * MAXD + r] : -1;
      }
      {  // stage Ah: 32 rows x 256 cols fp32->bf16
        const int row = tid >> 2, cb = (tid & 3) << 6;
        const float* src = hs + (size_t)(t0 + row) * HDM + cb;
#pragma unroll
        for (int c8 = 0; c8 < 8; ++c8) {
          short8 v;
#pragma unroll
          for (int j = 0; j < 8; j++) v[j] = (short)f2bf(src[c8 * 8 + j]);
          *(short8*)((char*)Ah + row * 512 + (((cb + c8 * 8) * 2) ^ ((row & 7) << 4))) = v;
        }
      }
      __syncthreads();
      {  // stage Ax: gathered nf[src] rows (needs tileE)
        const int row = tid >> 2, cb = (tid & 3) << 5;
        const int e = tileE[row];
        const int sn = (e >= 0) ? edges[2 * e] : 0;
        const float* src = nf + (size_t)sn * IND + cb;
#pragma unroll
        for (int c8 = 0; c8 < 4; ++c8) {
          short8 v;
#pragma unroll
          for (int j = 0; j < 8; j++) v[j] = (short)f2bf(src[c8 * 8 + j]);
          *(short8*)((char*)Ax + row * 256 + (((cb + c8 * 8) * 2) ^ ((row & 7) << 4))) = v;
        }
      }
      __syncthreads();
      f32x4 aR = {0,0,0,0}, aZ = {0,0,0,0}, aN = {0,0,0,0}, xN = {0,0,0,0};
      const int arow = (wm << 4) + jc;
#pragma unroll
      for (int ks = 0; ks < 8; ++ks) {   // hidden K=256
        const short8 a  = *(const short8*)((const char*)Ah  + arow * 512 + ((ks * 64 + kb) ^ ((arow & 7) << 4)));
        const short8 bR = *(const short8*)((const char*)Whh + r0 * 512 + ((ks * 64 + kb) ^ ((r0 & 7) << 4)));
        const short8 bZ = *(const short8*)((const char*)Whh + r1 * 512 + ((ks * 64 + kb) ^ ((r1 & 7) << 4)));
        const short8 bN = *(const short8*)((const char*)Whh + r2 * 512 + ((ks * 64 + kb) ^ ((r2 & 7) << 4)));
        aR = __builtin_amdgcn_mfma_f32_16x16x32_bf16(a, bR, aR, 0, 0, 0);
        aZ = __builtin_amdgcn_mfma_f32_16x16x32_bf16(a, bZ, aZ, 0, 0, 0);
        aN = __builtin_amdgcn_mfma_f32_16x16x32_bf16(a, bN, aN, 0, 0, 0);
      }
#pragma unroll
      for (int ks = 0; ks < 4; ++ks) {   // input K=128
        const short8 a  = *(const short8*)((const char*)Ax  + arow * 256 + ((ks * 64 + kb) ^ ((arow & 7) << 4)));
        const short8 bR = *(const short8*)((const char*)Wih + r0 * 256 + ((ks * 64 + kb) ^ ((r0 & 7) << 4)));
        const short8 bZ = *(const short8*)((const char*)Wih + r1 * 256 + ((ks * 64 + kb) ^ ((r1 & 7) << 4)));
        const short8 bN = *(const short8*)((const char*)Wih + r2 * 256 + ((ks * 64 + kb) ^ ((r2 & 7) << 4)));
        aR = __builtin_amdgcn_mfma_f32_16x16x32_bf16(a, bR, aR, 0, 0, 0);
        aZ = __builtin_amdgcn_mfma_f32_16x16x32_bf16(a, bZ, aZ, 0, 0, 0);
        xN = __builtin_amdgcn_mfma_f32_16x16x32_bf16(a, bN, xN, 0, 0, 0);
      }
#pragma unroll
      for (int v = 0; v < 4; ++v) {
        const int nodeLocal = (wm << 4) + ((ln >> 4) << 2) + v;
        const int rank = t0 + nodeLocal;
        if (rank < nr) {
          const float rr = sigf(aR[v] + biR + bhR);
          const float zz = sigf(aZ[v] + biZ + bhZ);
          const float nn2 = tanh_fast(xN[v] + biN + rr * (aN[v] + bhN));
          const float ho = hs[(size_t)rank * HDM + col];
          hd[(size_t)rank * HDM + col] = (1.0f - zz) * nn2 + zz * ho;
        }
      }
    }
    for (int rr2 = nr + bid; rr2 < NN; rr2 += 512) {   // carry inactive rows
      if (tid < 64) {
        *(float4*)(hd + (size_t)rr2 * HDM + tid * 4) =
            *(const float4*)(hs + (size_t)rr2 * HDM + tid * 4);
      }
    }
    __threadfence();
    grid.sync();
    p ^= 1;
  }
}

__global__ __launch_bounds__(256) void unperm(const int* __restrict__ perm,
                                              const int* __restrict__ maxd,
                                              const float* __restrict__ h0,
                                              const float* __restrict__ h1,
                                              float* __restrict__ x) {
  const float* hb = (maxd[0] & 1) ? h1 : h0;
  for (int i = 0; i < 16; ++i) {
    const int rank = blockIdx.x * 16 + i;
    x[(size_t)perm[rank] * HDM + threadIdx.x] = hb[(size_t)rank * HDM + threadIdx.x];
  }
}

// ================= transformer (unchanged fp32 path) =================
template <int ACT>
__global__ __launch_bounds__(256) void gemm_bias(const float* __restrict__ A,
                                                 const float* __restrict__ W,
                                                 const float* __restrict__ bias,
                                                 float* __restrict__ C, int M, int NCo, int K) {
  __shared__ float As[16][65];
  __shared__ float Ws[16][65];
  const int bm = blockIdx.y * 64, bn = blockIdx.x * 64;
  const int tid = threadIdx.x;
  const int tx = tid & 15, ty = tid >> 4;
  const int lr = tid >> 2;
  const int lk = (tid & 3) * 4;
  float acc[4][4] = {{0.0f}};
  for (int k0 = 0; k0 < K; k0 += 16) {
    __syncthreads();
    {
      const float4 a4 = *(const float4*)(A + (size_t)(bm + lr) * K + k0 + lk);
      As[lk + 0][lr] = a4.x; As[lk + 1][lr] = a4.y; As[lk + 2][lr] = a4.z; As[lk + 3][lr] = a4.w;
      const float4 w4 = *(const float4*)(W + (size_t)(bn + lr) * K + k0 + lk);
      Ws[lk + 0][lr] = w4.x; Ws[lk + 1][lr] = w4.y; Ws[lk + 2][lr] = w4.z; Ws[lk + 3][lr] = w4.w;
    }
    __syncthreads();
#pragma unroll
    for (int k = 0; k < 16; k++) {
      const float a0 = As[k][ty * 4 + 0], a1 = As[k][ty * 4 + 1];
      const float a2 = As[k][ty * 4 + 2], a3 = As[k][ty * 4 + 3];
      const float w0 = Ws[k][tx * 4 + 0], w1 = Ws[k][tx * 4 + 1];
      const float w2 = Ws[k][tx * 4 + 2], w3 = Ws[k][tx * 4 + 3];
      acc[0][0] += a0 * w0; acc[0][1] += a0 * w1; acc[0][2] += a0 * w2; acc[0][3] += a0 * w3;
      acc[1][0] += a1 * w0; acc[1][1] += a1 * w1; acc[1][2] += a1 * w2; acc[1][3] += a1 * w3;
      acc[2][0] += a2 * w0; acc[2][1] += a2 * w1; acc[2][2] += a2 * w2; acc[2][3] += a2 * w3;
      acc[3][0] += a3 * w0; acc[3][1] += a3 * w1; acc[3][2] += a3 * w2; acc[3][3] += a3 * w3;
    }
  }
  const float b0 = bias[bn + tx * 4 + 0], b1 = bias[bn + tx * 4 + 1];
  const float b2 = bias[bn + tx * 4 + 2], b3 = bias[bn + tx * 4 + 3];
#pragma unroll
  for (int i = 0; i < 4; i++) {
    float4 o;
    o.x = acc[i][0] + b0; o.y = acc[i][1] + b1; o.z = acc[i][2] + b2; o.w = acc[i][3] + b3;
    if (ACT == 1) {
      o.x = fmaxf(o.x, 0.0f); o.y = fmaxf(o.y, 0.0f);
      o.z = fmaxf(o.z, 0.0f); o.w = fmaxf(o.w, 0.0f);
    }
    *(float4*)(C + (size_t)(bm + ty * 4 + i) * NCo + bn + tx * 4) = o;
  }
}

__global__ __launch_bounds__(256) void flash_attn(const float* __restrict__ qkv,
                                                  float* __restrict__ out) {
  const int h = blockIdx.y;
  const int qb = blockIdx.x * 64;
  const int tid = threadIdx.x;
  const int tq = tid >> 2, ts = tid & 3;
  __shared__ float Ks[64][68];
  __shared__ float Vs[64][68];
  __shared__ float Ps[64][68];

  float q[64];
  {
    const float4* qp = (const float4*)(qkv + (size_t)(qb + tq) * 768 + h * 64);
#pragma unroll
    for (int u = 0; u < 16; u++) {
      const float4 v = qp[u];
      q[4 * u + 0] = v.x; q[4 * u + 1] = v.y; q[4 * u + 2] = v.z; q[4 * u + 3] = v.w;
    }
  }
  float m_run = -1e30f, l_run = 0.0f;
  float acc[16];
#pragma unroll
  for (int j = 0; j < 16; j++) acc[j] = 0.0f;

  for (int kb = 0; kb < 64; kb++) {
    __syncthreads();
    {
      const int r = tid >> 2;
      const int c4 = (tid & 3) * 16;
      const float4* kp = (const float4*)(qkv + (size_t)(kb * 64 + r) * 768 + 256 + h * 64 + c4);
      const float4* vp = (const float4*)(qkv + (size_t)(kb * 64 + r) * 768 + 512 + h * 64 + c4);
#pragma unroll
      for (int u = 0; u < 4; u++) {
        const float4 kv = kp[u];
        Ks[r][c4 + 4 * u + 0] = kv.x; Ks[r][c4 + 4 * u + 1] = kv.y;
        Ks[r][c4 + 4 * u + 2] = kv.z; Ks[r][c4 + 4 * u + 3] = kv.w;
        const float4 vv = vp[u];
        Vs[r][c4 + 4 * u + 0] = vv.x; Vs[r][c4 + 4 * u + 1] = vv.y;
        Vs[r][c4 + 4 * u + 2] = vv.z; Vs[r][c4 + 4 * u + 3] = vv.w;
      }
    }
    __syncthreads();
    float s[16];
#pragma unroll
    for (int i = 0; i < 16; i++) {
      const int kk = ts + 4 * i;
      const float4* krow = (const float4*)(&Ks[kk][0]);
      float a0 = 0.0f, a1 = 0.0f, a2 = 0.0f, a3 = 0.0f;
#pragma unroll
      for (int u = 0; u < 16; u++) {
        const float4 k4 = krow[u];
        a0 += q[4 * u + 0] * k4.x; a1 += q[4 * u + 1] * k4.y;
        a2 += q[4 * u + 2] * k4.z; a3 += q[4 * u + 3] * k4.w;
      }
      s[i] = 0.125f * ((a0 + a1) + (a2 + a3));
    }
    float mb = s[0];
#pragma unroll
    for (int i = 1; i < 16; i++) mb = fmaxf(mb, s[i]);
    mb = fmaxf(mb, __shfl_xor(mb, 1));
    mb = fmaxf(mb, __shfl_xor(mb, 2));
    const float m_new = fmaxf(m_run, mb);
    const float alpha = __expf(m_run - m_new);
    float psum = 0.0f;
#pragma unroll
    for (int i = 0; i < 16; i++) {
      const float p = __expf(s[i] - m_new);
      Ps[tq][ts + 4 * i] = p;
      psum += p;
    }
    psum += __shfl_xor(psum, 1);
    psum += __shfl_xor(psum, 2);
    l_run = l_run * alpha + psum;
    m_run = m_new;
    __syncthreads();
#pragma unroll
    for (int j = 0; j < 16; j++) acc[j] *= alpha;
    for (int k = 0; k < 64; k++) {
      const float p = Ps[tq][k];
      const float4* vrow = (const float4*)(&Vs[k][ts * 16]);
#pragma unroll
      for (int j2 = 0; j2 < 4; j2++) {
        const float4 v4 = vrow[j2];
        acc[4 * j2 + 0] += p * v4.x; acc[4 * j2 + 1] += p * v4.y;
        acc[4 * j2 + 2] += p * v4.z; acc[4 * j2 + 3] += p * v4.w;
      }
    }
  }
  const float inv_l = 1.0f / l_run;
  float* op = out + (size_t)(qb + tq) * HDM + h * 64 + ts * 16;
#pragma unroll
  for (int j2 = 0; j2 < 4; j2++) {
    float4 o;
    o.x = acc[4 * j2 + 0] * inv_l; o.y = acc[4 * j2 + 1] * inv_l;
    o.z = acc[4 * j2 + 2] * inv_l; o.w = acc[4 * j2 + 3] * inv_l;
    *(float4*)(op + 4 * j2) = o;
  }
}

__global__ __launch_bounds__(256) void ln_residual(float* __restrict__ x,
                                                   const float* __restrict__ a,
                                                   const float* __restrict__ g,
                                                   const float* __restrict__ b) {
  const int lane = threadIdx.x & 63;
  const int row = blockIdx.x * 4 + (threadIdx.x >> 6);
  float v[4];
  float s = 0.0f;
#pragma unroll
  for (int j = 0; j < 4; j++) {
    const int col = j * 64 + lane;
    v[j] = x[(size_t)row * HDM + col] + a[(size_t)row * HDM + col];
    s += v[j];
  }
#pragma unroll
  for (int off = 32; off > 0; off >>= 1) s += __shfl_xor(s, off);
  const float mu = s * (1.0f / HDM);
  float vs = 0.0f;
#pragma unroll
  for (int j = 0; j < 4; j++) {
    const float d = v[j] - mu;
    vs += d * d;
  }
#pragma unroll
  for (int off = 32; off > 0; off >>= 1) vs += __shfl_xor(vs, off);
  const float rinv = 1.0f / sqrtf(vs * (1.0f / HDM) + 1e-5f);
#pragma unroll
  for (int j = 0; j < 4; j++) {
    const int col = j * 64 + lane;
    x[(size_t)row * HDM + col] = g[col] * (v[j] - mu) * rinv + b[col];
  }
}

__global__ void gather_cat(const float* __restrict__ refined, const int* __restrict__ cand,
                           float* __restrict__ hcat) {
  const int c = blockIdx.x;
  const int t = threadIdx.x;  // 512
  const int n0 = cand[2 * c], n1 = cand[2 * c + 1];
  hcat[(size_t)c * 512 + t] = (t < 256) ? refined[(size_t)n0 * HDM + t]
                                        : refined[(size_t)n1 * HDM + (t - 256)];
}

__global__ void ep_final(const float* __restrict__ eph, const float* __restrict__ w2,
                         const float* __restrict__ b2, float* __restrict__ out) {
  const int c = blockIdx.x;
  const int lane = threadIdx.x;  // 64
  float s = 0.0f;
#pragma unroll
  for (int j = 0; j < 4; j++) s += eph[(size_t)c * HDM + j * 64 + lane] * w2[j * 64 + lane];
#pragma unroll
  for (int off = 32; off > 0; off >>= 1) s += __shfl_xor(s, off);
  if (lane == 0) out[c] = 1.0f / (1.0f + __expf(-(s + b2[0])));
}

extern "C" void kernel_launch(void* const* d_in, const int* in_sizes, int n_in,
                              void* d_out, int out_size, void* d_ws, size_t ws_size,
                              hipStream_t stream) {
  (void)in_sizes; (void)n_in; (void)out_size; (void)ws_size;
  const float* nf    = (const float*)d_in[0];
  const int*   edges = (const int*)d_in[1];
  const int*   cand  = (const int*)d_in[2];
  const float* w_ih  = (const float*)d_in[3];
  const float* w_hh  = (const float*)d_in[4];
  const float* b_ih  = (const float*)d_in[5];
  const float* b_hh  = (const float*)d_in[6];
  const float* ain_w = (const float*)d_in[7];
  const float* ain_b = (const float*)d_in[8];
  const float* aout_w = (const float*)d_in[9];
  const float* aout_b = (const float*)d_in[10];
  const float* ln1g = (const float*)d_in[11];
  const float* ln1b = (const float*)d_in[12];
  const float* f1w  = (const float*)d_in[13];
  const float* f1b  = (const float*)d_in[14];
  const float* f2w  = (const float*)d_in[15];
  const float* f2b  = (const float*)d_in[16];
  const float* ln2g = (const float*)d_in[17];
  const float* ln2b = (const float*)d_in[18];
  const float* s1w  = (const float*)d_in[19];
  const float* s1b  = (const float*)d_in[20];
  const float* s2w  = (const float*)d_in[21];
  const float* s2b  = (const float*)d_in[22];
  const float* e1w  = (const float*)d_in[23];
  const float* e1b  = (const float*)d_in[24];
  const float* e2w  = (const float*)d_in[25];
  const float* e2b  = (const float*)d_in[26];
  float* out = (float*)d_out;

  char* w = (char*)d_ws;
  float* x       = (float*)w; w += (size_t)NN * HDM * 4;
  float* qkv     = (float*)w; w += (size_t)NN * 3 * HDM * 4;
  float* abuf    = (float*)w; w += (size_t)NN * HDM * 4;
  float* fbuf    = (float*)w; w += (size_t)NN * 4 * HDM * 4;
  float* refined = (float*)w; w += (size_t)NN * HDM * 4;
  float* hcat    = (float*)w; w += (size_t)NCAND * 2 * HDM * 4;
  float* eph     = (float*)w; w += (size_t)NCAND * HDM * 4;
  int* cnt       = (int*)w;   w += (size_t)NN * 4;
  int* lists     = (int*)w;   w += (size_t)NN * MAXD * 4;
  int* meta      = (int*)w;   w += 256 * 4;
  int* perm      = (int*)w;   w += (size_t)NN * 4;
  float* h0      = (float*)w; w += (size_t)NN * HDM * 4;
  float* h1      = (float*)w; w += (size_t)NN * HDM * 4;
  int* hist   = meta;
  int* rcnt   = meta + 80;
  int* cursor = meta + 160;
  int* maxd   = meta + 240;

  hipMemsetAsync(cnt, 0, (size_t)NN * 4, stream);
  hipMemsetAsync(meta, 0, 256 * 4, stream);
  hipMemsetAsync(h0, 0, (size_t)NN * HDM * 4, stream);

  build_pos<<<NE / 256, 256, 0, stream>>>(edges, cnt, lists);
  sort_hist<<<NN / 256, 256, 0, stream>>>(cnt, lists, hist);
  scan_prep<<<1, 128, 0, stream>>>(hist, rcnt, cursor, maxd);
  perm_scatter<<<NN / 256, 256, 0, stream>>>(cnt, cursor, perm);

  {
    void* cargs[12];
    cargs[0] = (void*)&nf;    cargs[1] = (void*)&edges; cargs[2] = (void*)&lists;
    cargs[3] = (void*)&perm;  cargs[4] = (void*)&rcnt;  cargs[5] = (void*)&maxd;
    cargs[6] = (void*)&w_ih;  cargs[7] = (void*)&w_hh;  cargs[8] = (void*)&b_ih;
    cargs[9] = (void*)&b_hh;  cargs[10] = (void*)&h0;   cargs[11] = (void*)&h1;
    hipLaunchCooperativeKernel((const void*)gru_rounds, dim3(512), dim3(128), cargs, 0, stream);
  }
  unperm<<<NN / 16, 256, 0, stream>>>(perm, maxd, h0, h1, x);

  for (int l = 0; l < NL; l++) {
    gemm_bias<0><<<dim3(12, 64), 256, 0, stream>>>(x, ain_w + (size_t)l * 768 * 256,
                                                   ain_b + l * 768, qkv, NN, 768, 256);
    flash_attn<<<dim3(64, 4), 256, 0, stream>>>(qkv, abuf);
    gemm_bias<0><<<dim3(4, 64), 256, 0, stream>>>(abuf, aout_w + (size_t)l * 256 * 256,
                                                  aout_b + l * 256, fbuf, NN, 256, 256);
    ln_residual<<<NN / 4, 256, 0, stream>>>(x, fbuf, ln1g + l * 256, ln1b + l * 256);
    gemm_bias<1><<<dim3(16, 64), 256, 0, stream>>>(x, f1w + (size_t)l * 1024 * 256,
                                                   f1b + l * 1024, fbuf, NN, 1024, 256);
    gemm_bias<0><<<dim3(4, 64), 256, 0, stream>>>(fbuf, f2w + (size_t)l * 256 * 1024,
                                                  f2b + l * 256, abuf, NN, 256, 1024);
    ln_residual<<<NN / 4, 256, 0, stream>>>(x, abuf, ln2g + l * 256, ln2b + l * 256);
  }

  gemm_bias<1><<<dim3(4, 64), 256, 0, stream>>>(x, s1w, s1b, abuf, NN, 256, 256);
  gemm_bias<0><<<dim3(4, 64), 256, 0, stream>>>(abuf, s2w, s2b, refined, NN, 256, 256);
  gather_cat<<<NCAND, 512, 0, stream>>>(refined, cand, hcat);
  gemm_bias<1><<<dim3(4, 1), 256, 0, stream>>>(hcat, e1w, e1b, eph, NCAND, 256, 512);
  ep_final<<<NCAND, 64, 0, stream>>>(eph, e2w, e2b, out);
}

// Round 3
// 1538.473 us; speedup vs baseline: 3.5237x; 2.4011x over previous
//
#include <hip/hip_runtime.h>
#include <math.h>

#define NN     4096
#define NE     32768
#define NCAND  64
#define IND    128
#define HDM    256
#define NL     2
#define MAXD   64
#define GNPB   16   // GRU nodes per block

typedef __attribute__((ext_vector_type(8))) short short8;
typedef __attribute__((ext_vector_type(4))) float f32x4;

__device__ __forceinline__ float sigf(float x) { return 1.0f / (1.0f + __expf(-x)); }
__device__ __forceinline__ float tanh_fast(float x) {
  float e = __expf(-2.0f * fabsf(x));
  float r = (1.0f - e) / (1.0f + e);
  return x < 0.0f ? -r : r;
}
__device__ __forceinline__ unsigned short f2bf(float f) {
  unsigned int x = __float_as_uint(f);
  x += 0x7fffu + ((x >> 16) & 1u);   // RNE
  return (unsigned short)(x >> 16);
}
__device__ __forceinline__ float bf2f(unsigned short u) {
  return __uint_as_float(((unsigned int)u) << 16);
}

// ================= weight/feature fp32->bf16 conversion (one launch) =================
// packed dst segments (element offsets):
// nf 0..524288 | wih @524288 (98304) | ain @622592 (393216) | aout @1015808 (131072)
// f1 @1146880 (524288) | f2 @1671168 (524288) | s1 @2195456 (65536) | s2 @2260992 (65536)
#define CVT_TOT 2326528
__global__ __launch_bounds__(256) void cvt_weights(
    const float* __restrict__ nf, const float* __restrict__ wih,
    const float* __restrict__ ain, const float* __restrict__ aout,
    const float* __restrict__ f1, const float* __restrict__ f2,
    const float* __restrict__ s1, const float* __restrict__ s2,
    unsigned short* __restrict__ dst) {
  const size_t e = ((size_t)blockIdx.x * 256 + threadIdx.x) * 4;
  if (e >= CVT_TOT) return;
  const float* src;
  if (e < 524288)       src = nf   + e;
  else if (e < 622592)  src = wih  + (e - 524288);
  else if (e < 1015808) src = ain  + (e - 622592);
  else if (e < 1146880) src = aout + (e - 1015808);
  else if (e < 1671168) src = f1   + (e - 1146880);
  else if (e < 2195456) src = f2   + (e - 1671168);
  else if (e < 2260992) src = s1   + (e - 2195456);
  else                  src = s2   + (e - 2260992);
  const float4 v = *(const float4*)src;
  dst[e + 0] = f2bf(v.x); dst[e + 1] = f2bf(v.y);
  dst[e + 2] = f2bf(v.z); dst[e + 3] = f2bf(v.w);
}

// ================= GRU preprocessing =================
__global__ __launch_bounds__(256) void build_pos(const int* __restrict__ edges,
                                                 int* __restrict__ cnt, int* __restrict__ lists) {
  const int e = blockIdx.x * 256 + threadIdx.x;
  const int d = edges[2 * e + 1];
  const int slot = atomicAdd(&cnt[d], 1);
  if (slot < MAXD) lists[(size_t)d * MAXD + slot] = e;
}

__global__ __launch_bounds__(256) void sort_hist(int* __restrict__ cnt, int* __restrict__ lists,
                                                 int* __restrict__ hist) {
  const int d = blockIdx.x * 256 + threadIdx.x;
  int c = cnt[d]; if (c > MAXD) c = MAXD; cnt[d] = c;
  int* L = lists + (size_t)d * MAXD;
  for (int i = 1; i < c; ++i) {   // insertion sort ascending by edge id
    const int key = L[i];
    int j = i - 1;
    while (j >= 0 && L[j] > key) { L[j + 1] = L[j]; --j; }
    L[j + 1] = key;
  }
  atomicAdd(&hist[c], 1);
}

__global__ void scan_prep(const int* __restrict__ hist, int* __restrict__ cursor) {
  const int t = threadIdx.x;  // 128
  if (t <= MAXD) {
    int ss = 0;
    for (int dd = t + 1; dd <= MAXD; ++dd) ss += hist[dd];
    cursor[t] = ss;           // rank base for degree t (descending-degree order)
  }
}

__global__ __launch_bounds__(256) void perm_scatter(const int* __restrict__ cnt,
                                                    int* __restrict__ cursor, int* __restrict__ perm) {
  const int d = blockIdx.x * 256 + threadIdx.x;
  const int rank = atomicAdd(&cursor[cnt[d]], 1);
  perm[rank] = d;
}

// ================= generic bf16 MFMA GEMM =================
// C[M,N] = act(A[M,K] @ W[N,K]^T + bias); 64x64 tile, 256 thr, 4 waves (2m x 2n of 32x32)
// GS: A-row gather stride (0 = identity, 2 = edges src). OMODE: 0 fp32, 1 fp32+bf16, 2 bf16 only.
template <int ACT, int GS, int OMODE>
__global__ __launch_bounds__(256) void gemm_bf16(
    const unsigned short* __restrict__ A, const int* __restrict__ gidx,
    const unsigned short* __restrict__ W, const float* __restrict__ bias,
    float* __restrict__ C, unsigned short* __restrict__ Cb,
    int M, int N, int K) {
  __shared__ unsigned short As[64 * 64];   // row stride 128B, 16B-chunk XOR swizzle
  __shared__ unsigned short Ws[64 * 64];
  __shared__ int ridx[64];
  const int bm = blockIdx.y * 64, bn = blockIdx.x * 64;
  const int tid = threadIdx.x;
  const int ln = tid & 63, w = tid >> 6;
  const int jc = ln & 15, kq = ln >> 4;
  const int srow = tid >> 2, q = tid & 3;

  if constexpr (GS > 0) {
    if (tid < 64) ridx[tid] = gidx[(size_t)(bm + tid) * GS];
    __syncthreads();
  }
  const size_t arow = (GS > 0) ? (size_t)ridx[srow] : (size_t)(bm + srow);
  const unsigned short* Asrc = A + arow * K + q * 16;
  const unsigned short* Wsrc = W + (size_t)(bn + srow) * K + q * 16;

  f32x4 acc[2][2];
#pragma unroll
  for (int i = 0; i < 2; ++i)
#pragma unroll
    for (int j = 0; j < 2; ++j) acc[i][j] = (f32x4){0.f, 0.f, 0.f, 0.f};
  const int mrow = (w >> 1) * 32, ncol = (w & 1) * 32;
  const int sb0 = (q * 32) ^ ((srow & 7) << 4);
  const int sb1 = (q * 32 + 16) ^ ((srow & 7) << 4);

  for (int k0 = 0; k0 < K; k0 += 64) {
    __syncthreads();
    {
      const short8 a0 = *(const short8*)(Asrc + k0);
      const short8 a1 = *(const short8*)(Asrc + k0 + 8);
      const short8 w0 = *(const short8*)(Wsrc + k0);
      const short8 w1 = *(const short8*)(Wsrc + k0 + 8);
      *(short8*)((char*)As + srow * 128 + sb0) = a0;
      *(short8*)((char*)As + srow * 128 + sb1) = a1;
      *(short8*)((char*)Ws + srow * 128 + sb0) = w0;
      *(short8*)((char*)Ws + srow * 128 + sb1) = w1;
    }
    __syncthreads();
#pragma unroll
    for (int kt = 0; kt < 2; ++kt) {
      const int kb = kt * 64 + kq * 16;
      short8 a[2], bb[2];
#pragma unroll
      for (int i = 0; i < 2; ++i) {
        const int ra = mrow + i * 16 + jc;
        a[i] = *(const short8*)((const char*)As + ra * 128 + (kb ^ ((ra & 7) << 4)));
        const int rb = ncol + i * 16 + jc;
        bb[i] = *(const short8*)((const char*)Ws + rb * 128 + (kb ^ ((rb & 7) << 4)));
      }
#pragma unroll
      for (int mi = 0; mi < 2; ++mi)
#pragma unroll
        for (int ni = 0; ni < 2; ++ni)
          acc[mi][ni] = __builtin_amdgcn_mfma_f32_16x16x32_bf16(a[mi], bb[ni], acc[mi][ni], 0, 0, 0);
    }
  }
#pragma unroll
  for (int mi = 0; mi < 2; ++mi)
#pragma unroll
    for (int ni = 0; ni < 2; ++ni) {
      const int col = bn + ncol + ni * 16 + jc;
      const float bs = bias[col];
#pragma unroll
      for (int v = 0; v < 4; ++v) {
        const int row = bm + mrow + mi * 16 + kq * 4 + v;
        float val = acc[mi][ni][v] + bs;
        if (ACT == 1) val = fmaxf(val, 0.0f);
        if constexpr (OMODE != 2) C[(size_t)row * N + col] = val;
        if constexpr (OMODE >= 1) Cb[(size_t)row * N + col] = f2bf(val);
      }
    }
}

// ================= per-block independent GRU (no grid sync) =================
// 256 blocks x 256 thr (4 waves). Block owns 16 degree-sorted ranks end-to-end.
// h fp32 in LDS all rounds; w_hh bf16 fragments in VGPRs (wave w: cols [64w,64w+64) per gate);
// gi (= nf[src]@w_ih^T + b_ih, bf16, precomputed per edge) streamed per round (issue-early).
__global__ __launch_bounds__(256, 1) void gru_reg(
    const int* __restrict__ perm, const int* __restrict__ cnt,
    const int* __restrict__ lists, const unsigned short* __restrict__ gi,
    const float* __restrict__ w_hh, const float* __restrict__ b_hh,
    float* __restrict__ x, unsigned short* __restrict__ xb) {
  const int tid = threadIdx.x;
  const int ln = tid & 63;
  const int w = tid >> 6;
  const int jc = ln & 15;
  const int kq = ln >> 4;
  const int grow = tid >> 4;     // 0..15 (node row for staging)
  const int gpart = tid & 15;

  __shared__ float h[GNPB][260];
  __shared__ unsigned short Ah[GNPB * 256];   // row stride 512B, swz
  __shared__ unsigned short Gi[GNPB * 776];   // row stride 1552B
  __shared__ int lists_s[GNPB][MAXD];
  __shared__ int node_s[GNPB], cnt_s[GNPB], e_s[GNPB];
  __shared__ int Rb_s;

  if (tid < GNPB) {
    const int node = perm[blockIdx.x * GNPB + tid];
    node_s[tid] = node;
    cnt_s[tid] = cnt[node];
  }
  for (int i = tid; i < GNPB * 260; i += 256) ((float*)h)[i] = 0.0f;
  __syncthreads();
  for (int i = tid; i < GNPB * MAXD; i += 256)
    lists_s[i >> 6][i & 63] = lists[(size_t)node_s[i >> 6] * MAXD + (i & 63)];
  if (tid == 0) {
    int mx = 0;
    for (int i = 0; i < GNPB; ++i) mx = mx > cnt_s[i] ? mx : cnt_s[i];
    Rb_s = mx;
  }

  // stage w_hh -> 96 B-fragments in VGPRs (wave w, gate g: rows g*256 + w*64 + ct*16 + jc)
  short8 W[96];
#pragma unroll
  for (int g = 0; g < 3; ++g)
#pragma unroll
    for (int ct = 0; ct < 4; ++ct) {
      const int nrow = g * 256 + w * 64 + ct * 16 + jc;
      const float* src = w_hh + (size_t)nrow * 256 + kq * 8;
#pragma unroll
      for (int kt = 0; kt < 8; ++kt) {
        const float* s8 = src + kt * 32;
        short8 v;
#pragma unroll
        for (int j = 0; j < 8; ++j) v[j] = (short)f2bf(s8[j]);
        W[(g * 4 + ct) * 8 + kt] = v;
      }
    }
  float bh[12];
#pragma unroll
  for (int g = 0; g < 3; ++g)
#pragma unroll
    for (int ct = 0; ct < 4; ++ct)
      bh[g * 4 + ct] = b_hh[g * 256 + w * 64 + ct * 16 + jc];
  __syncthreads();
  const int Rb = Rb_s;

  for (int r = 0; r < Rb; ++r) {
    if (tid < GNPB) e_s[tid] = (r < cnt_s[tid]) ? lists_s[tid][r] : -1;
    __syncthreads();
    // issue gi loads early (written to LDS after MFMA)
    short8 gv[6];
    const int ge = e_s[grow];
    if (ge >= 0) {
      const unsigned short* gsrc = gi + (size_t)ge * 768 + gpart * 48;
#pragma unroll
      for (int c = 0; c < 6; ++c) gv[c] = *(const short8*)(gsrc + c * 8);
    }
    // convert h -> Ah bf16 (swizzled)
    {
      const float* hr = &h[grow][gpart * 16];
#pragma unroll
      for (int c = 0; c < 2; ++c) {
        short8 v;
#pragma unroll
        for (int j = 0; j < 8; ++j) v[j] = (short)f2bf(hr[c * 8 + j]);
        *(short8*)((char*)Ah + grow * 512 + ((gpart * 32 + c * 16) ^ ((grow & 7) << 4))) = v;
      }
    }
    __syncthreads();
    f32x4 acc[12];
#pragma unroll
    for (int i = 0; i < 12; ++i) acc[i] = (f32x4){0.f, 0.f, 0.f, 0.f};
#pragma unroll
    for (int kt = 0; kt < 8; ++kt) {
      const short8 a = *(const short8*)((const char*)Ah + jc * 512 + ((kt * 64 + kq * 16) ^ ((jc & 7) << 4)));
#pragma unroll
      for (int i = 0; i < 12; ++i)
        acc[i] = __builtin_amdgcn_mfma_f32_16x16x32_bf16(a, W[i * 8 + kt], acc[i], 0, 0, 0);
    }
    if (ge >= 0) {
      unsigned short* gdst = Gi + grow * 776 + gpart * 48;
#pragma unroll
      for (int c = 0; c < 6; ++c) *(short8*)(gdst + c * 8) = gv[c];
    }
    __syncthreads();
#pragma unroll
    for (int ct = 0; ct < 4; ++ct) {
      const int colg = w * 64 + ct * 16 + jc;
#pragma unroll
      for (int v = 0; v < 4; ++v) {
        const int node = kq * 4 + v;
        if (r < cnt_s[node]) {
          const float giR = bf2f(Gi[node * 776 + colg]);
          const float giZ = bf2f(Gi[node * 776 + 256 + colg]);
          const float giN = bf2f(Gi[node * 776 + 512 + colg]);
          const float rr = sigf(giR + acc[ct][v] + bh[ct]);
          const float zz = sigf(giZ + acc[4 + ct][v] + bh[4 + ct]);
          const float nn2 = tanh_fast(giN + rr * (acc[8 + ct][v] + bh[8 + ct]));
          h[node][colg] = (1.0f - zz) * nn2 + zz * h[node][colg];
        }
      }
    }
    __syncthreads();
  }
  // final write: x fp32 + xb bf16
  {
    const float* hr = &h[grow][gpart * 16];
    float* xd = x + (size_t)node_s[grow] * HDM + gpart * 16;
    unsigned short* xbd = xb + (size_t)node_s[grow] * HDM + gpart * 16;
#pragma unroll
    for (int c = 0; c < 4; ++c) *(float4*)(xd + c * 4) = *(const float4*)(hr + c * 4);
#pragma unroll
    for (int c = 0; c < 2; ++c) {
      short8 v;
#pragma unroll
      for (int j = 0; j < 8; ++j) v[j] = (short)f2bf(hr[c * 8 + j]);
      *(short8*)(xbd + c * 8) = v;
    }
  }
}

// ================= fp32 flash attention (emits fp32 + bf16) =================
__global__ __launch_bounds__(256) void flash_attn(const float* __restrict__ qkv,
                                                  float* __restrict__ out,
                                                  unsigned short* __restrict__ outb) {
  const int h = blockIdx.y;
  const int qb = blockIdx.x * 64;
  const int tid = threadIdx.x;
  const int tq = tid >> 2, ts = tid & 3;
  __shared__ float Ks[64][68];
  __shared__ float Vs[64][68];
  __shared__ float Ps[64][68];

  float q[64];
  {
    const float4* qp = (const float4*)(qkv + (size_t)(qb + tq) * 768 + h * 64);
#pragma unroll
    for (int u = 0; u < 16; u++) {
      const float4 v = qp[u];
      q[4 * u + 0] = v.x; q[4 * u + 1] = v.y; q[4 * u + 2] = v.z; q[4 * u + 3] = v.w;
    }
  }
  float m_run = -1e30f, l_run = 0.0f;
  float acc[16];
#pragma unroll
  for (int j = 0; j < 16; j++) acc[j] = 0.0f;

  for (int kb = 0; kb < 64; kb++) {
    __syncthreads();
    {
      const int r = tid >> 2;
      const int c4 = (tid & 3) * 16;
      const float4* kp = (const float4*)(qkv + (size_t)(kb * 64 + r) * 768 + 256 + h * 64 + c4);
      const float4* vp = (const float4*)(qkv + (size_t)(kb * 64 + r) * 768 + 512 + h * 64 + c4);
#pragma unroll
      for (int u = 0; u < 4; u++) {
        const float4 kv = kp[u];
        Ks[r][c4 + 4 * u + 0] = kv.x; Ks[r][c4 + 4 * u + 1] = kv.y;
        Ks[r][c4 + 4 * u + 2] = kv.z; Ks[r][c4 + 4 * u + 3] = kv.w;
        const float4 vv = vp[u];
        Vs[r][c4 + 4 * u + 0] = vv.x; Vs[r][c4 + 4 * u + 1] = vv.y;
        Vs[r][c4 + 4 * u + 2] = vv.z; Vs[r][c4 + 4 * u + 3] = vv.w;
      }
    }
    __syncthreads();
    float s[16];
#pragma unroll
    for (int i = 0; i < 16; i++) {
      const int kk = ts + 4 * i;
      const float4* krow = (const float4*)(&Ks[kk][0]);
      float a0 = 0.0f, a1 = 0.0f, a2 = 0.0f, a3 = 0.0f;
#pragma unroll
      for (int u = 0; u < 16; u++) {
        const float4 k4 = krow[u];
        a0 += q[4 * u + 0] * k4.x; a1 += q[4 * u + 1] * k4.y;
        a2 += q[4 * u + 2] * k4.z; a3 += q[4 * u + 3] * k4.w;
      }
      s[i] = 0.125f * ((a0 + a1) + (a2 + a3));
    }
    float mb = s[0];
#pragma unroll
    for (int i = 1; i < 16; i++) mb = fmaxf(mb, s[i]);
    mb = fmaxf(mb, __shfl_xor(mb, 1));
    mb = fmaxf(mb, __shfl_xor(mb, 2));
    const float m_new = fmaxf(m_run, mb);
    const float alpha = __expf(m_run - m_new);
    float psum = 0.0f;
#pragma unroll
    for (int i = 0; i < 16; i++) {
      const float p = __expf(s[i] - m_new);
      Ps[tq][ts + 4 * i] = p;
      psum += p;
    }
    psum += __shfl_xor(psum, 1);
    psum += __shfl_xor(psum, 2);
    l_run = l_run * alpha + psum;
    m_run = m_new;
    __syncthreads();
#pragma unroll
    for (int j = 0; j < 16; j++) acc[j] *= alpha;
    for (int k = 0; k < 64; k++) {
      const float p = Ps[tq][k];
      const float4* vrow = (const float4*)(&Vs[k][ts * 16]);
#pragma unroll
      for (int j2 = 0; j2 < 4; j2++) {
        const float4 v4 = vrow[j2];
        acc[4 * j2 + 0] += p * v4.x; acc[4 * j2 + 1] += p * v4.y;
        acc[4 * j2 + 2] += p * v4.z; acc[4 * j2 + 3] += p * v4.w;
      }
    }
  }
  const float inv_l = 1.0f / l_run;
  float* op = out + (size_t)(qb + tq) * HDM + h * 64 + ts * 16;
  unsigned short* ob = outb + (size_t)(qb + tq) * HDM + h * 64 + ts * 16;
#pragma unroll
  for (int j2 = 0; j2 < 4; j2++) {
    float4 o;
    o.x = acc[4 * j2 + 0] * inv_l; o.y = acc[4 * j2 + 1] * inv_l;
    o.z = acc[4 * j2 + 2] * inv_l; o.w = acc[4 * j2 + 3] * inv_l;
    *(float4*)(op + 4 * j2) = o;
    ob[4 * j2 + 0] = f2bf(o.x); ob[4 * j2 + 1] = f2bf(o.y);
    ob[4 * j2 + 2] = f2bf(o.z); ob[4 * j2 + 3] = f2bf(o.w);
  }
}

// ================= x = LN(x + a); emits fp32 x and bf16 xb =================
__global__ __launch_bounds__(256) void ln_residual(float* __restrict__ x,
                                                   const float* __restrict__ a,
                                                   const float* __restrict__ g,
                                                   const float* __restrict__ b,
                                                   unsigned short* __restrict__ xb) {
  const int lane = threadIdx.x & 63;
  const int row = blockIdx.x * 4 + (threadIdx.x >> 6);
  float v[4];
  float s = 0.0f;
#pragma unroll
  for (int j = 0; j < 4; j++) {
    const int col = j * 64 + lane;
    v[j] = x[(size_t)row * HDM + col] + a[(size_t)row * HDM + col];
    s += v[j];
  }
#pragma unroll
  for (int off = 32; off > 0; off >>= 1) s += __shfl_xor(s, off);
  const float mu = s * (1.0f / HDM);
  float vs = 0.0f;
#pragma unroll
  for (int j = 0; j < 4; j++) {
    const float d = v[j] - mu;
    vs += d * d;
  }
#pragma unroll
  for (int off = 32; off > 0; off >>= 1) vs += __shfl_xor(vs, off);
  const float rinv = 1.0f / sqrtf(vs * (1.0f / HDM) + 1e-5f);
#pragma unroll
  for (int j = 0; j < 4; j++) {
    const int col = j * 64 + lane;
    const float val = g[col] * (v[j] - mu) * rinv + b[col];
    x[(size_t)row * HDM + col] = val;
    xb[(size_t)row * HDM + col] = f2bf(val);
  }
}

// ================= edge predictor (fp32, tiny) =================
template <int ACT>
__global__ __launch_bounds__(256) void gemm_bias(const float* __restrict__ A,
                                                 const float* __restrict__ W,
                                                 const float* __restrict__ bias,
                                                 float* __restrict__ C, int M, int NCo, int K) {
  __shared__ float As[16][65];
  __shared__ float Ws[16][65];
  const int bm = blockIdx.y * 64, bn = blockIdx.x * 64;
  const int tid = threadIdx.x;
  const int tx = tid & 15, ty = tid >> 4;
  const int lr = tid >> 2;
  const int lk = (tid & 3) * 4;
  float acc[4][4] = {{0.0f}};
  for (int k0 = 0; k0 < K; k0 += 16) {
    __syncthreads();
    {
      const float4 a4 = *(const float4*)(A + (size_t)(bm + lr) * K + k0 + lk);
      As[lk + 0][lr] = a4.x; As[lk + 1][lr] = a4.y; As[lk + 2][lr] = a4.z; As[lk + 3][lr] = a4.w;
      const float4 w4 = *(const float4*)(W + (size_t)(bn + lr) * K + k0 + lk);
      Ws[lk + 0][lr] = w4.x; Ws[lk + 1][lr] = w4.y; Ws[lk + 2][lr] = w4.z; Ws[lk + 3][lr] = w4.w;
    }
    __syncthreads();
#pragma unroll
    for (int k = 0; k < 16; k++) {
      const float a0 = As[k][ty * 4 + 0], a1 = As[k][ty * 4 + 1];
      const float a2 = As[k][ty * 4 + 2], a3 = As[k][ty * 4 + 3];
      const float w0 = Ws[k][tx * 4 + 0], w1 = Ws[k][tx * 4 + 1];
      const float w2 = Ws[k][tx * 4 + 2], w3 = Ws[k][tx * 4 + 3];
      acc[0][0] += a0 * w0; acc[0][1] += a0 * w1; acc[0][2] += a0 * w2; acc[0][3] += a0 * w3;
      acc[1][0] += a1 * w0; acc[1][1] += a1 * w1; acc[1][2] += a1 * w2; acc[1][3] += a1 * w3;
      acc[2][0] += a2 * w0; acc[2][1] += a2 * w1; acc[2][2] += a2 * w2; acc[2][3] += a2 * w3;
      acc[3][0] += a3 * w0; acc[3][1] += a3 * w1; acc[3][2] += a3 * w2; acc[3][3] += a3 * w3;
    }
  }
  const float b0 = bias[bn + tx * 4 + 0], b1 = bias[bn + tx * 4 + 1];
  const float b2 = bias[bn + tx * 4 + 2], b3 = bias[bn + tx * 4 + 3];
#pragma unroll
  for (int i = 0; i < 4; i++) {
    float4 o;
    o.x = acc[i][0] + b0; o.y = acc[i][1] + b1; o.z = acc[i][2] + b2; o.w = acc[i][3] + b3;
    if (ACT == 1) {
      o.x = fmaxf(o.x, 0.0f); o.y = fmaxf(o.y, 0.0f);
      o.z = fmaxf(o.z, 0.0f); o.w = fmaxf(o.w, 0.0f);
    }
    *(float4*)(C + (size_t)(bm + ty * 4 + i) * NCo + bn + tx * 4) = o;
  }
}

__global__ void gather_cat(const float* __restrict__ refined, const int* __restrict__ cand,
                           float* __restrict__ hcat) {
  const int c = blockIdx.x;
  const int t = threadIdx.x;  // 512
  const int n0 = cand[2 * c], n1 = cand[2 * c + 1];
  hcat[(size_t)c * 512 + t] = (t < 256) ? refined[(size_t)n0 * HDM + t]
                                        : refined[(size_t)n1 * HDM + (t - 256)];
}

__global__ void ep_final(const float* __restrict__ eph, const float* __restrict__ w2,
                         const float* __restrict__ b2, float* __restrict__ out) {
  const int c = blockIdx.x;
  const int lane = threadIdx.x;  // 64
  float s = 0.0f;
#pragma unroll
  for (int j = 0; j < 4; j++) s += eph[(size_t)c * HDM + j * 64 + lane] * w2[j * 64 + lane];
#pragma unroll
  for (int off = 32; off > 0; off >>= 1) s += __shfl_xor(s, off);
  if (lane == 0) out[c] = 1.0f / (1.0f + __expf(-(s + b2[0])));
}

extern "C" void kernel_launch(void* const* d_in, const int* in_sizes, int n_in,
                              void* d_out, int out_size, void* d_ws, size_t ws_size,
                              hipStream_t stream) {
  (void)in_sizes; (void)n_in; (void)out_size; (void)ws_size;
  const float* nf    = (const float*)d_in[0];
  const int*   edges = (const int*)d_in[1];
  const int*   cand  = (const int*)d_in[2];
  const float* w_ih  = (const float*)d_in[3];
  const float* w_hh  = (const float*)d_in[4];
  const float* b_ih  = (const float*)d_in[5];
  const float* b_hh  = (const float*)d_in[6];
  const float* ain_w = (const float*)d_in[7];
  const float* ain_b = (const float*)d_in[8];
  const float* aout_w = (const float*)d_in[9];
  const float* aout_b = (const float*)d_in[10];
  const float* ln1g = (const float*)d_in[11];
  const float* ln1b = (const float*)d_in[12];
  const float* f1w  = (const float*)d_in[13];
  const float* f1b  = (const float*)d_in[14];
  const float* f2w  = (const float*)d_in[15];
  const float* f2b  = (const float*)d_in[16];
  const float* ln2g = (const float*)d_in[17];
  const float* ln2b = (const float*)d_in[18];
  const float* s1w  = (const float*)d_in[19];
  const float* s1b  = (const float*)d_in[20];
  const float* s2w  = (const float*)d_in[21];
  const float* s2b  = (const float*)d_in[22];
  const float* e1w  = (const float*)d_in[23];
  const float* e1b  = (const float*)d_in[24];
  const float* e2w  = (const float*)d_in[25];
  const float* e2b  = (const float*)d_in[26];
  float* out = (float*)d_out;

  char* wp = (char*)d_ws;
  float* x        = (float*)wp; wp += (size_t)NN * HDM * 4;          // 4 MB
  unsigned short* xb = (unsigned short*)wp; wp += (size_t)NN * HDM * 2;  // 2 MB
  unsigned short* wseg = (unsigned short*)wp; wp += (size_t)CVT_TOT * 2; // 4.65 MB
  int* cnt        = (int*)wp;  wp += (size_t)NN * 4;
  int* lists      = (int*)wp;  wp += (size_t)NN * MAXD * 4;          // 1 MB
  int* meta       = (int*)wp;  wp += 256 * 4;
  int* perm       = (int*)wp;  wp += (size_t)NN * 4;
  char* uni       = wp;        // union: gi (50.3 MB) OR transformer buffers
  unsigned short* gi = (unsigned short*)uni;                          // [E][768] bf16
  float* qkv     = (float*)uni;                                       // 12 MB
  float* abuf    = (float*)(uni + 12582912);                          // 4 MB
  unsigned short* abuf_b = (unsigned short*)(uni + 16777216);         // 2 MB
  float* fbuf    = (float*)(uni + 18874368);                          // 16 MB
  unsigned short* fbuf_b = (unsigned short*)(uni + 35651584);         // 8 MB
  float* refined = (float*)(uni + 44040192);                          // 4 MB
  float* hcat    = (float*)(uni + 48234496);
  float* eph     = (float*)(uni + 48365568);

  // packed bf16 weight segments
  unsigned short* nf_b  = wseg;
  unsigned short* wihb  = wseg + 524288;
  unsigned short* ainb  = wseg + 622592;
  unsigned short* aoutb = wseg + 1015808;
  unsigned short* f1b_  = wseg + 1146880;
  unsigned short* f2b_  = wseg + 1671168;
  unsigned short* s1b_  = wseg + 2195456;
  unsigned short* s2b_  = wseg + 2260992;

  int* hist   = meta;
  int* cursor = meta + 128;

  hipMemsetAsync(cnt, 0, (size_t)NN * 4, stream);
  hipMemsetAsync(meta, 0, 256 * 4, stream);

  cvt_weights<<<2272, 256, 0, stream>>>(nf, w_ih, ain_w, aout_w, f1w, f2w, s1w, s2w, wseg);
  build_pos<<<NE / 256, 256, 0, stream>>>(edges, cnt, lists);
  sort_hist<<<NN / 256, 256, 0, stream>>>(cnt, lists, hist);
  scan_prep<<<1, 128, 0, stream>>>(hist, cursor);
  perm_scatter<<<NN / 256, 256, 0, stream>>>(cnt, cursor, perm);

  // gi[e] = bf16( nf[edges[e,0]] @ w_ih^T + b_ih )   [E,768], K=128
  gemm_bf16<0, 2, 2><<<dim3(12, NE / 64), 256, 0, stream>>>(
      nf_b, edges, wihb, b_ih, nullptr, gi, NE, 768, IND);
  gru_reg<<<NN / GNPB, 256, 0, stream>>>(perm, cnt, lists, gi, w_hh, b_hh, x, xb);

  for (int l = 0; l < NL; l++) {
    gemm_bf16<0, 0, 0><<<dim3(12, 64), 256, 0, stream>>>(
        xb, nullptr, ainb + (size_t)l * 196608, ain_b + l * 768, qkv, nullptr, NN, 768, HDM);
    flash_attn<<<dim3(64, 4), 256, 0, stream>>>(qkv, abuf, abuf_b);
    gemm_bf16<0, 0, 0><<<dim3(4, 64), 256, 0, stream>>>(
        abuf_b, nullptr, aoutb + (size_t)l * 65536, aout_b + l * 256, fbuf, nullptr, NN, 256, HDM);
    ln_residual<<<NN / 4, 256, 0, stream>>>(x, fbuf, ln1g + l * 256, ln1b + l * 256, xb);
    gemm_bf16<1, 0, 1><<<dim3(16, 64), 256, 0, stream>>>(
        xb, nullptr, f1b_ + (size_t)l * 262144, f1b + l * 1024, fbuf, fbuf_b, NN, 1024, HDM);
    gemm_bf16<0, 0, 0><<<dim3(4, 64), 256, 0, stream>>>(
        fbuf_b, nullptr, f2b_ + (size_t)l * 262144, f2b + l * 256, abuf, nullptr, NN, 256, 1024);
    ln_residual<<<NN / 4, 256, 0, stream>>>(x, abuf, ln2g + l * 256, ln2b + l * 256, xb);
  }

  gemm_bf16<1, 0, 1><<<dim3(4, 64), 256, 0, stream>>>(
      xb, nullptr, s1b_, s1b, abuf, abuf_b, NN, 256, HDM);
  gemm_bf16<0, 0, 0><<<dim3(4, 64), 256, 0, stream>>>(
      abuf_b, nullptr, s2b_, s2b, refined, nullptr, NN, 256, HDM);
  gather_cat<<<NCAND, 512, 0, stream>>>(refined, cand, hcat);
  gemm_bias<1><<<dim3(4, 1), 256, 0, stream>>>(hcat, e1w, e1b, eph, NCAND, 256, 512);
  ep_final<<<NCAND, 64, 0, stream>>>(eph, e2w, e2b, out);
}

// Round 4
// 605.679 us; speedup vs baseline: 8.9505x; 2.5401x over previous
//
#include <hip/hip_runtime.h>
#include <math.h>

#define NN     4096
#define NE     32768
#define NCAND  64
#define IND    128
#define HDM    256
#define NL     2
#define MAXD   64
#define GNPB   16   // GRU nodes per block

typedef __attribute__((ext_vector_type(8))) short short8;
typedef __attribute__((ext_vector_type(4))) float f32x4;

__device__ __forceinline__ float sigf(float x) { return 1.0f / (1.0f + __expf(-x)); }
__device__ __forceinline__ float tanh_fast(float x) {
  float e = __expf(-2.0f * fabsf(x));
  float r = (1.0f - e) / (1.0f + e);
  return x < 0.0f ? -r : r;
}
__device__ __forceinline__ unsigned short f2bf(float f) {
  unsigned int x = __float_as_uint(f);
  x += 0x7fffu + ((x >> 16) & 1u);   // RNE
  return (unsigned short)(x >> 16);
}
__device__ __forceinline__ float bf2f(unsigned short u) {
  return __uint_as_float(((unsigned int)u) << 16);
}

// ================= weight/feature fp32->bf16 conversion (one launch) =================
#define CVT_TOT 2326528
__global__ __launch_bounds__(256) void cvt_weights(
    const float* __restrict__ nf, const float* __restrict__ wih,
    const float* __restrict__ ain, const float* __restrict__ aout,
    const float* __restrict__ f1, const float* __restrict__ f2,
    const float* __restrict__ s1, const float* __restrict__ s2,
    unsigned short* __restrict__ dst) {
  const size_t e = ((size_t)blockIdx.x * 256 + threadIdx.x) * 4;
  if (e >= CVT_TOT) return;
  const float* src;
  if (e < 524288)       src = nf   + e;
  else if (e < 622592)  src = wih  + (e - 524288);
  else if (e < 1015808) src = ain  + (e - 622592);
  else if (e < 1146880) src = aout + (e - 1015808);
  else if (e < 1671168) src = f1   + (e - 1146880);
  else if (e < 2195456) src = f2   + (e - 1671168);
  else if (e < 2260992) src = s1   + (e - 2195456);
  else                  src = s2   + (e - 2260992);
  const float4 v = *(const float4*)src;
  dst[e + 0] = f2bf(v.x); dst[e + 1] = f2bf(v.y);
  dst[e + 2] = f2bf(v.z); dst[e + 3] = f2bf(v.w);
}

// ================= GRU preprocessing =================
__global__ __launch_bounds__(256) void build_pos(const int* __restrict__ edges,
                                                 int* __restrict__ cnt, int* __restrict__ lists) {
  const int e = blockIdx.x * 256 + threadIdx.x;
  const int d = edges[2 * e + 1];
  const int slot = atomicAdd(&cnt[d], 1);
  if (slot < MAXD) lists[(size_t)d * MAXD + slot] = e;
}

__global__ __launch_bounds__(256) void sort_hist(int* __restrict__ cnt, int* __restrict__ lists,
                                                 int* __restrict__ hist) {
  const int d = blockIdx.x * 256 + threadIdx.x;
  int c = cnt[d]; if (c > MAXD) c = MAXD; cnt[d] = c;
  int* L = lists + (size_t)d * MAXD;
  for (int i = 1; i < c; ++i) {
    const int key = L[i];
    int j = i - 1;
    while (j >= 0 && L[j] > key) { L[j + 1] = L[j]; --j; }
    L[j + 1] = key;
  }
  atomicAdd(&hist[c], 1);
}

__global__ void scan_prep(const int* __restrict__ hist, int* __restrict__ cursor) {
  const int t = threadIdx.x;  // 128
  if (t <= MAXD) {
    int ss = 0;
    for (int dd = t + 1; dd <= MAXD; ++dd) ss += hist[dd];
    cursor[t] = ss;
  }
}

__global__ __launch_bounds__(256) void perm_scatter(const int* __restrict__ cnt,
                                                    int* __restrict__ cursor, int* __restrict__ perm) {
  const int d = blockIdx.x * 256 + threadIdx.x;
  const int rank = atomicAdd(&cursor[cnt[d]], 1);
  perm[rank] = d;
}

// ================= generic bf16 MFMA GEMM =================
// C[M,N] = act(A[M,K] @ W[N,K]^T + bias); 64x64 tile, 256 thr, 4 waves (2m x 2n of 32x32)
// GS: A-row gather stride. OMODE: 0 fp32, 1 fp32+bf16, 2 bf16 only.
template <int ACT, int GS, int OMODE>
__global__ __launch_bounds__(256) void gemm_bf16(
    const unsigned short* __restrict__ A, const int* __restrict__ gidx,
    const unsigned short* __restrict__ W, const float* __restrict__ bias,
    float* __restrict__ C, unsigned short* __restrict__ Cb,
    int M, int N, int K) {
  __shared__ unsigned short As[64 * 64];
  __shared__ unsigned short Ws[64 * 64];
  __shared__ int ridx[64];
  const int bm = blockIdx.y * 64, bn = blockIdx.x * 64;
  const int tid = threadIdx.x;
  const int ln = tid & 63, w = tid >> 6;
  const int jc = ln & 15, kq = ln >> 4;
  const int srow = tid >> 2, q = tid & 3;

  if constexpr (GS > 0) {
    if (tid < 64) ridx[tid] = gidx[(size_t)(bm + tid) * GS];
    __syncthreads();
  }
  const size_t arow = (GS > 0) ? (size_t)ridx[srow] : (size_t)(bm + srow);
  const unsigned short* Asrc = A + arow * K + q * 16;
  const unsigned short* Wsrc = W + (size_t)(bn + srow) * K + q * 16;

  f32x4 acc[2][2];
#pragma unroll
  for (int i = 0; i < 2; ++i)
#pragma unroll
    for (int j = 0; j < 2; ++j) acc[i][j] = (f32x4){0.f, 0.f, 0.f, 0.f};
  const int mrow = (w >> 1) * 32, ncol = (w & 1) * 32;
  const int sb0 = (q * 32) ^ ((srow & 7) << 4);
  const int sb1 = (q * 32 + 16) ^ ((srow & 7) << 4);

  for (int k0 = 0; k0 < K; k0 += 64) {
    __syncthreads();
    {
      const short8 a0 = *(const short8*)(Asrc + k0);
      const short8 a1 = *(const short8*)(Asrc + k0 + 8);
      const short8 w0 = *(const short8*)(Wsrc + k0);
      const short8 w1 = *(const short8*)(Wsrc + k0 + 8);
      *(short8*)((char*)As + srow * 128 + sb0) = a0;
      *(short8*)((char*)As + srow * 128 + sb1) = a1;
      *(short8*)((char*)Ws + srow * 128 + sb0) = w0;
      *(short8*)((char*)Ws + srow * 128 + sb1) = w1;
    }
    __syncthreads();
#pragma unroll
    for (int kt = 0; kt < 2; ++kt) {
      const int kb = kt * 64 + kq * 16;
      short8 a[2], bb[2];
#pragma unroll
      for (int i = 0; i < 2; ++i) {
        const int ra = mrow + i * 16 + jc;
        a[i] = *(const short8*)((const char*)As + ra * 128 + (kb ^ ((ra & 7) << 4)));
        const int rb = ncol + i * 16 + jc;
        bb[i] = *(const short8*)((const char*)Ws + rb * 128 + (kb ^ ((rb & 7) << 4)));
      }
#pragma unroll
      for (int mi = 0; mi < 2; ++mi)
#pragma unroll
        for (int ni = 0; ni < 2; ++ni)
          acc[mi][ni] = __builtin_amdgcn_mfma_f32_16x16x32_bf16(a[mi], bb[ni], acc[mi][ni], 0, 0, 0);
    }
  }
#pragma unroll
  for (int mi = 0; mi < 2; ++mi)
#pragma unroll
    for (int ni = 0; ni < 2; ++ni) {
      const int col = bn + ncol + ni * 16 + jc;
      const float bs = bias[col];
#pragma unroll
      for (int v = 0; v < 4; ++v) {
        const int row = bm + mrow + mi * 16 + kq * 4 + v;
        float val = acc[mi][ni][v] + bs;
        if (ACT == 1) val = fmaxf(val, 0.0f);
        if constexpr (OMODE != 2) C[(size_t)row * N + col] = val;
        if constexpr (OMODE >= 1) Cb[(size_t)row * N + col] = f2bf(val);
      }
    }
}

// ================= per-block independent GRU (no grid sync) =================
__global__ __launch_bounds__(256, 1) void gru_reg(
    const int* __restrict__ perm, const int* __restrict__ cnt,
    const int* __restrict__ lists, const unsigned short* __restrict__ gi,
    const float* __restrict__ w_hh, const float* __restrict__ b_hh,
    float* __restrict__ x, unsigned short* __restrict__ xb) {
  const int tid = threadIdx.x;
  const int ln = tid & 63;
  const int w = tid >> 6;
  const int jc = ln & 15;
  const int kq = ln >> 4;
  const int grow = tid >> 4;
  const int gpart = tid & 15;

  __shared__ float h[GNPB][260];
  __shared__ unsigned short Ah[GNPB * 256];
  __shared__ unsigned short Gi[GNPB * 776];
  __shared__ int lists_s[GNPB][MAXD];
  __shared__ int node_s[GNPB], cnt_s[GNPB], e_s[GNPB];
  __shared__ int Rb_s;

  if (tid < GNPB) {
    const int node = perm[blockIdx.x * GNPB + tid];
    node_s[tid] = node;
    cnt_s[tid] = cnt[node];
  }
  for (int i = tid; i < GNPB * 260; i += 256) ((float*)h)[i] = 0.0f;
  __syncthreads();
  for (int i = tid; i < GNPB * MAXD; i += 256)
    lists_s[i >> 6][i & 63] = lists[(size_t)node_s[i >> 6] * MAXD + (i & 63)];
  if (tid == 0) {
    int mx = 0;
    for (int i = 0; i < GNPB; ++i) mx = mx > cnt_s[i] ? mx : cnt_s[i];
    Rb_s = mx;
  }

  short8 W[96];
#pragma unroll
  for (int g = 0; g < 3; ++g)
#pragma unroll
    for (int ct = 0; ct < 4; ++ct) {
      const int nrow = g * 256 + w * 64 + ct * 16 + jc;
      const float* src = w_hh + (size_t)nrow * 256 + kq * 8;
#pragma unroll
      for (int kt = 0; kt < 8; ++kt) {
        const float* s8 = src + kt * 32;
        short8 v;
#pragma unroll
        for (int j = 0; j < 8; ++j) v[j] = (short)f2bf(s8[j]);
        W[(g * 4 + ct) * 8 + kt] = v;
      }
    }
  float bh[12];
#pragma unroll
  for (int g = 0; g < 3; ++g)
#pragma unroll
    for (int ct = 0; ct < 4; ++ct)
      bh[g * 4 + ct] = b_hh[g * 256 + w * 64 + ct * 16 + jc];
  __syncthreads();
  const int Rb = Rb_s;

  for (int r = 0; r < Rb; ++r) {
    if (tid < GNPB) e_s[tid] = (r < cnt_s[tid]) ? lists_s[tid][r] : -1;
    __syncthreads();
    short8 gv[6];
    const int ge = e_s[grow];
    if (ge >= 0) {
      const unsigned short* gsrc = gi + (size_t)ge * 768 + gpart * 48;
#pragma unroll
      for (int c = 0; c < 6; ++c) gv[c] = *(const short8*)(gsrc + c * 8);
    }
    {
      const float* hr = &h[grow][gpart * 16];
#pragma unroll
      for (int c = 0; c < 2; ++c) {
        short8 v;
#pragma unroll
        for (int j = 0; j < 8; ++j) v[j] = (short)f2bf(hr[c * 8 + j]);
        *(short8*)((char*)Ah + grow * 512 + ((gpart * 32 + c * 16) ^ ((grow & 7) << 4))) = v;
      }
    }
    __syncthreads();
    f32x4 acc[12];
#pragma unroll
    for (int i = 0; i < 12; ++i) acc[i] = (f32x4){0.f, 0.f, 0.f, 0.f};
#pragma unroll
    for (int kt = 0; kt < 8; ++kt) {
      const short8 a = *(const short8*)((const char*)Ah + jc * 512 + ((kt * 64 + kq * 16) ^ ((jc & 7) << 4)));
#pragma unroll
      for (int i = 0; i < 12; ++i)
        acc[i] = __builtin_amdgcn_mfma_f32_16x16x32_bf16(a, W[i * 8 + kt], acc[i], 0, 0, 0);
    }
    if (ge >= 0) {
      unsigned short* gdst = Gi + grow * 776 + gpart * 48;
#pragma unroll
      for (int c = 0; c < 6; ++c) *(short8*)(gdst + c * 8) = gv[c];
    }
    __syncthreads();
#pragma unroll
    for (int ct = 0; ct < 4; ++ct) {
      const int colg = w * 64 + ct * 16 + jc;
#pragma unroll
      for (int v = 0; v < 4; ++v) {
        const int node = kq * 4 + v;
        if (r < cnt_s[node]) {
          const float giR = bf2f(Gi[node * 776 + colg]);
          const float giZ = bf2f(Gi[node * 776 + 256 + colg]);
          const float giN = bf2f(Gi[node * 776 + 512 + colg]);
          const float rr = sigf(giR + acc[ct][v] + bh[ct]);
          const float zz = sigf(giZ + acc[4 + ct][v] + bh[4 + ct]);
          const float nn2 = tanh_fast(giN + rr * (acc[8 + ct][v] + bh[8 + ct]));
          h[node][colg] = (1.0f - zz) * nn2 + zz * h[node][colg];
        }
      }
    }
    __syncthreads();
  }
  {
    const float* hr = &h[grow][gpart * 16];
    float* xd = x + (size_t)node_s[grow] * HDM + gpart * 16;
    unsigned short* xbd = xb + (size_t)node_s[grow] * HDM + gpart * 16;
#pragma unroll
    for (int c = 0; c < 4; ++c) *(float4*)(xd + c * 4) = *(const float4*)(hr + c * 4);
#pragma unroll
    for (int c = 0; c < 2; ++c) {
      short8 v;
#pragma unroll
      for (int j = 0; j < 8; ++j) v[j] = (short)f2bf(hr[c * 8 + j]);
      *(short8*)(xbd + c * 8) = v;
    }
  }
}

// ================= V transpose: vtb[h*64+d][n] = qkvb[n][512+h*64+d] =================
__global__ __launch_bounds__(256) void transpose_v(const unsigned short* __restrict__ qkvb,
                                                   unsigned short* __restrict__ vtb) {
  const int h = blockIdx.y, nt = blockIdx.x;
  __shared__ unsigned short T[64][72];
  const int t = threadIdx.x;
  const int r = t >> 2, c = (t & 3) << 4;
  {
    const unsigned short* src = qkvb + (size_t)(nt * 64 + r) * 768 + 512 + h * 64 + c;
    *(short8*)&T[r][c] = *(const short8*)src;
    *(short8*)&T[r][c + 8] = *(const short8*)(src + 8);
  }
  __syncthreads();
  {
    short8 o0, o1;
#pragma unroll
    for (int j = 0; j < 8; ++j) { o0[j] = (short)T[c + j][r]; o1[j] = (short)T[c + 8 + j][r]; }
    unsigned short* dst = vtb + (size_t)(h * 64 + r) * 4096 + nt * 64 + c;
    *(short8*)dst = o0;
    *(short8*)(dst + 8) = o1;
  }
}

// ================= bf16 MFMA flash attention =================
// grid (64 qblocks, 4 heads), 256 thr = 4 waves x 16 q-rows. 64-key tiles.
__global__ __launch_bounds__(256) void flash_mfma(const unsigned short* __restrict__ qkvb,
                                                  const unsigned short* __restrict__ vtb,
                                                  unsigned short* __restrict__ outb) {
  const int h = blockIdx.y;
  const int qb = blockIdx.x * 64;
  const int tid = threadIdx.x;
  const int ln = tid & 63, w = tid >> 6;
  const int jc = ln & 15, kq = ln >> 4;
  __shared__ unsigned short Ks[64 * 64];   // [key][d] swz
  __shared__ unsigned short Vts[64 * 64];  // [d][key] swz
  __shared__ unsigned short Ps[64 * 64];   // [q][key] swz

  short8 aq[2];
  {
    const unsigned short* qsrc = qkvb + (size_t)(qb + w * 16 + jc) * 768 + h * 64 + kq * 8;
    aq[0] = *(const short8*)qsrc;
    aq[1] = *(const short8*)(qsrc + 32);
  }
  float m_run[4] = {-1e30f, -1e30f, -1e30f, -1e30f};
  float l_run[4] = {0.f, 0.f, 0.f, 0.f};
  f32x4 accO[4];
#pragma unroll
  for (int nf = 0; nf < 4; ++nf) accO[nf] = (f32x4){0.f, 0.f, 0.f, 0.f};

  const int srow = tid >> 2, sc = tid & 3;
  const int swb0 = (sc * 32) ^ ((srow & 7) << 4);
  const int swb1 = (sc * 32 + 16) ^ ((srow & 7) << 4);

  short8 kr0, kr1, vr0, vr1;
  {
    const unsigned short* ksrc = qkvb + (size_t)srow * 768 + 256 + h * 64 + sc * 16;
    kr0 = *(const short8*)ksrc; kr1 = *(const short8*)(ksrc + 8);
    const unsigned short* vsrc = vtb + (size_t)(h * 64 + srow) * 4096 + sc * 16;
    vr0 = *(const short8*)vsrc; vr1 = *(const short8*)(vsrc + 8);
  }

  for (int kb = 0; kb < 64; ++kb) {
    *(short8*)((char*)Ks + srow * 128 + swb0) = kr0;
    *(short8*)((char*)Ks + srow * 128 + swb1) = kr1;
    *(short8*)((char*)Vts + srow * 128 + swb0) = vr0;
    *(short8*)((char*)Vts + srow * 128 + swb1) = vr1;
    if (kb < 63) {
      const unsigned short* ksrc = qkvb + (size_t)((kb + 1) * 64 + srow) * 768 + 256 + h * 64 + sc * 16;
      kr0 = *(const short8*)ksrc; kr1 = *(const short8*)(ksrc + 8);
      const unsigned short* vsrc = vtb + (size_t)(h * 64 + srow) * 4096 + (kb + 1) * 64 + sc * 16;
      vr0 = *(const short8*)vsrc; vr1 = *(const short8*)(vsrc + 8);
    }
    __syncthreads();
    // ---- S = Q @ K^T ----
    f32x4 s[4];
#pragma unroll
    for (int kt = 0; kt < 4; ++kt) s[kt] = (f32x4){0.f, 0.f, 0.f, 0.f};
#pragma unroll
    for (int ks = 0; ks < 2; ++ks) {
#pragma unroll
      for (int kt = 0; kt < 4; ++kt) {
        const int brow = kt * 16 + jc;
        const short8 bk = *(const short8*)((const char*)Ks + brow * 128 + ((ks * 64 + kq * 16) ^ ((brow & 7) << 4)));
        s[kt] = __builtin_amdgcn_mfma_f32_16x16x32_bf16(aq[ks], bk, s[kt], 0, 0, 0);
      }
    }
    // ---- online softmax (rows = kq*4+v, cols = kt*16+jc) ----
    float mt[4], alpha[4], psum[4];
#pragma unroll
    for (int v = 0; v < 4; ++v) {
      float m0 = fmaxf(fmaxf(s[0][v], s[1][v]), fmaxf(s[2][v], s[3][v])) * 0.125f;
      m0 = fmaxf(m0, __shfl_xor(m0, 1));
      m0 = fmaxf(m0, __shfl_xor(m0, 2));
      m0 = fmaxf(m0, __shfl_xor(m0, 4));
      m0 = fmaxf(m0, __shfl_xor(m0, 8));
      const float mnew = fmaxf(m_run[v], m0);
      alpha[v] = __expf(m_run[v] - mnew);
      m_run[v] = mnew;
      psum[v] = 0.f;
      mt[v] = mnew;
    }
    const int prowb = w * 16 + kq * 4;
#pragma unroll
    for (int kt = 0; kt < 4; ++kt) {
#pragma unroll
      for (int v = 0; v < 4; ++v) {
        const float pv = __expf(s[kt][v] * 0.125f - mt[v]);
        psum[v] += pv;
        const int prow = prowb + v;
        const int cb = kt * 32 + jc * 2;
        const int sbyte = (cb & 15) | ((cb & 112) ^ ((prow & 7) << 4));
        *(unsigned short*)((char*)Ps + prow * 128 + sbyte) = f2bf(pv);
      }
    }
#pragma unroll
    for (int v = 0; v < 4; ++v) {
      float ps = psum[v];
      ps += __shfl_xor(ps, 1);
      ps += __shfl_xor(ps, 2);
      ps += __shfl_xor(ps, 4);
      ps += __shfl_xor(ps, 8);
      l_run[v] = l_run[v] * alpha[v] + ps;
#pragma unroll
      for (int nf = 0; nf < 4; ++nf) accO[nf][v] *= alpha[v];
    }
    __syncthreads();
    // ---- O += P @ V ----
    const int arow = w * 16 + jc;
#pragma unroll
    for (int ks = 0; ks < 2; ++ks) {
      const short8 ap = *(const short8*)((const char*)Ps + arow * 128 + ((ks * 64 + kq * 16) ^ ((arow & 7) << 4)));
#pragma unroll
      for (int nf = 0; nf < 4; ++nf) {
        const int brow = nf * 16 + jc;
        const short8 bv = *(const short8*)((const char*)Vts + brow * 128 + ((ks * 64 + kq * 16) ^ ((brow & 7) << 4)));
        accO[nf] = __builtin_amdgcn_mfma_f32_16x16x32_bf16(ap, bv, accO[nf], 0, 0, 0);
      }
    }
    __syncthreads();
  }
  float invl[4];
#pragma unroll
  for (int v = 0; v < 4; ++v) invl[v] = 1.0f / l_run[v];
#pragma unroll
  for (int nf = 0; nf < 4; ++nf)
#pragma unroll
    for (int v = 0; v < 4; ++v)
      outb[(size_t)(qb + w * 16 + kq * 4 + v) * HDM + h * 64 + nf * 16 + jc] =
          f2bf(accO[nf][v] * invl[v]);
}

// ================= x = LN(x + a); emits fp32 x and bf16 xb =================
__global__ __launch_bounds__(256) void ln_residual(float* __restrict__ x,
                                                   const float* __restrict__ a,
                                                   const float* __restrict__ g,
                                                   const float* __restrict__ b,
                                                   unsigned short* __restrict__ xb) {
  const int lane = threadIdx.x & 63;
  const int row = blockIdx.x * 4 + (threadIdx.x >> 6);
  float v[4];
  float s = 0.0f;
#pragma unroll
  for (int j = 0; j < 4; j++) {
    const int col = j * 64 + lane;
    v[j] = x[(size_t)row * HDM + col] + a[(size_t)row * HDM + col];
    s += v[j];
  }
#pragma unroll
  for (int off = 32; off > 0; off >>= 1) s += __shfl_xor(s, off);
  const float mu = s * (1.0f / HDM);
  float vs = 0.0f;
#pragma unroll
  for (int j = 0; j < 4; j++) {
    const float d = v[j] - mu;
    vs += d * d;
  }
#pragma unroll
  for (int off = 32; off > 0; off >>= 1) vs += __shfl_xor(vs, off);
  const float rinv = 1.0f / sqrtf(vs * (1.0f / HDM) + 1e-5f);
#pragma unroll
  for (int j = 0; j < 4; j++) {
    const int col = j * 64 + lane;
    const float val = g[col] * (v[j] - mu) * rinv + b[col];
    x[(size_t)row * HDM + col] = val;
    xb[(size_t)row * HDM + col] = f2bf(val);
  }
}

// ================= edge predictor (fp32, tiny) =================
template <int ACT>
__global__ __launch_bounds__(256) void gemm_bias(const float* __restrict__ A,
                                                 const float* __restrict__ W,
                                                 const float* __restrict__ bias,
                                                 float* __restrict__ C, int M, int NCo, int K) {
  __shared__ float As[16][65];
  __shared__ float Ws[16][65];
  const int bm = blockIdx.y * 64, bn = blockIdx.x * 64;
  const int tid = threadIdx.x;
  const int tx = tid & 15, ty = tid >> 4;
  const int lr = tid >> 2;
  const int lk = (tid & 3) * 4;
  float acc[4][4] = {{0.0f}};
  for (int k0 = 0; k0 < K; k0 += 16) {
    __syncthreads();
    {
      const float4 a4 = *(const float4*)(A + (size_t)(bm + lr) * K + k0 + lk);
      As[lk + 0][lr] = a4.x; As[lk + 1][lr] = a4.y; As[lk + 2][lr] = a4.z; As[lk + 3][lr] = a4.w;
      const float4 w4 = *(const float4*)(W + (size_t)(bn + lr) * K + k0 + lk);
      Ws[lk + 0][lr] = w4.x; Ws[lk + 1][lr] = w4.y; Ws[lk + 2][lr] = w4.z; Ws[lk + 3][lr] = w4.w;
    }
    __syncthreads();
#pragma unroll
    for (int k = 0; k < 16; k++) {
      const float a0 = As[k][ty * 4 + 0], a1 = As[k][ty * 4 + 1];
      const float a2 = As[k][ty * 4 + 2], a3 = As[k][ty * 4 + 3];
      const float w0 = Ws[k][tx * 4 + 0], w1 = Ws[k][tx * 4 + 1];
      const float w2 = Ws[k][tx * 4 + 2], w3 = Ws[k][tx * 4 + 3];
      acc[0][0] += a0 * w0; acc[0][1] += a0 * w1; acc[0][2] += a0 * w2; acc[0][3] += a0 * w3;
      acc[1][0] += a1 * w0; acc[1][1] += a1 * w1; acc[1][2] += a1 * w2; acc[1][3] += a1 * w3;
      acc[2][0] += a2 * w0; acc[2][1] += a2 * w1; acc[2][2] += a2 * w2; acc[2][3] += a2 * w3;
      acc[3][0] += a3 * w0; acc[3][1] += a3 * w1; acc[3][2] += a3 * w2; acc[3][3] += a3 * w3;
    }
  }
  const float b0 = bias[bn + tx * 4 + 0], b1 = bias[bn + tx * 4 + 1];
  const float b2 = bias[bn + tx * 4 + 2], b3 = bias[bn + tx * 4 + 3];
#pragma unroll
  for (int i = 0; i < 4; i++) {
    float4 o;
    o.x = acc[i][0] + b0; o.y = acc[i][1] + b1; o.z = acc[i][2] + b2; o.w = acc[i][3] + b3;
    if (ACT == 1) {
      o.x = fmaxf(o.x, 0.0f); o.y = fmaxf(o.y, 0.0f);
      o.z = fmaxf(o.z, 0.0f); o.w = fmaxf(o.w, 0.0f);
    }
    *(float4*)(C + (size_t)(bm + ty * 4 + i) * NCo + bn + tx * 4) = o;
  }
}

__global__ void gather_cat(const float* __restrict__ refined, const int* __restrict__ cand,
                           float* __restrict__ hcat) {
  const int c = blockIdx.x;
  const int t = threadIdx.x;  // 512
  const int n0 = cand[2 * c], n1 = cand[2 * c + 1];
  hcat[(size_t)c * 512 + t] = (t < 256) ? refined[(size_t)n0 * HDM + t]
                                        : refined[(size_t)n1 * HDM + (t - 256)];
}

__global__ void ep_final(const float* __restrict__ eph, const float* __restrict__ w2,
                         const float* __restrict__ b2, float* __restrict__ out) {
  const int c = blockIdx.x;
  const int lane = threadIdx.x;  // 64
  float s = 0.0f;
#pragma unroll
  for (int j = 0; j < 4; j++) s += eph[(size_t)c * HDM + j * 64 + lane] * w2[j * 64 + lane];
#pragma unroll
  for (int off = 32; off > 0; off >>= 1) s += __shfl_xor(s, off);
  if (lane == 0) out[c] = 1.0f / (1.0f + __expf(-(s + b2[0])));
}

extern "C" void kernel_launch(void* const* d_in, const int* in_sizes, int n_in,
                              void* d_out, int out_size, void* d_ws, size_t ws_size,
                              hipStream_t stream) {
  (void)in_sizes; (void)n_in; (void)out_size; (void)ws_size;
  const float* nf    = (const float*)d_in[0];
  const int*   edges = (const int*)d_in[1];
  const int*   cand  = (const int*)d_in[2];
  const float* w_ih  = (const float*)d_in[3];
  const float* w_hh  = (const float*)d_in[4];
  const float* b_ih  = (const float*)d_in[5];
  const float* b_hh  = (const float*)d_in[6];
  const float* ain_w = (const float*)d_in[7];
  const float* ain_b = (const float*)d_in[8];
  const float* aout_w = (const float*)d_in[9];
  const float* aout_b = (const float*)d_in[10];
  const float* ln1g = (const float*)d_in[11];
  const float* ln1b = (const float*)d_in[12];
  const float* f1w  = (const float*)d_in[13];
  const float* f1b  = (const float*)d_in[14];
  const float* f2w  = (const float*)d_in[15];
  const float* f2b  = (const float*)d_in[16];
  const float* ln2g = (const float*)d_in[17];
  const float* ln2b = (const float*)d_in[18];
  const float* s1w  = (const float*)d_in[19];
  const float* s1b  = (const float*)d_in[20];
  const float* s2w  = (const float*)d_in[21];
  const float* s2b  = (const float*)d_in[22];
  const float* e1w  = (const float*)d_in[23];
  const float* e1b  = (const float*)d_in[24];
  const float* e2w  = (const float*)d_in[25];
  const float* e2b  = (const float*)d_in[26];
  float* out = (float*)d_out;

  char* wp = (char*)d_ws;
  float* x        = (float*)wp; wp += (size_t)NN * HDM * 4;
  unsigned short* xb = (unsigned short*)wp; wp += (size_t)NN * HDM * 2;
  unsigned short* wseg = (unsigned short*)wp; wp += (size_t)CVT_TOT * 2;
  int* cnt        = (int*)wp;  wp += (size_t)NN * 4;
  int* lists      = (int*)wp;  wp += (size_t)NN * MAXD * 4;
  int* meta       = (int*)wp;  wp += 256 * 4;
  int* perm       = (int*)wp;  wp += (size_t)NN * 4;
  char* uni       = wp;        // union: gi (50.3 MB) OR transformer buffers
  unsigned short* gi = (unsigned short*)uni;
  unsigned short* qkvb   = (unsigned short*)uni;                      // 6 MB
  unsigned short* vtb    = (unsigned short*)(uni + 6291456);          // 2 MB
  float* abuf    = (float*)(uni + 8388608);                           // 4 MB
  unsigned short* abuf_b = (unsigned short*)(uni + 12582912);         // 2 MB
  float* fbuf    = (float*)(uni + 14680064);                          // 16 MB
  unsigned short* fbuf_b = (unsigned short*)(uni + 31457280);         // 8 MB
  float* refined = (float*)(uni + 39845888);                          // 4 MB
  float* hcat    = (float*)(uni + 44040192);
  float* eph     = (float*)(uni + 44171264);

  unsigned short* nf_b  = wseg;
  unsigned short* wihb  = wseg + 524288;
  unsigned short* ainb  = wseg + 622592;
  unsigned short* aoutb = wseg + 1015808;
  unsigned short* f1b_  = wseg + 1146880;
  unsigned short* f2b_  = wseg + 1671168;
  unsigned short* s1b_  = wseg + 2195456;
  unsigned short* s2b_  = wseg + 2260992;

  int* hist   = meta;
  int* cursor = meta + 128;

  hipMemsetAsync(cnt, 0, (size_t)NN * 4, stream);
  hipMemsetAsync(meta, 0, 256 * 4, stream);

  cvt_weights<<<2272, 256, 0, stream>>>(nf, w_ih, ain_w, aout_w, f1w, f2w, s1w, s2w, wseg);
  build_pos<<<NE / 256, 256, 0, stream>>>(edges, cnt, lists);
  sort_hist<<<NN / 256, 256, 0, stream>>>(cnt, lists, hist);
  scan_prep<<<1, 128, 0, stream>>>(hist, cursor);
  perm_scatter<<<NN / 256, 256, 0, stream>>>(cnt, cursor, perm);

  gemm_bf16<0, 2, 2><<<dim3(12, NE / 64), 256, 0, stream>>>(
      nf_b, edges, wihb, b_ih, nullptr, gi, NE, 768, IND);
  gru_reg<<<NN / GNPB, 256, 0, stream>>>(perm, cnt, lists, gi, w_hh, b_hh, x, xb);

  for (int l = 0; l < NL; l++) {
    gemm_bf16<0, 0, 2><<<dim3(12, 64), 256, 0, stream>>>(
        xb, nullptr, ainb + (size_t)l * 196608, ain_b + l * 768, nullptr, qkvb, NN, 768, HDM);
    transpose_v<<<dim3(64, 4), 256, 0, stream>>>(qkvb, vtb);
    flash_mfma<<<dim3(64, 4), 256, 0, stream>>>(qkvb, vtb, abuf_b);
    gemm_bf16<0, 0, 0><<<dim3(4, 64), 256, 0, stream>>>(
        abuf_b, nullptr, aoutb + (size_t)l * 65536, aout_b + l * 256, fbuf, nullptr, NN, 256, HDM);
    ln_residual<<<NN / 4, 256, 0, stream>>>(x, fbuf, ln1g + l * 256, ln1b + l * 256, xb);
    gemm_bf16<1, 0, 1><<<dim3(16, 64), 256, 0, stream>>>(
        xb, nullptr, f1b_ + (size_t)l * 262144, f1b + l * 1024, fbuf, fbuf_b, NN, 1024, HDM);
    gemm_bf16<0, 0, 0><<<dim3(4, 64), 256, 0, stream>>>(
        fbuf_b, nullptr, f2b_ + (size_t)l * 262144, f2b + l * 256, abuf, nullptr, NN, 256, 1024);
    ln_residual<<<NN / 4, 256, 0, stream>>>(x, abuf, ln2g + l * 256, ln2b + l * 256, xb);
  }

  gemm_bf16<1, 0, 1><<<dim3(4, 64), 256, 0, stream>>>(
      xb, nullptr, s1b_, s1b, abuf, abuf_b, NN, 256, HDM);
  gemm_bf16<0, 0, 0><<<dim3(4, 64), 256, 0, stream>>>(
      abuf_b, nullptr, s2b_, s2b, refined, nullptr, NN, 256, HDM);
  gather_cat<<<NCAND, 512, 0, stream>>>(refined, cand, hcat);
  gemm_bias<1><<<dim3(4, 1), 256, 0, stream>>>(hcat, e1w, e1b, eph, NCAND, 256, 512);
  ep_final<<<NCAND, 64, 0, stream>>>(eph, e2w, e2b, out);
}

// Round 5
// 526.185 us; speedup vs baseline: 10.3027x; 1.1511x over previous
//
#include <hip/hip_runtime.h>
#include <math.h>

#define NN     4096
#define NE     32768
#define NCAND  64
#define IND    128
#define HDM    256
#define NL     2
#define MAXD   64
#define GNPB   16   // GRU nodes per block

typedef __attribute__((ext_vector_type(8))) short short8;
typedef __attribute__((ext_vector_type(4))) float f32x4;

__device__ __forceinline__ float sigf(float x) { return 1.0f / (1.0f + __expf(-x)); }
__device__ __forceinline__ float tanh_fast(float x) {
  float e = __expf(-2.0f * fabsf(x));
  float r = (1.0f - e) / (1.0f + e);
  return x < 0.0f ? -r : r;
}
__device__ __forceinline__ unsigned short f2bf(float f) {
  unsigned int x = __float_as_uint(f);
  x += 0x7fffu + ((x >> 16) & 1u);   // RNE
  return (unsigned short)(x >> 16);
}
__device__ __forceinline__ float bf2f(unsigned short u) {
  return __uint_as_float(((unsigned int)u) << 16);
}

// ================= weight/feature fp32->bf16 conversion (one launch) =================
// segments (elem offsets): nf 0 | wih 524288 | ain 622592 | aout 1015808 | f1 1146880
// | f2 1671168 | s1 2195456 | s2 2260992 | whh 2326528 (196608) -> total 2523136
#define CVT_TOT 2523136
__global__ __launch_bounds__(256) void cvt_weights(
    const float* __restrict__ nf, const float* __restrict__ wih,
    const float* __restrict__ ain, const float* __restrict__ aout,
    const float* __restrict__ f1, const float* __restrict__ f2,
    const float* __restrict__ s1, const float* __restrict__ s2,
    const float* __restrict__ whh, unsigned short* __restrict__ dst) {
  const size_t e = ((size_t)blockIdx.x * 256 + threadIdx.x) * 4;
  if (e >= CVT_TOT) return;
  const float* src;
  if (e < 524288)       src = nf   + e;
  else if (e < 622592)  src = wih  + (e - 524288);
  else if (e < 1015808) src = ain  + (e - 622592);
  else if (e < 1146880) src = aout + (e - 1015808);
  else if (e < 1671168) src = f1   + (e - 1146880);
  else if (e < 2195456) src = f2   + (e - 1671168);
  else if (e < 2260992) src = s1   + (e - 2195456);
  else if (e < 2326528) src = s2   + (e - 2260992);
  else                  src = whh  + (e - 2326528);
  const float4 v = *(const float4*)src;
  dst[e + 0] = f2bf(v.x); dst[e + 1] = f2bf(v.y);
  dst[e + 2] = f2bf(v.z); dst[e + 3] = f2bf(v.w);
}

// ================= GRU preprocessing =================
__global__ __launch_bounds__(256) void build_pos(const int* __restrict__ edges,
                                                 int* __restrict__ cnt, int* __restrict__ lists) {
  const int e = blockIdx.x * 256 + threadIdx.x;
  const int d = edges[2 * e + 1];
  const int slot = atomicAdd(&cnt[d], 1);
  if (slot < MAXD) lists[(size_t)d * MAXD + slot] = e;
}

// LDS-staged per-node sort (edge-id order) + emit srcs + degree histogram
__global__ __launch_bounds__(256) void sort_srcs(const int* __restrict__ edges,
                                                 int* __restrict__ cnt,
                                                 const int* __restrict__ lists,
                                                 int* __restrict__ srcs,
                                                 int* __restrict__ hist) {
  __shared__ int Ls[256][65];
  const int t = threadIdx.x;
  const int d = blockIdx.x * 256 + t;
  int c = cnt[d]; if (c > MAXD) c = MAXD;
  for (int i = 0; i < c; ++i) Ls[t][i] = lists[(size_t)d * MAXD + i];
  for (int i = 1; i < c; ++i) {
    const int key = Ls[t][i];
    int j = i - 1;
    while (j >= 0 && Ls[t][j] > key) { Ls[t][j + 1] = Ls[t][j]; --j; }
    Ls[t][j + 1] = key;
  }
  for (int i = 0; i < c; ++i) srcs[(size_t)d * MAXD + i] = edges[2 * Ls[t][i]];
  cnt[d] = c;
  atomicAdd(&hist[c], 1);
}

__global__ void scan_prep(const int* __restrict__ hist, int* __restrict__ cursor) {
  const int t = threadIdx.x;  // 128
  if (t <= MAXD) {
    int ss = 0;
    for (int dd = t + 1; dd <= MAXD; ++dd) ss += hist[dd];
    cursor[t] = ss;
  }
}

__global__ __launch_bounds__(256) void perm_scatter(const int* __restrict__ cnt,
                                                    int* __restrict__ cursor, int* __restrict__ perm) {
  const int d = blockIdx.x * 256 + threadIdx.x;
  const int rank = atomicAdd(&cursor[cnt[d]], 1);
  perm[rank] = d;
}

// bias for gx GEMM: b_ih + b_hh for R/Z gates (N-gate hh bias stays in gru)
__global__ void prep_bias(const float* __restrict__ b_ih, const float* __restrict__ b_hh,
                          float* __restrict__ bias_gx) {
  const int t = blockIdx.x * 256 + threadIdx.x;
  if (t < 768) bias_gx[t] = b_ih[t] + (t < 512 ? b_hh[t] : 0.0f);
}

// ================= generic bf16 MFMA GEMM =================
// C[M,N] = act(A[M,K] @ W[N,K]^T + bias); 64x64 tile, 256 thr, 4 waves (2m x 2n of 32x32)
template <int ACT, int GS, int OMODE>
__global__ __launch_bounds__(256) void gemm_bf16(
    const unsigned short* __restrict__ A, const int* __restrict__ gidx,
    const unsigned short* __restrict__ W, const float* __restrict__ bias,
    float* __restrict__ C, unsigned short* __restrict__ Cb,
    int M, int N, int K) {
  __shared__ unsigned short As[64 * 64];
  __shared__ unsigned short Ws[64 * 64];
  __shared__ int ridx[64];
  const int bm = blockIdx.y * 64, bn = blockIdx.x * 64;
  const int tid = threadIdx.x;
  const int ln = tid & 63, w = tid >> 6;
  const int jc = ln & 15, kq = ln >> 4;
  const int srow = tid >> 2, q = tid & 3;

  if constexpr (GS > 0) {
    if (tid < 64) ridx[tid] = gidx[(size_t)(bm + tid) * GS];
    __syncthreads();
  }
  const size_t arow = (GS > 0) ? (size_t)ridx[srow] : (size_t)(bm + srow);
  const unsigned short* Asrc = A + arow * K + q * 16;
  const unsigned short* Wsrc = W + (size_t)(bn + srow) * K + q * 16;

  f32x4 acc[2][2];
#pragma unroll
  for (int i = 0; i < 2; ++i)
#pragma unroll
    for (int j = 0; j < 2; ++j) acc[i][j] = (f32x4){0.f, 0.f, 0.f, 0.f};
  const int mrow = (w >> 1) * 32, ncol = (w & 1) * 32;
  const int sb0 = (q * 32) ^ ((srow & 7) << 4);
  const int sb1 = (q * 32 + 16) ^ ((srow & 7) << 4);

  for (int k0 = 0; k0 < K; k0 += 64) {
    __syncthreads();
    {
      const short8 a0 = *(const short8*)(Asrc + k0);
      const short8 a1 = *(const short8*)(Asrc + k0 + 8);
      const short8 w0 = *(const short8*)(Wsrc + k0);
      const short8 w1 = *(const short8*)(Wsrc + k0 + 8);
      *(short8*)((char*)As + srow * 128 + sb0) = a0;
      *(short8*)((char*)As + srow * 128 + sb1) = a1;
      *(short8*)((char*)Ws + srow * 128 + sb0) = w0;
      *(short8*)((char*)Ws + srow * 128 + sb1) = w1;
    }
    __syncthreads();
#pragma unroll
    for (int kt = 0; kt < 2; ++kt) {
      const int kb = kt * 64 + kq * 16;
      short8 a[2], bb[2];
#pragma unroll
      for (int i = 0; i < 2; ++i) {
        const int ra = mrow + i * 16 + jc;
        a[i] = *(const short8*)((const char*)As + ra * 128 + (kb ^ ((ra & 7) << 4)));
        const int rb = ncol + i * 16 + jc;
        bb[i] = *(const short8*)((const char*)Ws + rb * 128 + (kb ^ ((rb & 7) << 4)));
      }
#pragma unroll
      for (int mi = 0; mi < 2; ++mi)
#pragma unroll
        for (int ni = 0; ni < 2; ++ni)
          acc[mi][ni] = __builtin_amdgcn_mfma_f32_16x16x32_bf16(a[mi], bb[ni], acc[mi][ni], 0, 0, 0);
    }
  }
#pragma unroll
  for (int mi = 0; mi < 2; ++mi)
#pragma unroll
    for (int ni = 0; ni < 2; ++ni) {
      const int col = bn + ncol + ni * 16 + jc;
      const float bs = bias[col];
#pragma unroll
      for (int v = 0; v < 4; ++v) {
        const int row = bm + mrow + mi * 16 + kq * 4 + v;
        float val = acc[mi][ni][v] + bs;
        if (ACT == 1) val = fmaxf(val, 0.0f);
        if constexpr (OMODE != 2) C[(size_t)row * N + col] = val;
        if constexpr (OMODE >= 1) Cb[(size_t)row * N + col] = f2bf(val);
      }
    }
}

// ================= per-block independent GRU, register-resident weights =================
// 256 blocks x 512 thr (8 waves). Wave w owns hidden cols [32w,32w+32) for all 3 gates:
// 6 B-tiles x 8 k-frags = 48 short8 = 192 VGPRs (no spill). h lives in regs (8 f32/thread).
// gx[n] = nf[n]@wih^T + b_ih (+b_hh R/Z) precomputed per NODE (6 MB, L2/L3-resident).
__global__ __launch_bounds__(512, 1) void gru_reg(
    const int* __restrict__ perm, const int* __restrict__ cnt,
    const int* __restrict__ srcs, const unsigned short* __restrict__ gx,
    const unsigned short* __restrict__ whhb, const float* __restrict__ b_hh,
    float* __restrict__ x, unsigned short* __restrict__ xb) {
  const int tid = threadIdx.x;
  const int w = tid >> 6;
  const int ln = tid & 63;
  const int jc = ln & 15, kq = ln >> 4;
  const int grow = tid >> 5, gpart = tid & 31;

  __shared__ unsigned short Ah[GNPB * 256];   // [node][col] bf16, stride 512B, swz
  __shared__ unsigned short Gi[GNPB * 776];   // staged gx rows, stride 1552B
  __shared__ int srcs_s[GNPB][MAXD];
  __shared__ int node_s[GNPB], cnt_s[GNPB];
  __shared__ int Rb_s;

  if (tid < GNPB) {
    const int node = perm[blockIdx.x * GNPB + tid];
    node_s[tid] = node;
    cnt_s[tid] = cnt[node];
  }
  for (int i = tid; i < GNPB * 256; i += 512) Ah[i] = 0;
  __syncthreads();
  for (int i = tid; i < GNPB * MAXD; i += 512)
    srcs_s[i >> 6][i & 63] = srcs[(size_t)node_s[i >> 6] * MAXD + (i & 63)];
  if (tid == 0) {
    int mx = 0;
    for (int i = 0; i < GNPB; ++i) mx = mx > cnt_s[i] ? mx : cnt_s[i];
    Rb_s = mx;
  }

  // stage w_hh slice: wave w, tile (g,ct) rows g*256 + w*32 + ct*16 + jc
  short8 W[48];
#pragma unroll
  for (int g = 0; g < 3; ++g)
#pragma unroll
    for (int ct = 0; ct < 2; ++ct) {
      const unsigned short* src =
          whhb + (size_t)(g * 256 + w * 32 + ct * 16 + jc) * 256 + kq * 8;
#pragma unroll
      for (int kt = 0; kt < 8; ++kt)
        W[(g * 2 + ct) * 8 + kt] = *(const short8*)(src + kt * 32);
    }
  float bhN[2];
  bhN[0] = b_hh[512 + w * 32 + jc];
  bhN[1] = b_hh[512 + w * 32 + 16 + jc];

  float h[8];
#pragma unroll
  for (int i = 0; i < 8; ++i) h[i] = 0.f;

  __syncthreads();
  const int Rb = Rb_s;
  const int myc = cnt_s[grow];

  for (int r = 0; r < Rb; ++r) {
    // issue gx gather early (coalesced: 32 threads per node-row)
    const int sn = (r < myc) ? srcs_s[grow][r] : 0;
    const unsigned short* gsrc = gx + (size_t)sn * 768 + gpart * 24;
    const short8 gv0 = *(const short8*)gsrc;
    const short8 gv1 = *(const short8*)(gsrc + 8);
    const short8 gv2 = *(const short8*)(gsrc + 16);

    // hidden-gate MFMA: gates[16 nodes][my 32 cols x 3] = Ah @ W^T
    f32x4 acc[6];
#pragma unroll
    for (int i = 0; i < 6; ++i) acc[i] = (f32x4){0.f, 0.f, 0.f, 0.f};
#pragma unroll
    for (int kt = 0; kt < 8; ++kt) {
      const short8 a = *(const short8*)((const char*)Ah + jc * 512 +
                                        ((kt * 64 + kq * 16) ^ ((jc & 7) << 4)));
#pragma unroll
      for (int t = 0; t < 6; ++t)
        acc[t] = __builtin_amdgcn_mfma_f32_16x16x32_bf16(a, W[t * 8 + kt], acc[t], 0, 0, 0);
    }
    {
      unsigned short* gdst = Gi + grow * 776 + gpart * 24;
      *(short8*)gdst = gv0;
      *(short8*)(gdst + 8) = gv1;
      *(short8*)(gdst + 16) = gv2;
    }
    __syncthreads();   // Gi visible; everyone done reading Ah
    // fused GRU elementwise; thread owns (node=kq*4+v, col=32w+ct*16+jc)
#pragma unroll
    for (int ct = 0; ct < 2; ++ct) {
      const int col = w * 32 + ct * 16 + jc;
#pragma unroll
      for (int v = 0; v < 4; ++v) {
        const int nd = kq * 4 + v;
        if (r < cnt_s[nd]) {
          const float giR = bf2f(Gi[nd * 776 + col]);
          const float giZ = bf2f(Gi[nd * 776 + 256 + col]);
          const float giN = bf2f(Gi[nd * 776 + 512 + col]);
          const float rr = sigf(giR + acc[ct][v]);
          const float zz = sigf(giZ + acc[2 + ct][v]);
          const float nn2 = tanh_fast(giN + rr * (acc[4 + ct][v] + bhN[ct]));
          const float hn = (1.0f - zz) * nn2 + zz * h[ct * 4 + v];
          h[ct * 4 + v] = hn;
          *(unsigned short*)((char*)Ah + nd * 512 + ((col * 2) ^ ((nd & 7) << 4))) = f2bf(hn);
        }
      }
    }
    __syncthreads();   // Ah updates visible before next round's MFMA
  }
#pragma unroll
  for (int ct = 0; ct < 2; ++ct) {
    const int col = w * 32 + ct * 16 + jc;
#pragma unroll
    for (int v = 0; v < 4; ++v) {
      const int gnode = node_s[kq * 4 + v];
      x[(size_t)gnode * HDM + col] = h[ct * 4 + v];
      xb[(size_t)gnode * HDM + col] = f2bf(h[ct * 4 + v]);
    }
  }
}

// ================= V transpose: vtb[h*64+d][n] = qkvb[n][512+h*64+d] =================
__global__ __launch_bounds__(256) void transpose_v(const unsigned short* __restrict__ qkvb,
                                                   unsigned short* __restrict__ vtb) {
  const int h = blockIdx.y, nt = blockIdx.x;
  __shared__ unsigned short T[64][72];
  const int t = threadIdx.x;
  const int r = t >> 2, c = (t & 3) << 4;
  {
    const unsigned short* src = qkvb + (size_t)(nt * 64 + r) * 768 + 512 + h * 64 + c;
    *(short8*)&T[r][c] = *(const short8*)src;
    *(short8*)&T[r][c + 8] = *(const short8*)(src + 8);
  }
  __syncthreads();
  {
    short8 o0, o1;
#pragma unroll
    for (int j = 0; j < 8; ++j) { o0[j] = (short)T[c + j][r]; o1[j] = (short)T[c + 8 + j][r]; }
    unsigned short* dst = vtb + (size_t)(h * 64 + r) * 4096 + nt * 64 + c;
    *(short8*)dst = o0;
    *(short8*)(dst + 8) = o1;
  }
}

// ================= bf16 MFMA flash attention =================
__global__ __launch_bounds__(256) void flash_mfma(const unsigned short* __restrict__ qkvb,
                                                  const unsigned short* __restrict__ vtb,
                                                  unsigned short* __restrict__ outb) {
  const int h = blockIdx.y;
  const int qb = blockIdx.x * 64;
  const int tid = threadIdx.x;
  const int ln = tid & 63, w = tid >> 6;
  const int jc = ln & 15, kq = ln >> 4;
  __shared__ unsigned short Ks[64 * 64];
  __shared__ unsigned short Vts[64 * 64];
  __shared__ unsigned short Ps[64 * 64];

  short8 aq[2];
  {
    const unsigned short* qsrc = qkvb + (size_t)(qb + w * 16 + jc) * 768 + h * 64 + kq * 8;
    aq[0] = *(const short8*)qsrc;
    aq[1] = *(const short8*)(qsrc + 32);
  }
  float m_run[4] = {-1e30f, -1e30f, -1e30f, -1e30f};
  float l_run[4] = {0.f, 0.f, 0.f, 0.f};
  f32x4 accO[4];
#pragma unroll
  for (int nf = 0; nf < 4; ++nf) accO[nf] = (f32x4){0.f, 0.f, 0.f, 0.f};

  const int srow = tid >> 2, sc = tid & 3;
  const int swb0 = (sc * 32) ^ ((srow & 7) << 4);
  const int swb1 = (sc * 32 + 16) ^ ((srow & 7) << 4);

  short8 kr0, kr1, vr0, vr1;
  {
    const unsigned short* ksrc = qkvb + (size_t)srow * 768 + 256 + h * 64 + sc * 16;
    kr0 = *(const short8*)ksrc; kr1 = *(const short8*)(ksrc + 8);
    const unsigned short* vsrc = vtb + (size_t)(h * 64 + srow) * 4096 + sc * 16;
    vr0 = *(const short8*)vsrc; vr1 = *(const short8*)(vsrc + 8);
  }

  for (int kb = 0; kb < 64; ++kb) {
    *(short8*)((char*)Ks + srow * 128 + swb0) = kr0;
    *(short8*)((char*)Ks + srow * 128 + swb1) = kr1;
    *(short8*)((char*)Vts + srow * 128 + swb0) = vr0;
    *(short8*)((char*)Vts + srow * 128 + swb1) = vr1;
    if (kb < 63) {
      const unsigned short* ksrc = qkvb + (size_t)((kb + 1) * 64 + srow) * 768 + 256 + h * 64 + sc * 16;
      kr0 = *(const short8*)ksrc; kr1 = *(const short8*)(ksrc + 8);
      const unsigned short* vsrc = vtb + (size_t)(h * 64 + srow) * 4096 + (kb + 1) * 64 + sc * 16;
      vr0 = *(const short8*)vsrc; vr1 = *(const short8*)(vsrc + 8);
    }
    __syncthreads();
    f32x4 s[4];
#pragma unroll
    for (int kt = 0; kt < 4; ++kt) s[kt] = (f32x4){0.f, 0.f, 0.f, 0.f};
#pragma unroll
    for (int ks = 0; ks < 2; ++ks) {
#pragma unroll
      for (int kt = 0; kt < 4; ++kt) {
        const int brow = kt * 16 + jc;
        const short8 bk = *(const short8*)((const char*)Ks + brow * 128 + ((ks * 64 + kq * 16) ^ ((brow & 7) << 4)));
        s[kt] = __builtin_amdgcn_mfma_f32_16x16x32_bf16(aq[ks], bk, s[kt], 0, 0, 0);
      }
    }
    float mt[4], alpha[4], psum[4];
#pragma unroll
    for (int v = 0; v < 4; ++v) {
      float m0 = fmaxf(fmaxf(s[0][v], s[1][v]), fmaxf(s[2][v], s[3][v])) * 0.125f;
      m0 = fmaxf(m0, __shfl_xor(m0, 1));
      m0 = fmaxf(m0, __shfl_xor(m0, 2));
      m0 = fmaxf(m0, __shfl_xor(m0, 4));
      m0 = fmaxf(m0, __shfl_xor(m0, 8));
      const float mnew = fmaxf(m_run[v], m0);
      alpha[v] = __expf(m_run[v] - mnew);
      m_run[v] = mnew;
      psum[v] = 0.f;
      mt[v] = mnew;
    }
    const int prowb = w * 16 + kq * 4;
#pragma unroll
    for (int kt = 0; kt < 4; ++kt) {
#pragma unroll
      for (int v = 0; v < 4; ++v) {
        const float pv = __expf(s[kt][v] * 0.125f - mt[v]);
        psum[v] += pv;
        const int prow = prowb + v;
        const int cb = kt * 32 + jc * 2;
        const int sbyte = (cb & 15) | ((cb & 112) ^ ((prow & 7) << 4));
        *(unsigned short*)((char*)Ps + prow * 128 + sbyte) = f2bf(pv);
      }
    }
#pragma unroll
    for (int v = 0; v < 4; ++v) {
      float ps = psum[v];
      ps += __shfl_xor(ps, 1);
      ps += __shfl_xor(ps, 2);
      ps += __shfl_xor(ps, 4);
      ps += __shfl_xor(ps, 8);
      l_run[v] = l_run[v] * alpha[v] + ps;
#pragma unroll
      for (int nf = 0; nf < 4; ++nf) accO[nf][v] *= alpha[v];
    }
    __syncthreads();
    const int arow = w * 16 + jc;
#pragma unroll
    for (int ks = 0; ks < 2; ++ks) {
      const short8 ap = *(const short8*)((const char*)Ps + arow * 128 + ((ks * 64 + kq * 16) ^ ((arow & 7) << 4)));
#pragma unroll
      for (int nf = 0; nf < 4; ++nf) {
        const int brow = nf * 16 + jc;
        const short8 bv = *(const short8*)((const char*)Vts + brow * 128 + ((ks * 64 + kq * 16) ^ ((brow & 7) << 4)));
        accO[nf] = __builtin_amdgcn_mfma_f32_16x16x32_bf16(ap, bv, accO[nf], 0, 0, 0);
      }
    }
    __syncthreads();
  }
  float invl[4];
#pragma unroll
  for (int v = 0; v < 4; ++v) invl[v] = 1.0f / l_run[v];
#pragma unroll
  for (int nf = 0; nf < 4; ++nf)
#pragma unroll
    for (int v = 0; v < 4; ++v)
      outb[(size_t)(qb + w * 16 + kq * 4 + v) * HDM + h * 64 + nf * 16 + jc] =
          f2bf(accO[nf][v] * invl[v]);
}

// ================= x = LN(x + a); emits fp32 x and bf16 xb =================
__global__ __launch_bounds__(256) void ln_residual(float* __restrict__ x,
                                                   const float* __restrict__ a,
                                                   const float* __restrict__ g,
                                                   const float* __restrict__ b,
                                                   unsigned short* __restrict__ xb) {
  const int lane = threadIdx.x & 63;
  const int row = blockIdx.x * 4 + (threadIdx.x >> 6);
  float v[4];
  float s = 0.0f;
#pragma unroll
  for (int j = 0; j < 4; j++) {
    const int col = j * 64 + lane;
    v[j] = x[(size_t)row * HDM + col] + a[(size_t)row * HDM + col];
    s += v[j];
  }
#pragma unroll
  for (int off = 32; off > 0; off >>= 1) s += __shfl_xor(s, off);
  const float mu = s * (1.0f / HDM);
  float vs = 0.0f;
#pragma unroll
  for (int j = 0; j < 4; j++) {
    const float d = v[j] - mu;
    vs += d * d;
  }
#pragma unroll
  for (int off = 32; off > 0; off >>= 1) vs += __shfl_xor(vs, off);
  const float rinv = 1.0f / sqrtf(vs * (1.0f / HDM) + 1e-5f);
#pragma unroll
  for (int j = 0; j < 4; j++) {
    const int col = j * 64 + lane;
    const float val = g[col] * (v[j] - mu) * rinv + b[col];
    x[(size_t)row * HDM + col] = val;
    xb[(size_t)row * HDM + col] = f2bf(val);
  }
}

// ================= edge predictor (fp32, tiny) =================
template <int ACT>
__global__ __launch_bounds__(256) void gemm_bias(const float* __restrict__ A,
                                                 const float* __restrict__ W,
                                                 const float* __restrict__ bias,
                                                 float* __restrict__ C, int M, int NCo, int K) {
  __shared__ float As[16][65];
  __shared__ float Ws[16][65];
  const int bm = blockIdx.y * 64, bn = blockIdx.x * 64;
  const int tid = threadIdx.x;
  const int tx = tid & 15, ty = tid >> 4;
  const int lr = tid >> 2;
  const int lk = (tid & 3) * 4;
  float acc[4][4] = {{0.0f}};
  for (int k0 = 0; k0 < K; k0 += 16) {
    __syncthreads();
    {
      const float4 a4 = *(const float4*)(A + (size_t)(bm + lr) * K + k0 + lk);
      As[lk + 0][lr] = a4.x; As[lk + 1][lr] = a4.y; As[lk + 2][lr] = a4.z; As[lk + 3][lr] = a4.w;
      const float4 w4 = *(const float4*)(W + (size_t)(bn + lr) * K + k0 + lk);
      Ws[lk + 0][lr] = w4.x; Ws[lk + 1][lr] = w4.y; Ws[lk + 2][lr] = w4.z; Ws[lk + 3][lr] = w4.w;
    }
    __syncthreads();
#pragma unroll
    for (int k = 0; k < 16; k++) {
      const float a0 = As[k][ty * 4 + 0], a1 = As[k][ty * 4 + 1];
      const float a2 = As[k][ty * 4 + 2], a3 = As[k][ty * 4 + 3];
      const float w0 = Ws[k][tx * 4 + 0], w1 = Ws[k][tx * 4 + 1];
      const float w2 = Ws[k][tx * 4 + 2], w3 = Ws[k][tx * 4 + 3];
      acc[0][0] += a0 * w0; acc[0][1] += a0 * w1; acc[0][2] += a0 * w2; acc[0][3] += a0 * w3;
      acc[1][0] += a1 * w0; acc[1][1] += a1 * w1; acc[1][2] += a1 * w2; acc[1][3] += a1 * w3;
      acc[2][0] += a2 * w0; acc[2][1] += a2 * w1; acc[2][2] += a2 * w2; acc[2][3] += a2 * w3;
      acc[3][0] += a3 * w0; acc[3][1] += a3 * w1; acc[3][2] += a3 * w2; acc[3][3] += a3 * w3;
    }
  }
  const float b0 = bias[bn + tx * 4 + 0], b1 = bias[bn + tx * 4 + 1];
  const float b2 = bias[bn + tx * 4 + 2], b3 = bias[bn + tx * 4 + 3];
#pragma unroll
  for (int i = 0; i < 4; i++) {
    float4 o;
    o.x = acc[i][0] + b0; o.y = acc[i][1] + b1; o.z = acc[i][2] + b2; o.w = acc[i][3] + b3;
    if (ACT == 1) {
      o.x = fmaxf(o.x, 0.0f); o.y = fmaxf(o.y, 0.0f);
      o.z = fmaxf(o.z, 0.0f); o.w = fmaxf(o.w, 0.0f);
    }
    *(float4*)(C + (size_t)(bm + ty * 4 + i) * NCo + bn + tx * 4) = o;
  }
}

__global__ void gather_cat(const float* __restrict__ refined, const int* __restrict__ cand,
                           float* __restrict__ hcat) {
  const int c = blockIdx.x;
  const int t = threadIdx.x;  // 512
  const int n0 = cand[2 * c], n1 = cand[2 * c + 1];
  hcat[(size_t)c * 512 + t] = (t < 256) ? refined[(size_t)n0 * HDM + t]
                                        : refined[(size_t)n1 * HDM + (t - 256)];
}

__global__ void ep_final(const float* __restrict__ eph, const float* __restrict__ w2,
                         const float* __restrict__ b2, float* __restrict__ out) {
  const int c = blockIdx.x;
  const int lane = threadIdx.x;  // 64
  float s = 0.0f;
#pragma unroll
  for (int j = 0; j < 4; j++) s += eph[(size_t)c * HDM + j * 64 + lane] * w2[j * 64 + lane];
#pragma unroll
  for (int off = 32; off > 0; off >>= 1) s += __shfl_xor(s, off);
  if (lane == 0) out[c] = 1.0f / (1.0f + __expf(-(s + b2[0])));
}

extern "C" void kernel_launch(void* const* d_in, const int* in_sizes, int n_in,
                              void* d_out, int out_size, void* d_ws, size_t ws_size,
                              hipStream_t stream) {
  (void)in_sizes; (void)n_in; (void)out_size; (void)ws_size;
  const float* nf    = (const float*)d_in[0];
  const int*   edges = (const int*)d_in[1];
  const int*   cand  = (const int*)d_in[2];
  const float* w_ih  = (const float*)d_in[3];
  const float* w_hh  = (const float*)d_in[4];
  const float* b_ih  = (const float*)d_in[5];
  const float* b_hh  = (const float*)d_in[6];
  const float* ain_w = (const float*)d_in[7];
  const float* ain_b = (const float*)d_in[8];
  const float* aout_w = (const float*)d_in[9];
  const float* aout_b = (const float*)d_in[10];
  const float* ln1g = (const float*)d_in[11];
  const float* ln1b = (const float*)d_in[12];
  const float* f1w  = (const float*)d_in[13];
  const float* f1b  = (const float*)d_in[14];
  const float* f2w  = (const float*)d_in[15];
  const float* f2b  = (const float*)d_in[16];
  const float* ln2g = (const float*)d_in[17];
  const float* ln2b = (const float*)d_in[18];
  const float* s1w  = (const float*)d_in[19];
  const float* s1b  = (const float*)d_in[20];
  const float* s2w  = (const float*)d_in[21];
  const float* s2b  = (const float*)d_in[22];
  const float* e1w  = (const float*)d_in[23];
  const float* e1b  = (const float*)d_in[24];
  const float* e2w  = (const float*)d_in[25];
  const float* e2b  = (const float*)d_in[26];
  float* out = (float*)d_out;

  char* wp = (char*)d_ws;
  float* x        = (float*)wp; wp += (size_t)NN * HDM * 4;            // 4 MB
  unsigned short* xb = (unsigned short*)wp; wp += (size_t)NN * HDM * 2; // 2 MB
  unsigned short* wseg = (unsigned short*)wp; wp += (size_t)CVT_TOT * 2; // 5.05 MB
  int* cnt        = (int*)wp;  wp += (size_t)NN * 4;
  int* lists      = (int*)wp;  wp += (size_t)NN * MAXD * 4;            // 1 MB
  int* srcs       = (int*)wp;  wp += (size_t)NN * MAXD * 4;            // 1 MB
  int* meta       = (int*)wp;  wp += 256 * 4;
  float* bias_gx  = (float*)wp; wp += 1024 * 4;
  int* perm       = (int*)wp;  wp += (size_t)NN * 4;
  unsigned short* gx = (unsigned short*)wp; wp += (size_t)NN * 768 * 2; // 6 MB
  char* uni       = wp;        // transformer buffers
  unsigned short* qkvb   = (unsigned short*)uni;                      // 6 MB
  unsigned short* vtb    = (unsigned short*)(uni + 6291456);          // 2 MB
  float* abuf    = (float*)(uni + 8388608);                           // 4 MB
  unsigned short* abuf_b = (unsigned short*)(uni + 12582912);         // 2 MB
  float* fbuf    = (float*)(uni + 14680064);                          // 16 MB
  unsigned short* fbuf_b = (unsigned short*)(uni + 31457280);         // 8 MB
  float* refined = (float*)(uni + 39845888);                          // 4 MB
  float* hcat    = (float*)(uni + 44040192);
  float* eph     = (float*)(uni + 44171264);

  unsigned short* nf_b  = wseg;
  unsigned short* wihb  = wseg + 524288;
  unsigned short* ainb  = wseg + 622592;
  unsigned short* aoutb = wseg + 1015808;
  unsigned short* f1b_  = wseg + 1146880;
  unsigned short* f2b_  = wseg + 1671168;
  unsigned short* s1b_  = wseg + 2195456;
  unsigned short* s2b_  = wseg + 2260992;
  unsigned short* whhb  = wseg + 2326528;

  int* hist   = meta;
  int* cursor = meta + 128;

  hipMemsetAsync(cnt, 0, (size_t)NN * 4, stream);
  hipMemsetAsync(meta, 0, 256 * 4, stream);

  cvt_weights<<<2464, 256, 0, stream>>>(nf, w_ih, ain_w, aout_w, f1w, f2w, s1w, s2w, w_hh, wseg);
  build_pos<<<NE / 256, 256, 0, stream>>>(edges, cnt, lists);
  sort_srcs<<<NN / 256, 256, 0, stream>>>(edges, cnt, lists, srcs, hist);
  scan_prep<<<1, 128, 0, stream>>>(hist, cursor);
  perm_scatter<<<NN / 256, 256, 0, stream>>>(cnt, cursor, perm);
  prep_bias<<<3, 256, 0, stream>>>(b_ih, b_hh, bias_gx);

  // gx[n] = bf16( nf[n] @ w_ih^T + b_ih (+ b_hh R/Z) )   [NN,768], K=128
  gemm_bf16<0, 0, 2><<<dim3(12, NN / 64), 256, 0, stream>>>(
      nf_b, nullptr, wihb, bias_gx, nullptr, gx, NN, 768, IND);
  gru_reg<<<NN / GNPB, 512, 0, stream>>>(perm, cnt, srcs, gx, whhb, b_hh, x, xb);

  for (int l = 0; l < NL; l++) {
    gemm_bf16<0, 0, 2><<<dim3(12, 64), 256, 0, stream>>>(
        xb, nullptr, ainb + (size_t)l * 196608, ain_b + l * 768, nullptr, qkvb, NN, 768, HDM);
    transpose_v<<<dim3(64, 4), 256, 0, stream>>>(qkvb, vtb);
    flash_mfma<<<dim3(64, 4), 256, 0, stream>>>(qkvb, vtb, abuf_b);
    gemm_bf16<0, 0, 0><<<dim3(4, 64), 256, 0, stream>>>(
        abuf_b, nullptr, aoutb + (size_t)l * 65536, aout_b + l * 256, fbuf, nullptr, NN, 256, HDM);
    ln_residual<<<NN / 4, 256, 0, stream>>>(x, fbuf, ln1g + l * 256, ln1b + l * 256, xb);
    gemm_bf16<1, 0, 1><<<dim3(16, 64), 256, 0, stream>>>(
        xb, nullptr, f1b_ + (size_t)l * 262144, f1b + l * 1024, fbuf, fbuf_b, NN, 1024, HDM);
    gemm_bf16<0, 0, 0><<<dim3(4, 64), 256, 0, stream>>>(
        fbuf_b, nullptr, f2b_ + (size_t)l * 262144, f2b + l * 256, abuf, nullptr, NN, 256, 1024);
    ln_residual<<<NN / 4, 256, 0, stream>>>(x, abuf, ln2g + l * 256, ln2b + l * 256, xb);
  }

  gemm_bf16<1, 0, 1><<<dim3(4, 64), 256, 0, stream>>>(
      xb, nullptr, s1b_, s1b, abuf, abuf_b, NN, 256, HDM);
  gemm_bf16<0, 0, 0><<<dim3(4, 64), 256, 0, stream>>>(
      abuf_b, nullptr, s2b_, s2b, refined, nullptr, NN, 256, HDM);
  gather_cat<<<NCAND, 512, 0, stream>>>(refined, cand, hcat);
  gemm_bias<1><<<dim3(4, 1), 256, 0, stream>>>(hcat, e1w, e1b, eph, NCAND, 256, 512);
  ep_final<<<NCAND, 64, 0, stream>>>(eph, e2w, e2b, out);
}

// Round 6
// 390.851 us; speedup vs baseline: 13.8701x; 1.3463x over previous
//
#include <hip/hip_runtime.h>
#include <math.h>

#define NN     4096
#define NE     32768
#define NCAND  64
#define IND    128
#define HDM    256
#define NL     2
#define MAXD   64
#define GNPB   16   // GRU nodes per block
#define NS     4    // attention KV splits

typedef __attribute__((ext_vector_type(8))) short short8;
typedef __attribute__((ext_vector_type(4))) float f32x4;

__device__ __forceinline__ float sigf(float x) { return 1.0f / (1.0f + __expf(-x)); }
__device__ __forceinline__ float tanh_fast(float x) {
  float e = __expf(-2.0f * fabsf(x));
  float r = (1.0f - e) / (1.0f + e);
  return x < 0.0f ? -r : r;
}
__device__ __forceinline__ unsigned short f2bf(float f) {
  unsigned int x = __float_as_uint(f);
  x += 0x7fffu + ((x >> 16) & 1u);   // RNE
  return (unsigned short)(x >> 16);
}
__device__ __forceinline__ float bf2f(unsigned short u) {
  return __uint_as_float(((unsigned int)u) << 16);
}

// ================= weight/feature fp32->bf16 conversion (one launch) =================
// segments (elem offsets): nf 0 | wih 524288 | ain 622592 | aout 1015808 | f1 1146880
// | f2 1671168 | s1 2195456 | s2 2260992 | whh 2326528 (196608) -> total 2523136
#define CVT_TOT 2523136
__global__ __launch_bounds__(256) void cvt_weights(
    const float* __restrict__ nf, const float* __restrict__ wih,
    const float* __restrict__ ain, const float* __restrict__ aout,
    const float* __restrict__ f1, const float* __restrict__ f2,
    const float* __restrict__ s1, const float* __restrict__ s2,
    const float* __restrict__ whh, unsigned short* __restrict__ dst) {
  const size_t e = ((size_t)blockIdx.x * 256 + threadIdx.x) * 4;
  if (e >= CVT_TOT) return;
  const float* src;
  if (e < 524288)       src = nf   + e;
  else if (e < 622592)  src = wih  + (e - 524288);
  else if (e < 1015808) src = ain  + (e - 622592);
  else if (e < 1146880) src = aout + (e - 1015808);
  else if (e < 1671168) src = f1   + (e - 1146880);
  else if (e < 2195456) src = f2   + (e - 1671168);
  else if (e < 2260992) src = s1   + (e - 2195456);
  else if (e < 2326528) src = s2   + (e - 2260992);
  else                  src = whh  + (e - 2326528);
  const float4 v = *(const float4*)src;
  dst[e + 0] = f2bf(v.x); dst[e + 1] = f2bf(v.y);
  dst[e + 2] = f2bf(v.z); dst[e + 3] = f2bf(v.w);
}

// ================= GRU preprocessing =================
__global__ __launch_bounds__(256) void build_pos(const int* __restrict__ edges,
                                                 int* __restrict__ cnt, int* __restrict__ lists) {
  const int e = blockIdx.x * 256 + threadIdx.x;
  const int d = edges[2 * e + 1];
  const int slot = atomicAdd(&cnt[d], 1);
  if (slot < MAXD) lists[(size_t)d * MAXD + slot] = e;
}

// LDS-staged per-node sort (edge-id order) + emit srcs + degree histogram
__global__ __launch_bounds__(256) void sort_srcs(const int* __restrict__ edges,
                                                 int* __restrict__ cnt,
                                                 const int* __restrict__ lists,
                                                 int* __restrict__ srcs,
                                                 int* __restrict__ hist) {
  __shared__ int Ls[256][65];
  const int t = threadIdx.x;
  const int d = blockIdx.x * 256 + t;
  int c = cnt[d]; if (c > MAXD) c = MAXD;
  for (int i = 0; i < c; ++i) Ls[t][i] = lists[(size_t)d * MAXD + i];
  for (int i = 1; i < c; ++i) {
    const int key = Ls[t][i];
    int j = i - 1;
    while (j >= 0 && Ls[t][j] > key) { Ls[t][j + 1] = Ls[t][j]; --j; }
    Ls[t][j + 1] = key;
  }
  for (int i = 0; i < c; ++i) srcs[(size_t)d * MAXD + i] = edges[2 * Ls[t][i]];
  cnt[d] = c;
  atomicAdd(&hist[c], 1);
}

__global__ void scan_prep(const int* __restrict__ hist, int* __restrict__ cursor) {
  const int t = threadIdx.x;  // 128
  if (t <= MAXD) {
    int ss = 0;
    for (int dd = t + 1; dd <= MAXD; ++dd) ss += hist[dd];
    cursor[t] = ss;
  }
}

__global__ __launch_bounds__(256) void perm_scatter(const int* __restrict__ cnt,
                                                    int* __restrict__ cursor, int* __restrict__ perm) {
  const int d = blockIdx.x * 256 + threadIdx.x;
  const int rank = atomicAdd(&cursor[cnt[d]], 1);
  perm[rank] = d;
}

// bias for gx GEMM: b_ih + b_hh for R/Z gates (N-gate hh bias stays in gru)
__global__ void prep_bias(const float* __restrict__ b_ih, const float* __restrict__ b_hh,
                          float* __restrict__ bias_gx) {
  const int t = blockIdx.x * 256 + threadIdx.x;
  if (t < 768) bias_gx[t] = b_ih[t] + (t < 512 ? b_hh[t] : 0.0f);
}

// ================= generic bf16 MFMA GEMM =================
// C[M,N] = act(A[M,K] @ W[N,K]^T + bias); 64x64 tile, 256 thr, 4 waves (2m x 2n of 32x32)
template <int ACT, int GS, int OMODE>
__global__ __launch_bounds__(256) void gemm_bf16(
    const unsigned short* __restrict__ A, const int* __restrict__ gidx,
    const unsigned short* __restrict__ W, const float* __restrict__ bias,
    float* __restrict__ C, unsigned short* __restrict__ Cb,
    int M, int N, int K) {
  __shared__ unsigned short As[64 * 64];
  __shared__ unsigned short Ws[64 * 64];
  __shared__ int ridx[64];
  const int bm = blockIdx.y * 64, bn = blockIdx.x * 64;
  const int tid = threadIdx.x;
  const int ln = tid & 63, w = tid >> 6;
  const int jc = ln & 15, kq = ln >> 4;
  const int srow = tid >> 2, q = tid & 3;

  if constexpr (GS > 0) {
    if (tid < 64) ridx[tid] = gidx[(size_t)(bm + tid) * GS];
    __syncthreads();
  }
  const size_t arow = (GS > 0) ? (size_t)ridx[srow] : (size_t)(bm + srow);
  const unsigned short* Asrc = A + arow * K + q * 16;
  const unsigned short* Wsrc = W + (size_t)(bn + srow) * K + q * 16;

  f32x4 acc[2][2];
#pragma unroll
  for (int i = 0; i < 2; ++i)
#pragma unroll
    for (int j = 0; j < 2; ++j) acc[i][j] = (f32x4){0.f, 0.f, 0.f, 0.f};
  const int mrow = (w >> 1) * 32, ncol = (w & 1) * 32;
  const int sb0 = (q * 32) ^ ((srow & 7) << 4);
  const int sb1 = (q * 32 + 16) ^ ((srow & 7) << 4);

  for (int k0 = 0; k0 < K; k0 += 64) {
    __syncthreads();
    {
      const short8 a0 = *(const short8*)(Asrc + k0);
      const short8 a1 = *(const short8*)(Asrc + k0 + 8);
      const short8 w0 = *(const short8*)(Wsrc + k0);
      const short8 w1 = *(const short8*)(Wsrc + k0 + 8);
      *(short8*)((char*)As + srow * 128 + sb0) = a0;
      *(short8*)((char*)As + srow * 128 + sb1) = a1;
      *(short8*)((char*)Ws + srow * 128 + sb0) = w0;
      *(short8*)((char*)Ws + srow * 128 + sb1) = w1;
    }
    __syncthreads();
#pragma unroll
    for (int kt = 0; kt < 2; ++kt) {
      const int kb = kt * 64 + kq * 16;
      short8 a[2], bb[2];
#pragma unroll
      for (int i = 0; i < 2; ++i) {
        const int ra = mrow + i * 16 + jc;
        a[i] = *(const short8*)((const char*)As + ra * 128 + (kb ^ ((ra & 7) << 4)));
        const int rb = ncol + i * 16 + jc;
        bb[i] = *(const short8*)((const char*)Ws + rb * 128 + (kb ^ ((rb & 7) << 4)));
      }
#pragma unroll
      for (int mi = 0; mi < 2; ++mi)
#pragma unroll
        for (int ni = 0; ni < 2; ++ni)
          acc[mi][ni] = __builtin_amdgcn_mfma_f32_16x16x32_bf16(a[mi], bb[ni], acc[mi][ni], 0, 0, 0);
    }
  }
#pragma unroll
  for (int mi = 0; mi < 2; ++mi)
#pragma unroll
    for (int ni = 0; ni < 2; ++ni) {
      const int col = bn + ncol + ni * 16 + jc;
      const float bs = bias[col];
#pragma unroll
      for (int v = 0; v < 4; ++v) {
        const int row = bm + mrow + mi * 16 + kq * 4 + v;
        float val = acc[mi][ni][v] + bs;
        if (ACT == 1) val = fmaxf(val, 0.0f);
        if constexpr (OMODE != 2) C[(size_t)row * N + col] = val;
        if constexpr (OMODE >= 1) Cb[(size_t)row * N + col] = f2bf(val);
      }
    }
}

// ================= per-block independent GRU, register-resident weights =================
__global__ __launch_bounds__(512, 1) void gru_reg(
    const int* __restrict__ perm, const int* __restrict__ cnt,
    const int* __restrict__ srcs, const unsigned short* __restrict__ gx,
    const unsigned short* __restrict__ whhb, const float* __restrict__ b_hh,
    float* __restrict__ x, unsigned short* __restrict__ xb) {
  const int tid = threadIdx.x;
  const int w = tid >> 6;
  const int ln = tid & 63;
  const int jc = ln & 15, kq = ln >> 4;
  const int grow = tid >> 5, gpart = tid & 31;

  __shared__ unsigned short Ah[GNPB * 256];   // [node][col] bf16, stride 512B, swz
  __shared__ unsigned short Gi[GNPB * 776];   // staged gx rows, stride 1552B
  __shared__ int srcs_s[GNPB][MAXD];
  __shared__ int node_s[GNPB], cnt_s[GNPB];
  __shared__ int Rb_s;

  if (tid < GNPB) {
    const int node = perm[blockIdx.x * GNPB + tid];
    node_s[tid] = node;
    cnt_s[tid] = cnt[node];
  }
  for (int i = tid; i < GNPB * 256; i += 512) Ah[i] = 0;
  __syncthreads();
  for (int i = tid; i < GNPB * MAXD; i += 512)
    srcs_s[i >> 6][i & 63] = srcs[(size_t)node_s[i >> 6] * MAXD + (i & 63)];
  if (tid == 0) {
    int mx = 0;
    for (int i = 0; i < GNPB; ++i) mx = mx > cnt_s[i] ? mx : cnt_s[i];
    Rb_s = mx;
  }

  short8 W[48];
#pragma unroll
  for (int g = 0; g < 3; ++g)
#pragma unroll
    for (int ct = 0; ct < 2; ++ct) {
      const unsigned short* src =
          whhb + (size_t)(g * 256 + w * 32 + ct * 16 + jc) * 256 + kq * 8;
#pragma unroll
      for (int kt = 0; kt < 8; ++kt)
        W[(g * 2 + ct) * 8 + kt] = *(const short8*)(src + kt * 32);
    }
  float bhN[2];
  bhN[0] = b_hh[512 + w * 32 + jc];
  bhN[1] = b_hh[512 + w * 32 + 16 + jc];

  float h[8];
#pragma unroll
  for (int i = 0; i < 8; ++i) h[i] = 0.f;

  __syncthreads();
  const int Rb = Rb_s;
  const int myc = cnt_s[grow];

  for (int r = 0; r < Rb; ++r) {
    const int sn = (r < myc) ? srcs_s[grow][r] : 0;
    const unsigned short* gsrc = gx + (size_t)sn * 768 + gpart * 24;
    const short8 gv0 = *(const short8*)gsrc;
    const short8 gv1 = *(const short8*)(gsrc + 8);
    const short8 gv2 = *(const short8*)(gsrc + 16);

    f32x4 acc[6];
#pragma unroll
    for (int i = 0; i < 6; ++i) acc[i] = (f32x4){0.f, 0.f, 0.f, 0.f};
#pragma unroll
    for (int kt = 0; kt < 8; ++kt) {
      const short8 a = *(const short8*)((const char*)Ah + jc * 512 +
                                        ((kt * 64 + kq * 16) ^ ((jc & 7) << 4)));
#pragma unroll
      for (int t = 0; t < 6; ++t)
        acc[t] = __builtin_amdgcn_mfma_f32_16x16x32_bf16(a, W[t * 8 + kt], acc[t], 0, 0, 0);
    }
    {
      unsigned short* gdst = Gi + grow * 776 + gpart * 24;
      *(short8*)gdst = gv0;
      *(short8*)(gdst + 8) = gv1;
      *(short8*)(gdst + 16) = gv2;
    }
    __syncthreads();
#pragma unroll
    for (int ct = 0; ct < 2; ++ct) {
      const int col = w * 32 + ct * 16 + jc;
#pragma unroll
      for (int v = 0; v < 4; ++v) {
        const int nd = kq * 4 + v;
        if (r < cnt_s[nd]) {
          const float giR = bf2f(Gi[nd * 776 + col]);
          const float giZ = bf2f(Gi[nd * 776 + 256 + col]);
          const float giN = bf2f(Gi[nd * 776 + 512 + col]);
          const float rr = sigf(giR + acc[ct][v]);
          const float zz = sigf(giZ + acc[2 + ct][v]);
          const float nn2 = tanh_fast(giN + rr * (acc[4 + ct][v] + bhN[ct]));
          const float hn = (1.0f - zz) * nn2 + zz * h[ct * 4 + v];
          h[ct * 4 + v] = hn;
          *(unsigned short*)((char*)Ah + nd * 512 + ((col * 2) ^ ((nd & 7) << 4))) = f2bf(hn);
        }
      }
    }
    __syncthreads();
  }
#pragma unroll
  for (int ct = 0; ct < 2; ++ct) {
    const int col = w * 32 + ct * 16 + jc;
#pragma unroll
    for (int v = 0; v < 4; ++v) {
      const int gnode = node_s[kq * 4 + v];
      x[(size_t)gnode * HDM + col] = h[ct * 4 + v];
      xb[(size_t)gnode * HDM + col] = f2bf(h[ct * 4 + v]);
    }
  }
}

// ================= V transpose: vtb[h*64+d][n] = qkvb[n][512+h*64+d] =================
__global__ __launch_bounds__(256) void transpose_v(const unsigned short* __restrict__ qkvb,
                                                   unsigned short* __restrict__ vtb) {
  const int h = blockIdx.y, nt = blockIdx.x;
  __shared__ unsigned short T[64][72];
  const int t = threadIdx.x;
  const int r = t >> 2, c = (t & 3) << 4;
  {
    const unsigned short* src = qkvb + (size_t)(nt * 64 + r) * 768 + 512 + h * 64 + c;
    *(short8*)&T[r][c] = *(const short8*)src;
    *(short8*)&T[r][c + 8] = *(const short8*)(src + 8);
  }
  __syncthreads();
  {
    short8 o0, o1;
#pragma unroll
    for (int j = 0; j < 8; ++j) { o0[j] = (short)T[c + j][r]; o1[j] = (short)T[c + 8 + j][r]; }
    unsigned short* dst = vtb + (size_t)(h * 64 + r) * 4096 + nt * 64 + c;
    *(short8*)dst = o0;
    *(short8*)(dst + 8) = o1;
  }
}

// ================= bf16 MFMA flash attention, KV-split, fixed-max softmax =================
// grid (64 qblocks, 4 heads, NS), 256 thr = 4 waves x 16 q-rows. 16 x 64-key tiles per block.
// Fixed max m=8 (scores bounded): no online max/rescale; psum accumulated locally,
// reduced once after the k-loop. P is wave-private LDS (no barrier, lgkmcnt only).
__global__ __launch_bounds__(256) void flash_part(
    const unsigned short* __restrict__ qkvb, const unsigned short* __restrict__ vtb,
    float* __restrict__ Op, float* __restrict__ lp) {
  const int h = blockIdx.y;
  const int qb = blockIdx.x * 64;
  const int z = blockIdx.z;
  const int tid = threadIdx.x;
  const int ln = tid & 63, w = tid >> 6;
  const int jc = ln & 15, kq = ln >> 4;
  __shared__ unsigned short Ks[2][64 * 64];
  __shared__ unsigned short Vts[2][64 * 64];
  __shared__ unsigned short Ps[4][16 * 64];   // per-wave private

  short8 aq[2];
  {
    const unsigned short* qsrc = qkvb + (size_t)(qb + w * 16 + jc) * 768 + h * 64 + kq * 8;
    aq[0] = *(const short8*)qsrc;
    aq[1] = *(const short8*)(qsrc + 32);
  }
  f32x4 accO[4];
#pragma unroll
  for (int nf = 0; nf < 4; ++nf) accO[nf] = (f32x4){0.f, 0.f, 0.f, 0.f};
  float psum[4] = {0.f, 0.f, 0.f, 0.f};

  const int srow = tid >> 2, sc = tid & 3;
  const int swb0 = (sc * 32) ^ ((srow & 7) << 4);
  const int swb1 = (sc * 32 + 16) ^ ((srow & 7) << 4);
  const int k0 = z * 1024;
  unsigned short* Pw = Ps[w];

  short8 kr0, kr1, vr0, vr1;
  {
    const unsigned short* ksrc = qkvb + (size_t)(k0 + srow) * 768 + 256 + h * 64 + sc * 16;
    kr0 = *(const short8*)ksrc; kr1 = *(const short8*)(ksrc + 8);
    const unsigned short* vsrc = vtb + (size_t)(h * 64 + srow) * 4096 + k0 + sc * 16;
    vr0 = *(const short8*)vsrc; vr1 = *(const short8*)(vsrc + 8);
  }

  for (int t = 0; t < 16; ++t) {
    const int cur = t & 1;
    *(short8*)((char*)Ks[cur] + srow * 128 + swb0) = kr0;
    *(short8*)((char*)Ks[cur] + srow * 128 + swb1) = kr1;
    *(short8*)((char*)Vts[cur] + srow * 128 + swb0) = vr0;
    *(short8*)((char*)Vts[cur] + srow * 128 + swb1) = vr1;
    {
      const int tn = t < 15 ? t + 1 : 15;
      const unsigned short* ksrc =
          qkvb + (size_t)(k0 + tn * 64 + srow) * 768 + 256 + h * 64 + sc * 16;
      kr0 = *(const short8*)ksrc; kr1 = *(const short8*)(ksrc + 8);
      const unsigned short* vsrc =
          vtb + (size_t)(h * 64 + srow) * 4096 + k0 + tn * 64 + sc * 16;
      vr0 = *(const short8*)vsrc; vr1 = *(const short8*)(vsrc + 8);
    }
    __syncthreads();
    // ---- S = Q @ K^T ----
    f32x4 s[4];
#pragma unroll
    for (int kt = 0; kt < 4; ++kt) s[kt] = (f32x4){0.f, 0.f, 0.f, 0.f};
    __builtin_amdgcn_s_setprio(1);
#pragma unroll
    for (int ks = 0; ks < 2; ++ks) {
#pragma unroll
      for (int kt = 0; kt < 4; ++kt) {
        const int brow = kt * 16 + jc;
        const short8 bk = *(const short8*)((const char*)Ks[cur] + brow * 128 +
                                           ((ks * 64 + kq * 16) ^ ((brow & 7) << 4)));
        s[kt] = __builtin_amdgcn_mfma_f32_16x16x32_bf16(aq[ks], bk, s[kt], 0, 0, 0);
      }
    }
    __builtin_amdgcn_s_setprio(0);
    // ---- P = exp(S/8 - 8), local psum accumulate, wave-private store ----
#pragma unroll
    for (int kt = 0; kt < 4; ++kt) {
#pragma unroll
      for (int v = 0; v < 4; ++v) {
        const float pv = __expf(s[kt][v] * 0.125f - 8.0f);
        psum[v] += pv;
        const int pr = kq * 4 + v;
        const int cb = kt * 32 + jc * 2;
        *(unsigned short*)((char*)Pw + pr * 128 + (cb ^ ((pr & 7) << 4))) = f2bf(pv);
      }
    }
    asm volatile("s_waitcnt lgkmcnt(0)" ::: "memory");
    __builtin_amdgcn_sched_barrier(0);
    // ---- O += P @ V ----
    __builtin_amdgcn_s_setprio(1);
#pragma unroll
    for (int ks = 0; ks < 2; ++ks) {
      const short8 ap = *(const short8*)((const char*)Pw + jc * 128 +
                                         ((ks * 64 + kq * 16) ^ ((jc & 7) << 4)));
#pragma unroll
      for (int nf = 0; nf < 4; ++nf) {
        const int brow = nf * 16 + jc;
        const short8 bv = *(const short8*)((const char*)Vts[cur] + brow * 128 +
                                           ((ks * 64 + kq * 16) ^ ((brow & 7) << 4)));
        accO[nf] = __builtin_amdgcn_mfma_f32_16x16x32_bf16(ap, bv, accO[nf], 0, 0, 0);
      }
    }
    __builtin_amdgcn_s_setprio(0);
  }
#pragma unroll
  for (int v = 0; v < 4; ++v) {
    float ps = psum[v];
    ps += __shfl_xor(ps, 1);
    ps += __shfl_xor(ps, 2);
    ps += __shfl_xor(ps, 4);
    ps += __shfl_xor(ps, 8);
    psum[v] = ps;
  }
  float* opb = Op + ((size_t)z * NN + qb + w * 16 + kq * 4) * HDM + h * 64 + jc;
#pragma unroll
  for (int nf = 0; nf < 4; ++nf)
#pragma unroll
    for (int v = 0; v < 4; ++v)
      opb[(size_t)v * HDM + nf * 16] = accO[nf][v];
  if (jc == 0) {
#pragma unroll
    for (int v = 0; v < 4; ++v)
      lp[((size_t)z * 4 + h) * NN + qb + w * 16 + kq * 4 + v] = psum[v];
  }
}

// combine: out = (sum_z Op) / (sum_z l)  -> bf16
__global__ __launch_bounds__(256) void attn_combine(const float* __restrict__ Op,
                                                    const float* __restrict__ lp,
                                                    unsigned short* __restrict__ outb) {
  const int row = blockIdx.x * 4 + (threadIdx.x >> 6);
  const int lane = threadIdx.x & 63;
  const int col = lane * 4;
  const int h = col >> 6;
  float l = 0.f;
  float4 o = {0.f, 0.f, 0.f, 0.f};
#pragma unroll
  for (int z = 0; z < NS; ++z) {
    l += lp[((size_t)z * 4 + h) * NN + row];
    const float4 p = *(const float4*)(Op + ((size_t)z * NN + row) * HDM + col);
    o.x += p.x; o.y += p.y; o.z += p.z; o.w += p.w;
  }
  const float inv = 1.0f / l;
  unsigned short* d = outb + (size_t)row * HDM + col;
  d[0] = f2bf(o.x * inv); d[1] = f2bf(o.y * inv);
  d[2] = f2bf(o.z * inv); d[3] = f2bf(o.w * inv);
}

// ================= x = LN(x + a); emits fp32 x and bf16 xb =================
__global__ __launch_bounds__(256) void ln_residual(float* __restrict__ x,
                                                   const float* __restrict__ a,
                                                   const float* __restrict__ g,
                                                   const float* __restrict__ b,
                                                   unsigned short* __restrict__ xb) {
  const int lane = threadIdx.x & 63;
  const int row = blockIdx.x * 4 + (threadIdx.x >> 6);
  float v[4];
  float s = 0.0f;
#pragma unroll
  for (int j = 0; j < 4; j++) {
    const int col = j * 64 + lane;
    v[j] = x[(size_t)row * HDM + col] + a[(size_t)row * HDM + col];
    s += v[j];
  }
#pragma unroll
  for (int off = 32; off > 0; off >>= 1) s += __shfl_xor(s, off);
  const float mu = s * (1.0f / HDM);
  float vs = 0.0f;
#pragma unroll
  for (int j = 0; j < 4; j++) {
    const float d = v[j] - mu;
    vs += d * d;
  }
#pragma unroll
  for (int off = 32; off > 0; off >>= 1) vs += __shfl_xor(vs, off);
  const float rinv = 1.0f / sqrtf(vs * (1.0f / HDM) + 1e-5f);
#pragma unroll
  for (int j = 0; j < 4; j++) {
    const int col = j * 64 + lane;
    const float val = g[col] * (v[j] - mu) * rinv + b[col];
    x[(size_t)row * HDM + col] = val;
    xb[(size_t)row * HDM + col] = f2bf(val);
  }
}

// ================= edge predictor (fp32, tiny) =================
template <int ACT>
__global__ __launch_bounds__(256) void gemm_bias(const float* __restrict__ A,
                                                 const float* __restrict__ W,
                                                 const float* __restrict__ bias,
                                                 float* __restrict__ C, int M, int NCo, int K) {
  __shared__ float As[16][65];
  __shared__ float Ws[16][65];
  const int bm = blockIdx.y * 64, bn = blockIdx.x * 64;
  const int tid = threadIdx.x;
  const int tx = tid & 15, ty = tid >> 4;
  const int lr = tid >> 2;
  const int lk = (tid & 3) * 4;
  float acc[4][4] = {{0.0f}};
  for (int k0 = 0; k0 < K; k0 += 16) {
    __syncthreads();
    {
      const float4 a4 = *(const float4*)(A + (size_t)(bm + lr) * K + k0 + lk);
      As[lk + 0][lr] = a4.x; As[lk + 1][lr] = a4.y; As[lk + 2][lr] = a4.z; As[lk + 3][lr] = a4.w;
      const float4 w4 = *(const float4*)(W + (size_t)(bn + lr) * K + k0 + lk);
      Ws[lk + 0][lr] = w4.x; Ws[lk + 1][lr] = w4.y; Ws[lk + 2][lr] = w4.z; Ws[lk + 3][lr] = w4.w;
    }
    __syncthreads();
#pragma unroll
    for (int k = 0; k < 16; k++) {
      const float a0 = As[k][ty * 4 + 0], a1 = As[k][ty * 4 + 1];
      const float a2 = As[k][ty * 4 + 2], a3 = As[k][ty * 4 + 3];
      const float w0 = Ws[k][tx * 4 + 0], w1 = Ws[k][tx * 4 + 1];
      const float w2 = Ws[k][tx * 4 + 2], w3 = Ws[k][tx * 4 + 3];
      acc[0][0] += a0 * w0; acc[0][1] += a0 * w1; acc[0][2] += a0 * w2; acc[0][3] += a0 * w3;
      acc[1][0] += a1 * w0; acc[1][1] += a1 * w1; acc[1][2] += a1 * w2; acc[1][3] += a1 * w3;
      acc[2][0] += a2 * w0; acc[2][1] += a2 * w1; acc[2][2] += a2 * w2; acc[2][3] += a2 * w3;
      acc[3][0] += a3 * w0; acc[3][1] += a3 * w1; acc[3][2] += a3 * w2; acc[3][3] += a3 * w3;
    }
  }
  const float b0 = bias[bn + tx * 4 + 0], b1 = bias[bn + tx * 4 + 1];
  const float b2 = bias[bn + tx * 4 + 2], b3 = bias[bn + tx * 4 + 3];
#pragma unroll
  for (int i = 0; i < 4; i++) {
    float4 o;
    o.x = acc[i][0] + b0; o.y = acc[i][1] + b1; o.z = acc[i][2] + b2; o.w = acc[i][3] + b3;
    if (ACT == 1) {
      o.x = fmaxf(o.x, 0.0f); o.y = fmaxf(o.y, 0.0f);
      o.z = fmaxf(o.z, 0.0f); o.w = fmaxf(o.w, 0.0f);
    }
    *(float4*)(C + (size_t)(bm + ty * 4 + i) * NCo + bn + tx * 4) = o;
  }
}

__global__ void gather_cat(const float* __restrict__ refined, const int* __restrict__ cand,
                           float* __restrict__ hcat) {
  const int c = blockIdx.x;
  const int t = threadIdx.x;  // 512
  const int n0 = cand[2 * c], n1 = cand[2 * c + 1];
  hcat[(size_t)c * 512 + t] = (t < 256) ? refined[(size_t)n0 * HDM + t]
                                        : refined[(size_t)n1 * HDM + (t - 256)];
}

__global__ void ep_final(const float* __restrict__ eph, const float* __restrict__ w2,
                         const float* __restrict__ b2, float* __restrict__ out) {
  const int c = blockIdx.x;
  const int lane = threadIdx.x;  // 64
  float s = 0.0f;
#pragma unroll
  for (int j = 0; j < 4; j++) s += eph[(size_t)c * HDM + j * 64 + lane] * w2[j * 64 + lane];
#pragma unroll
  for (int off = 32; off > 0; off >>= 1) s += __shfl_xor(s, off);
  if (lane == 0) out[c] = 1.0f / (1.0f + __expf(-(s + b2[0])));
}

extern "C" void kernel_launch(void* const* d_in, const int* in_sizes, int n_in,
                              void* d_out, int out_size, void* d_ws, size_t ws_size,
                              hipStream_t stream) {
  (void)in_sizes; (void)n_in; (void)out_size; (void)ws_size;
  const float* nf    = (const float*)d_in[0];
  const int*   edges = (const int*)d_in[1];
  const int*   cand  = (const int*)d_in[2];
  const float* w_ih  = (const float*)d_in[3];
  const float* w_hh  = (const float*)d_in[4];
  const float* b_ih  = (const float*)d_in[5];
  const float* b_hh  = (const float*)d_in[6];
  const float* ain_w = (const float*)d_in[7];
  const float* ain_b = (const float*)d_in[8];
  const float* aout_w = (const float*)d_in[9];
  const float* aout_b = (const float*)d_in[10];
  const float* ln1g = (const float*)d_in[11];
  const float* ln1b = (const float*)d_in[12];
  const float* f1w  = (const float*)d_in[13];
  const float* f1b  = (const float*)d_in[14];
  const float* f2w  = (const float*)d_in[15];
  const float* f2b  = (const float*)d_in[16];
  const float* ln2g = (const float*)d_in[17];
  const float* ln2b = (const float*)d_in[18];
  const float* s1w  = (const float*)d_in[19];
  const float* s1b  = (const float*)d_in[20];
  const float* s2w  = (const float*)d_in[21];
  const float* s2b  = (const float*)d_in[22];
  const float* e1w  = (const float*)d_in[23];
  const float* e1b  = (const float*)d_in[24];
  const float* e2w  = (const float*)d_in[25];
  const float* e2b  = (const float*)d_in[26];
  float* out = (float*)d_out;

  char* wp = (char*)d_ws;
  float* x        = (float*)wp; wp += (size_t)NN * HDM * 4;            // 4 MB
  unsigned short* xb = (unsigned short*)wp; wp += (size_t)NN * HDM * 2; // 2 MB
  unsigned short* wseg = (unsigned short*)wp; wp += (size_t)CVT_TOT * 2; // 5.05 MB
  int* cnt        = (int*)wp;  wp += (size_t)NN * 4;
  int* lists      = (int*)wp;  wp += (size_t)NN * MAXD * 4;            // 1 MB
  int* srcs       = (int*)wp;  wp += (size_t)NN * MAXD * 4;            // 1 MB
  int* meta       = (int*)wp;  wp += 256 * 4;
  float* bias_gx  = (float*)wp; wp += 1024 * 4;
  int* perm       = (int*)wp;  wp += (size_t)NN * 4;
  unsigned short* gx = (unsigned short*)wp; wp += (size_t)NN * 768 * 2; // 6 MB
  char* uni       = wp;        // transformer buffers
  unsigned short* qkvb   = (unsigned short*)uni;                      // 6 MB
  unsigned short* vtb    = (unsigned short*)(uni + 6291456);          // 2 MB
  float* abuf    = (float*)(uni + 8388608);                           // 4 MB
  unsigned short* abuf_b = (unsigned short*)(uni + 12582912);         // 2 MB
  float* fbuf    = (float*)(uni + 14680064);                          // 16 MB (also attn Op)
  float* Op      = fbuf;
  unsigned short* fbuf_b = (unsigned short*)(uni + 31457280);         // 8 MB (also attn lp)
  float* lp      = (float*)(uni + 31457280);                          // 256 KB
  float* refined = (float*)(uni + 39845888);                          // 4 MB
  float* hcat    = (float*)(uni + 44040192);
  float* eph     = (float*)(uni + 44171264);

  unsigned short* nf_b  = wseg;
  unsigned short* wihb  = wseg + 524288;
  unsigned short* ainb  = wseg + 622592;
  unsigned short* aoutb = wseg + 1015808;
  unsigned short* f1b_  = wseg + 1146880;
  unsigned short* f2b_  = wseg + 1671168;
  unsigned short* s1b_  = wseg + 2195456;
  unsigned short* s2b_  = wseg + 2260992;
  unsigned short* whhb  = wseg + 2326528;

  int* hist   = meta;
  int* cursor = meta + 128;

  hipMemsetAsync(cnt, 0, (size_t)NN * 4, stream);
  hipMemsetAsync(meta, 0, 256 * 4, stream);

  cvt_weights<<<2464, 256, 0, stream>>>(nf, w_ih, ain_w, aout_w, f1w, f2w, s1w, s2w, w_hh, wseg);
  build_pos<<<NE / 256, 256, 0, stream>>>(edges, cnt, lists);
  sort_srcs<<<NN / 256, 256, 0, stream>>>(edges, cnt, lists, srcs, hist);
  scan_prep<<<1, 128, 0, stream>>>(hist, cursor);
  perm_scatter<<<NN / 256, 256, 0, stream>>>(cnt, cursor, perm);
  prep_bias<<<3, 256, 0, stream>>>(b_ih, b_hh, bias_gx);

  // gx[n] = bf16( nf[n] @ w_ih^T + b_ih (+ b_hh R/Z) )   [NN,768], K=128
  gemm_bf16<0, 0, 2><<<dim3(12, NN / 64), 256, 0, stream>>>(
      nf_b, nullptr, wihb, bias_gx, nullptr, gx, NN, 768, IND);
  gru_reg<<<NN / GNPB, 512, 0, stream>>>(perm, cnt, srcs, gx, whhb, b_hh, x, xb);

  for (int l = 0; l < NL; l++) {
    gemm_bf16<0, 0, 2><<<dim3(12, 64), 256, 0, stream>>>(
        xb, nullptr, ainb + (size_t)l * 196608, ain_b + l * 768, nullptr, qkvb, NN, 768, HDM);
    transpose_v<<<dim3(64, 4), 256, 0, stream>>>(qkvb, vtb);
    flash_part<<<dim3(64, 4, NS), 256, 0, stream>>>(qkvb, vtb, Op, lp);
    attn_combine<<<NN / 4, 256, 0, stream>>>(Op, lp, abuf_b);
    gemm_bf16<0, 0, 0><<<dim3(4, 64), 256, 0, stream>>>(
        abuf_b, nullptr, aoutb + (size_t)l * 65536, aout_b + l * 256, fbuf, nullptr, NN, 256, HDM);
    ln_residual<<<NN / 4, 256, 0, stream>>>(x, fbuf, ln1g + l * 256, ln1b + l * 256, xb);
    gemm_bf16<1, 0, 2><<<dim3(16, 64), 256, 0, stream>>>(
        xb, nullptr, f1b_ + (size_t)l * 262144, f1b + l * 1024, nullptr, fbuf_b, NN, 1024, HDM);
    gemm_bf16<0, 0, 0><<<dim3(4, 64), 256, 0, stream>>>(
        fbuf_b, nullptr, f2b_ + (size_t)l * 262144, f2b + l * 256, abuf, nullptr, NN, 256, 1024);
    ln_residual<<<NN / 4, 256, 0, stream>>>(x, abuf, ln2g + l * 256, ln2b + l * 256, xb);
  }

  gemm_bf16<1, 0, 1><<<dim3(4, 64), 256, 0, stream>>>(
      xb, nullptr, s1b_, s1b, abuf, abuf_b, NN, 256, HDM);
  gemm_bf16<0, 0, 0><<<dim3(4, 64), 256, 0, stream>>>(
      abuf_b, nullptr, s2b_, s2b, refined, nullptr, NN, 256, HDM);
  gather_cat<<<NCAND, 512, 0, stream>>>(refined, cand, hcat);
  gemm_bias<1><<<dim3(4, 1), 256, 0, stream>>>(hcat, e1w, e1b, eph, NCAND, 256, 512);
  ep_final<<<NCAND, 64, 0, stream>>>(eph, e2w, e2b, out);
}

// Round 7
// 358.601 us; speedup vs baseline: 15.1174x; 1.0899x over previous
//
#include <hip/hip_runtime.h>
#include <math.h>

#define NN     4096
#define NE     32768
#define NCAND  64
#define IND    128
#define HDM    256
#define NL     2
#define MAXD   64
#define GNPB   16   // GRU nodes per block
#define NS     4    // attention KV splits

typedef __attribute__((ext_vector_type(8))) short short8;
typedef __attribute__((ext_vector_type(4))) short short4b;
typedef __attribute__((ext_vector_type(4))) float f32x4;

__device__ __forceinline__ float sigf(float x) { return 1.0f / (1.0f + __expf(-x)); }
__device__ __forceinline__ float tanh_fast(float x) {
  float e = __expf(-2.0f * fabsf(x));
  float r = (1.0f - e) / (1.0f + e);
  return x < 0.0f ? -r : r;
}
__device__ __forceinline__ unsigned short f2bf(float f) {
  unsigned int x = __float_as_uint(f);
  x += 0x7fffu + ((x >> 16) & 1u);   // RNE
  return (unsigned short)(x >> 16);
}
__device__ __forceinline__ float bf2f(unsigned short u) {
  return __uint_as_float(((unsigned int)u) << 16);
}

// ================= weight/feature fp32->bf16 conversion (one launch) =================
// segments (elem offsets): nf 0 | wih 524288 | ain 622592 | aout 1015808 | f1 1146880
// | f2 1671168 | s1 2195456 | s2 2260992 | whh 2326528 (196608) -> total 2523136
#define CVT_TOT 2523136
__global__ __launch_bounds__(256) void cvt_weights(
    const float* __restrict__ nf, const float* __restrict__ wih,
    const float* __restrict__ ain, const float* __restrict__ aout,
    const float* __restrict__ f1, const float* __restrict__ f2,
    const float* __restrict__ s1, const float* __restrict__ s2,
    const float* __restrict__ whh, unsigned short* __restrict__ dst) {
  const size_t e = ((size_t)blockIdx.x * 256 + threadIdx.x) * 4;
  if (e >= CVT_TOT) return;
  const float* src;
  if (e < 524288)       src = nf   + e;
  else if (e < 622592)  src = wih  + (e - 524288);
  else if (e < 1015808) src = ain  + (e - 622592);
  else if (e < 1146880) src = aout + (e - 1015808);
  else if (e < 1671168) src = f1   + (e - 1146880);
  else if (e < 2195456) src = f2   + (e - 1671168);
  else if (e < 2260992) src = s1   + (e - 2195456);
  else if (e < 2326528) src = s2   + (e - 2260992);
  else                  src = whh  + (e - 2326528);
  const float4 v = *(const float4*)src;
  dst[e + 0] = f2bf(v.x); dst[e + 1] = f2bf(v.y);
  dst[e + 2] = f2bf(v.z); dst[e + 3] = f2bf(v.w);
}

// ================= GRU preprocessing =================
__global__ __launch_bounds__(256) void build_pos(const int* __restrict__ edges,
                                                 int* __restrict__ cnt, int* __restrict__ lists) {
  const int e = blockIdx.x * 256 + threadIdx.x;
  const int d = edges[2 * e + 1];
  const int slot = atomicAdd(&cnt[d], 1);
  if (slot < MAXD) lists[(size_t)d * MAXD + slot] = e;
}

// LDS-staged per-node sort (edge-id order) + emit srcs + degree histogram
__global__ __launch_bounds__(256) void sort_srcs(const int* __restrict__ edges,
                                                 int* __restrict__ cnt,
                                                 const int* __restrict__ lists,
                                                 int* __restrict__ srcs,
                                                 int* __restrict__ hist) {
  __shared__ int Ls[256][65];
  const int t = threadIdx.x;
  const int d = blockIdx.x * 256 + t;
  int c = cnt[d]; if (c > MAXD) c = MAXD;
  for (int i = 0; i < c; ++i) Ls[t][i] = lists[(size_t)d * MAXD + i];
  for (int i = 1; i < c; ++i) {
    const int key = Ls[t][i];
    int j = i - 1;
    while (j >= 0 && Ls[t][j] > key) { Ls[t][j + 1] = Ls[t][j]; --j; }
    Ls[t][j + 1] = key;
  }
  for (int i = 0; i < c; ++i) srcs[(size_t)d * MAXD + i] = edges[2 * Ls[t][i]];
  cnt[d] = c;
  atomicAdd(&hist[c], 1);
}

// block 3: rank cursor prefix; blocks 0-2: gx bias (b_ih + b_hh for R/Z)
__global__ __launch_bounds__(256) void scan_prep(const int* __restrict__ hist,
                                                 int* __restrict__ cursor,
                                                 const float* __restrict__ b_ih,
                                                 const float* __restrict__ b_hh,
                                                 float* __restrict__ bias_gx) {
  if (blockIdx.x == 3) {
    const int t = threadIdx.x;
    if (t <= MAXD) {
      int ss = 0;
      for (int dd = t + 1; dd <= MAXD; ++dd) ss += hist[dd];
      cursor[t] = ss;
    }
  } else {
    const int gt = blockIdx.x * 256 + threadIdx.x;
    if (gt < 768) bias_gx[gt] = b_ih[gt] + (gt < 512 ? b_hh[gt] : 0.0f);
  }
}

__global__ __launch_bounds__(256) void perm_scatter(const int* __restrict__ cnt,
                                                    int* __restrict__ cursor, int* __restrict__ perm) {
  const int d = blockIdx.x * 256 + threadIdx.x;
  const int rank = atomicAdd(&cursor[cnt[d]], 1);
  perm[rank] = d;
}

// ================= generic bf16 MFMA GEMM =================
// C[M,N] = act(A[M,K] @ W[N,K]^T + bias); 64x64 tile, 256 thr, 4 waves (2m x 2n of 32x32)
// OMODE: 0 fp32, 1 fp32+bf16, 2 bf16 only. VT=1: blocks with bn>=512 also write
// transposed bf16 into Vt[(col-512)][row] (fused V-transpose for attention).
template <int ACT, int GS, int OMODE, int VT>
__global__ __launch_bounds__(256) void gemm_bf16(
    const unsigned short* __restrict__ A, const int* __restrict__ gidx,
    const unsigned short* __restrict__ W, const float* __restrict__ bias,
    float* __restrict__ C, unsigned short* __restrict__ Cb,
    unsigned short* __restrict__ Vt, int M, int N, int K) {
  __shared__ unsigned short As[64 * 64];
  __shared__ unsigned short Ws[64 * 64];
  __shared__ int ridx[64];
  const int bm = blockIdx.y * 64, bn = blockIdx.x * 64;
  const int tid = threadIdx.x;
  const int ln = tid & 63, w = tid >> 6;
  const int jc = ln & 15, kq = ln >> 4;
  const int srow = tid >> 2, q = tid & 3;

  if constexpr (GS > 0) {
    if (tid < 64) ridx[tid] = gidx[(size_t)(bm + tid) * GS];
    __syncthreads();
  }
  const size_t arow = (GS > 0) ? (size_t)ridx[srow] : (size_t)(bm + srow);
  const unsigned short* Asrc = A + arow * K + q * 16;
  const unsigned short* Wsrc = W + (size_t)(bn + srow) * K + q * 16;

  f32x4 acc[2][2];
#pragma unroll
  for (int i = 0; i < 2; ++i)
#pragma unroll
    for (int j = 0; j < 2; ++j) acc[i][j] = (f32x4){0.f, 0.f, 0.f, 0.f};
  const int mrow = (w >> 1) * 32, ncol = (w & 1) * 32;
  const int sb0 = (q * 32) ^ ((srow & 7) << 4);
  const int sb1 = (q * 32 + 16) ^ ((srow & 7) << 4);

  for (int k0 = 0; k0 < K; k0 += 64) {
    __syncthreads();
    {
      const short8 a0 = *(const short8*)(Asrc + k0);
      const short8 a1 = *(const short8*)(Asrc + k0 + 8);
      const short8 w0 = *(const short8*)(Wsrc + k0);
      const short8 w1 = *(const short8*)(Wsrc + k0 + 8);
      *(short8*)((char*)As + srow * 128 + sb0) = a0;
      *(short8*)((char*)As + srow * 128 + sb1) = a1;
      *(short8*)((char*)Ws + srow * 128 + sb0) = w0;
      *(short8*)((char*)Ws + srow * 128 + sb1) = w1;
    }
    __syncthreads();
#pragma unroll
    for (int kt = 0; kt < 2; ++kt) {
      const int kb = kt * 64 + kq * 16;
      short8 a[2], bb[2];
#pragma unroll
      for (int i = 0; i < 2; ++i) {
        const int ra = mrow + i * 16 + jc;
        a[i] = *(const short8*)((const char*)As + ra * 128 + (kb ^ ((ra & 7) << 4)));
        const int rb = ncol + i * 16 + jc;
        bb[i] = *(const short8*)((const char*)Ws + rb * 128 + (kb ^ ((rb & 7) << 4)));
      }
#pragma unroll
      for (int mi = 0; mi < 2; ++mi)
#pragma unroll
        for (int ni = 0; ni < 2; ++ni)
          acc[mi][ni] = __builtin_amdgcn_mfma_f32_16x16x32_bf16(a[mi], bb[ni], acc[mi][ni], 0, 0, 0);
    }
  }
#pragma unroll
  for (int mi = 0; mi < 2; ++mi)
#pragma unroll
    for (int ni = 0; ni < 2; ++ni) {
      const int col = bn + ncol + ni * 16 + jc;
      const float bs = bias[col];
      float vals[4];
#pragma unroll
      for (int v = 0; v < 4; ++v) {
        float val = acc[mi][ni][v] + bs;
        if (ACT == 1) val = fmaxf(val, 0.0f);
        vals[v] = val;
      }
#pragma unroll
      for (int v = 0; v < 4; ++v) {
        const int row = bm + mrow + mi * 16 + kq * 4 + v;
        if constexpr (OMODE != 2) C[(size_t)row * N + col] = vals[v];
        if constexpr (OMODE >= 1) Cb[(size_t)row * N + col] = f2bf(vals[v]);
      }
      if constexpr (VT == 1) {
        if (bn >= 512) {
          short4b p;
#pragma unroll
          for (int v = 0; v < 4; ++v) p[v] = (short)f2bf(vals[v]);
          *(short4b*)(Vt + (size_t)(col - 512) * NN + bm + mrow + mi * 16 + kq * 4) = p;
        }
      }
    }
}

// ================= per-block independent GRU, register-resident weights, pipelined =================
// 256 blocks x 512 thr (8 waves). Wave w owns hidden cols [32w,32w+32) x 3 gates:
// 48 short8 = 192 VGPRs (no spill). h in regs. gx for round r+1 prefetched to regs
// during round r (L3 latency hidden under MFMA + elementwise + barriers).
__global__ __launch_bounds__(512, 1) void gru_reg(
    const int* __restrict__ perm, const int* __restrict__ cnt,
    const int* __restrict__ srcs, const unsigned short* __restrict__ gx,
    const unsigned short* __restrict__ whhb, const float* __restrict__ b_hh,
    float* __restrict__ x, unsigned short* __restrict__ xb) {
  const int tid = threadIdx.x;
  const int w = tid >> 6;
  const int ln = tid & 63;
  const int jc = ln & 15, kq = ln >> 4;
  const int grow = tid >> 5, gpart = tid & 31;

  __shared__ unsigned short Ah[GNPB * 256];   // [node][col] bf16, stride 512B, swz
  __shared__ unsigned short Gi[GNPB * 776];   // staged gx rows, stride 1552B
  __shared__ int srcs_s[GNPB][MAXD];
  __shared__ int node_s[GNPB], cnt_s[GNPB];
  __shared__ int Rb_s;

  if (tid < GNPB) {
    const int node = perm[blockIdx.x * GNPB + tid];
    node_s[tid] = node;
    cnt_s[tid] = cnt[node];
  }
  for (int i = tid; i < GNPB * 256; i += 512) Ah[i] = 0;
  __syncthreads();
  for (int i = tid; i < GNPB * MAXD; i += 512)
    srcs_s[i >> 6][i & 63] = srcs[(size_t)node_s[i >> 6] * MAXD + (i & 63)];
  if (tid == 0) {
    int mx = 0;
    for (int i = 0; i < GNPB; ++i) mx = mx > cnt_s[i] ? mx : cnt_s[i];
    Rb_s = mx;
  }

  short8 W[48];
#pragma unroll
  for (int g = 0; g < 3; ++g)
#pragma unroll
    for (int ct = 0; ct < 2; ++ct) {
      const unsigned short* src =
          whhb + (size_t)(g * 256 + w * 32 + ct * 16 + jc) * 256 + kq * 8;
#pragma unroll
      for (int kt = 0; kt < 8; ++kt)
        W[(g * 2 + ct) * 8 + kt] = *(const short8*)(src + kt * 32);
    }
  float bhN[2];
  bhN[0] = b_hh[512 + w * 32 + jc];
  bhN[1] = b_hh[512 + w * 32 + 16 + jc];

  float h[8];
#pragma unroll
  for (int i = 0; i < 8; ++i) h[i] = 0.f;

  __syncthreads();
  const int Rb = Rb_s;
  const int myc = cnt_s[grow];

  // prologue: prefetch round 0's gx rows into registers
  short8 gv0, gv1, gv2;
  {
    const int sn = (0 < myc) ? srcs_s[grow][0] : 0;
    const unsigned short* gs = gx + (size_t)sn * 768 + gpart * 24;
    gv0 = *(const short8*)gs; gv1 = *(const short8*)(gs + 8); gv2 = *(const short8*)(gs + 16);
  }

  for (int r = 0; r < Rb; ++r) {
    // (a) write this round's Gi from prefetched regs (prev barrier ended all readers)
    {
      unsigned short* gdst = Gi + grow * 776 + gpart * 24;
      *(short8*)gdst = gv0;
      *(short8*)(gdst + 8) = gv1;
      *(short8*)(gdst + 16) = gv2;
    }
    // (b) issue next round's gather (hidden under MFMA + barriers + elementwise)
    {
      const int rn = r + 1;
      const int sn = (rn < myc) ? srcs_s[grow][rn] : 0;
      const unsigned short* gs = gx + (size_t)sn * 768 + gpart * 24;
      gv0 = *(const short8*)gs; gv1 = *(const short8*)(gs + 8); gv2 = *(const short8*)(gs + 16);
    }
    // (c) hidden-gate MFMA: Ah @ W^T
    f32x4 acc[6];
#pragma unroll
    for (int i = 0; i < 6; ++i) acc[i] = (f32x4){0.f, 0.f, 0.f, 0.f};
#pragma unroll
    for (int kt = 0; kt < 8; ++kt) {
      const short8 a = *(const short8*)((const char*)Ah + jc * 512 +
                                        ((kt * 64 + kq * 16) ^ ((jc & 7) << 4)));
#pragma unroll
      for (int t = 0; t < 6; ++t)
        acc[t] = __builtin_amdgcn_mfma_f32_16x16x32_bf16(a, W[t * 8 + kt], acc[t], 0, 0, 0);
    }
    __syncthreads();   // Gi visible; all MFMA Ah reads done
    // (e) fused GRU elementwise; thread owns (node=kq*4+v, col=32w+ct*16+jc)
#pragma unroll
    for (int ct = 0; ct < 2; ++ct) {
      const int col = w * 32 + ct * 16 + jc;
#pragma unroll
      for (int v = 0; v < 4; ++v) {
        const int nd = kq * 4 + v;
        if (r < cnt_s[nd]) {
          const float giR = bf2f(Gi[nd * 776 + col]);
          const float giZ = bf2f(Gi[nd * 776 + 256 + col]);
          const float giN = bf2f(Gi[nd * 776 + 512 + col]);
          const float rr = sigf(giR + acc[ct][v]);
          const float zz = sigf(giZ + acc[2 + ct][v]);
          const float nn2 = tanh_fast(giN + rr * (acc[4 + ct][v] + bhN[ct]));
          const float hn = (1.0f - zz) * nn2 + zz * h[ct * 4 + v];
          h[ct * 4 + v] = hn;
          *(unsigned short*)((char*)Ah + nd * 512 + ((col * 2) ^ ((nd & 7) << 4))) = f2bf(hn);
        }
      }
    }
    __syncthreads();   // Ah updates visible before next round's MFMA / Gi rewrite
  }
#pragma unroll
  for (int ct = 0; ct < 2; ++ct) {
    const int col = w * 32 + ct * 16 + jc;
#pragma unroll
    for (int v = 0; v < 4; ++v) {
      const int gnode = node_s[kq * 4 + v];
      x[(size_t)gnode * HDM + col] = h[ct * 4 + v];
      xb[(size_t)gnode * HDM + col] = f2bf(h[ct * 4 + v]);
    }
  }
}

// ================= bf16 MFMA flash attention, KV-split, fixed-max softmax =================
__global__ __launch_bounds__(256) void flash_part(
    const unsigned short* __restrict__ qkvb, const unsigned short* __restrict__ vtb,
    float* __restrict__ Op, float* __restrict__ lp) {
  const int h = blockIdx.y;
  const int qb = blockIdx.x * 64;
  const int z = blockIdx.z;
  const int tid = threadIdx.x;
  const int ln = tid & 63, w = tid >> 6;
  const int jc = ln & 15, kq = ln >> 4;
  __shared__ unsigned short Ks[2][64 * 64];
  __shared__ unsigned short Vts[2][64 * 64];
  __shared__ unsigned short Ps[4][16 * 64];   // per-wave private

  short8 aq[2];
  {
    const unsigned short* qsrc = qkvb + (size_t)(qb + w * 16 + jc) * 768 + h * 64 + kq * 8;
    aq[0] = *(const short8*)qsrc;
    aq[1] = *(const short8*)(qsrc + 32);
  }
  f32x4 accO[4];
#pragma unroll
  for (int nf = 0; nf < 4; ++nf) accO[nf] = (f32x4){0.f, 0.f, 0.f, 0.f};
  float psum[4] = {0.f, 0.f, 0.f, 0.f};

  const int srow = tid >> 2, sc = tid & 3;
  const int swb0 = (sc * 32) ^ ((srow & 7) << 4);
  const int swb1 = (sc * 32 + 16) ^ ((srow & 7) << 4);
  const int k0 = z * 1024;
  unsigned short* Pw = Ps[w];

  short8 kr0, kr1, vr0, vr1;
  {
    const unsigned short* ksrc = qkvb + (size_t)(k0 + srow) * 768 + 256 + h * 64 + sc * 16;
    kr0 = *(const short8*)ksrc; kr1 = *(const short8*)(ksrc + 8);
    const unsigned short* vsrc = vtb + (size_t)(h * 64 + srow) * 4096 + k0 + sc * 16;
    vr0 = *(const short8*)vsrc; vr1 = *(const short8*)(vsrc + 8);
  }

  for (int t = 0; t < 16; ++t) {
    const int cur = t & 1;
    *(short8*)((char*)Ks[cur] + srow * 128 + swb0) = kr0;
    *(short8*)((char*)Ks[cur] + srow * 128 + swb1) = kr1;
    *(short8*)((char*)Vts[cur] + srow * 128 + swb0) = vr0;
    *(short8*)((char*)Vts[cur] + srow * 128 + swb1) = vr1;
    {
      const int tn = t < 15 ? t + 1 : 15;
      const unsigned short* ksrc =
          qkvb + (size_t)(k0 + tn * 64 + srow) * 768 + 256 + h * 64 + sc * 16;
      kr0 = *(const short8*)ksrc; kr1 = *(const short8*)(ksrc + 8);
      const unsigned short* vsrc =
          vtb + (size_t)(h * 64 + srow) * 4096 + k0 + tn * 64 + sc * 16;
      vr0 = *(const short8*)vsrc; vr1 = *(const short8*)(vsrc + 8);
    }
    __syncthreads();
    // ---- S = Q @ K^T ----
    f32x4 s[4];
#pragma unroll
    for (int kt = 0; kt < 4; ++kt) s[kt] = (f32x4){0.f, 0.f, 0.f, 0.f};
    __builtin_amdgcn_s_setprio(1);
#pragma unroll
    for (int ks = 0; ks < 2; ++ks) {
#pragma unroll
      for (int kt = 0; kt < 4; ++kt) {
        const int brow = kt * 16 + jc;
        const short8 bk = *(const short8*)((const char*)Ks[cur] + brow * 128 +
                                           ((ks * 64 + kq * 16) ^ ((brow & 7) << 4)));
        s[kt] = __builtin_amdgcn_mfma_f32_16x16x32_bf16(aq[ks], bk, s[kt], 0, 0, 0);
      }
    }
    __builtin_amdgcn_s_setprio(0);
    // ---- P = exp(S/8 - 8), local psum accumulate, wave-private store ----
#pragma unroll
    for (int kt = 0; kt < 4; ++kt) {
#pragma unroll
      for (int v = 0; v < 4; ++v) {
        const float pv = __expf(s[kt][v] * 0.125f - 8.0f);
        psum[v] += pv;
        const int pr = kq * 4 + v;
        const int cb = kt * 32 + jc * 2;
        *(unsigned short*)((char*)Pw + pr * 128 + (cb ^ ((pr & 7) << 4))) = f2bf(pv);
      }
    }
    asm volatile("s_waitcnt lgkmcnt(0)" ::: "memory");
    __builtin_amdgcn_sched_barrier(0);
    // ---- O += P @ V ----
    __builtin_amdgcn_s_setprio(1);
#pragma unroll
    for (int ks = 0; ks < 2; ++ks) {
      const short8 ap = *(const short8*)((const char*)Pw + jc * 128 +
                                         ((ks * 64 + kq * 16) ^ ((jc & 7) << 4)));
#pragma unroll
      for (int nf = 0; nf < 4; ++nf) {
        const int brow = nf * 16 + jc;
        const short8 bv = *(const short8*)((const char*)Vts[cur] + brow * 128 +
                                           ((ks * 64 + kq * 16) ^ ((brow & 7) << 4)));
        accO[nf] = __builtin_amdgcn_mfma_f32_16x16x32_bf16(ap, bv, accO[nf], 0, 0, 0);
      }
    }
    __builtin_amdgcn_s_setprio(0);
  }
#pragma unroll
  for (int v = 0; v < 4; ++v) {
    float ps = psum[v];
    ps += __shfl_xor(ps, 1);
    ps += __shfl_xor(ps, 2);
    ps += __shfl_xor(ps, 4);
    ps += __shfl_xor(ps, 8);
    psum[v] = ps;
  }
  float* opb = Op + ((size_t)z * NN + qb + w * 16 + kq * 4) * HDM + h * 64 + jc;
#pragma unroll
  for (int nf = 0; nf < 4; ++nf)
#pragma unroll
    for (int v = 0; v < 4; ++v)
      opb[(size_t)v * HDM + nf * 16] = accO[nf][v];
  if (jc == 0) {
#pragma unroll
    for (int v = 0; v < 4; ++v)
      lp[((size_t)z * 4 + h) * NN + qb + w * 16 + kq * 4 + v] = psum[v];
  }
}

// combine: out = (sum_z Op) / (sum_z l)  -> bf16
__global__ __launch_bounds__(256) void attn_combine(const float* __restrict__ Op,
                                                    const float* __restrict__ lp,
                                                    unsigned short* __restrict__ outb) {
  const int row = blockIdx.x * 4 + (threadIdx.x >> 6);
  const int lane = threadIdx.x & 63;
  const int col = lane * 4;
  const int h = col >> 6;
  float l = 0.f;
  float4 o = {0.f, 0.f, 0.f, 0.f};
#pragma unroll
  for (int z = 0; z < NS; ++z) {
    l += lp[((size_t)z * 4 + h) * NN + row];
    const float4 p = *(const float4*)(Op + ((size_t)z * NN + row) * HDM + col);
    o.x += p.x; o.y += p.y; o.z += p.z; o.w += p.w;
  }
  const float inv = 1.0f / l;
  unsigned short* d = outb + (size_t)row * HDM + col;
  d[0] = f2bf(o.x * inv); d[1] = f2bf(o.y * inv);
  d[2] = f2bf(o.z * inv); d[3] = f2bf(o.w * inv);
}

// ================= x = LN(x + a); emits fp32 x and bf16 xb =================
__global__ __launch_bounds__(256) void ln_residual(float* __restrict__ x,
                                                   const float* __restrict__ a,
                                                   const float* __restrict__ g,
                                                   const float* __restrict__ b,
                                                   unsigned short* __restrict__ xb) {
  const int lane = threadIdx.x & 63;
  const int row = blockIdx.x * 4 + (threadIdx.x >> 6);
  float v[4];
  float s = 0.0f;
#pragma unroll
  for (int j = 0; j < 4; j++) {
    const int col = j * 64 + lane;
    v[j] = x[(size_t)row * HDM + col] + a[(size_t)row * HDM + col];
    s += v[j];
  }
#pragma unroll
  for (int off = 32; off > 0; off >>= 1) s += __shfl_xor(s, off);
  const float mu = s * (1.0f / HDM);
  float vs = 0.0f;
#pragma unroll
  for (int j = 0; j < 4; j++) {
    const float d = v[j] - mu;
    vs += d * d;
  }
#pragma unroll
  for (int off = 32; off > 0; off >>= 1) vs += __shfl_xor(vs, off);
  const float rinv = 1.0f / sqrtf(vs * (1.0f / HDM) + 1e-5f);
#pragma unroll
  for (int j = 0; j < 4; j++) {
    const int col = j * 64 + lane;
    const float val = g[col] * (v[j] - mu) * rinv + b[col];
    x[(size_t)row * HDM + col] = val;
    xb[(size_t)row * HDM + col] = f2bf(val);
  }
}

// ================= fused edge predictor: gather-cat + MLP + sigmoid =================
// 1 block per candidate, 256 threads.
__global__ __launch_bounds__(256) void ep_fused(const float* __restrict__ refined,
                                                const int* __restrict__ cand,
                                                const float* __restrict__ e1w,
                                                const float* __restrict__ e1b,
                                                const float* __restrict__ e2w,
                                                const float* __restrict__ e2b,
                                                float* __restrict__ out) {
  const int c = blockIdx.x;
  const int t = threadIdx.x;
  __shared__ float hrow[512];
  __shared__ float eph_s[256];
  const int n0 = cand[2 * c], n1 = cand[2 * c + 1];
  hrow[t] = refined[(size_t)n0 * HDM + t];
  hrow[256 + t] = refined[(size_t)n1 * HDM + t];
  __syncthreads();
  const float4* wrow = (const float4*)(e1w + (size_t)t * 512);
  float s = 0.f;
#pragma unroll 8
  for (int k = 0; k < 128; ++k) {
    const float4 w4 = wrow[k];
    const float4 h4 = *(const float4*)(hrow + k * 4);
    s += w4.x * h4.x + w4.y * h4.y + w4.z * h4.z + w4.w * h4.w;
  }
  eph_s[t] = fmaxf(s + e1b[t], 0.0f);
  __syncthreads();
  if (t < 64) {
    float p = 0.f;
#pragma unroll
    for (int j = 0; j < 4; ++j) p += eph_s[j * 64 + t] * e2w[j * 64 + t];
#pragma unroll
    for (int off = 32; off > 0; off >>= 1) p += __shfl_xor(p, off);
    if (t == 0) out[c] = 1.0f / (1.0f + __expf(-(p + e2b[0])));
  }
}

extern "C" void kernel_launch(void* const* d_in, const int* in_sizes, int n_in,
                              void* d_out, int out_size, void* d_ws, size_t ws_size,
                              hipStream_t stream) {
  (void)in_sizes; (void)n_in; (void)out_size; (void)ws_size;
  const float* nf    = (const float*)d_in[0];
  const int*   edges = (const int*)d_in[1];
  const int*   cand  = (const int*)d_in[2];
  const float* w_ih  = (const float*)d_in[3];
  const float* w_hh  = (const float*)d_in[4];
  const float* b_ih  = (const float*)d_in[5];
  const float* b_hh  = (const float*)d_in[6];
  const float* ain_w = (const float*)d_in[7];
  const float* ain_b = (const float*)d_in[8];
  const float* aout_w = (const float*)d_in[9];
  const float* aout_b = (const float*)d_in[10];
  const float* ln1g = (const float*)d_in[11];
  const float* ln1b = (const float*)d_in[12];
  const float* f1w  = (const float*)d_in[13];
  const float* f1b  = (const float*)d_in[14];
  const float* f2w  = (const float*)d_in[15];
  const float* f2b  = (const float*)d_in[16];
  const float* ln2g = (const float*)d_in[17];
  const float* ln2b = (const float*)d_in[18];
  const float* s1w  = (const float*)d_in[19];
  const float* s1b  = (const float*)d_in[20];
  const float* s2w  = (const float*)d_in[21];
  const float* s2b  = (const float*)d_in[22];
  const float* e1w  = (const float*)d_in[23];
  const float* e1b  = (const float*)d_in[24];
  const float* e2w  = (const float*)d_in[25];
  const float* e2b  = (const float*)d_in[26];
  float* out = (float*)d_out;

  char* wp = (char*)d_ws;
  float* x        = (float*)wp; wp += (size_t)NN * HDM * 4;            // 4 MB
  unsigned short* xb = (unsigned short*)wp; wp += (size_t)NN * HDM * 2; // 2 MB
  unsigned short* wseg = (unsigned short*)wp; wp += (size_t)CVT_TOT * 2; // 5.05 MB
  int* cnt        = (int*)wp;  wp += (size_t)NN * 4;
  int* lists      = (int*)wp;  wp += (size_t)NN * MAXD * 4;            // 1 MB
  int* srcs       = (int*)wp;  wp += (size_t)NN * MAXD * 4;            // 1 MB
  int* meta       = (int*)wp;  wp += 256 * 4;
  float* bias_gx  = (float*)wp; wp += 1024 * 4;
  int* perm       = (int*)wp;  wp += (size_t)NN * 4;
  unsigned short* gx = (unsigned short*)wp; wp += (size_t)NN * 768 * 2; // 6 MB
  char* uni       = wp;        // transformer buffers
  unsigned short* qkvb   = (unsigned short*)uni;                      // 6 MB
  unsigned short* vtb    = (unsigned short*)(uni + 6291456);          // 2 MB
  float* abuf    = (float*)(uni + 8388608);                           // 4 MB
  unsigned short* abuf_b = (unsigned short*)(uni + 12582912);         // 2 MB
  float* fbuf    = (float*)(uni + 14680064);                          // 16 MB (also attn Op)
  float* Op      = fbuf;
  unsigned short* fbuf_b = (unsigned short*)(uni + 31457280);         // 8 MB (also attn lp)
  float* lp      = (float*)(uni + 31457280);                          // 256 KB
  float* refined = (float*)(uni + 39845888);                          // 4 MB

  unsigned short* nf_b  = wseg;
  unsigned short* wihb  = wseg + 524288;
  unsigned short* ainb  = wseg + 622592;
  unsigned short* aoutb = wseg + 1015808;
  unsigned short* f1b_  = wseg + 1146880;
  unsigned short* f2b_  = wseg + 1671168;
  unsigned short* s1b_  = wseg + 2195456;
  unsigned short* s2b_  = wseg + 2260992;
  unsigned short* whhb  = wseg + 2326528;

  int* hist   = meta;
  int* cursor = meta + 128;

  hipMemsetAsync(cnt, 0, (size_t)NN * 4, stream);
  hipMemsetAsync(meta, 0, 256 * 4, stream);

  cvt_weights<<<2464, 256, 0, stream>>>(nf, w_ih, ain_w, aout_w, f1w, f2w, s1w, s2w, w_hh, wseg);
  build_pos<<<NE / 256, 256, 0, stream>>>(edges, cnt, lists);
  sort_srcs<<<NN / 256, 256, 0, stream>>>(edges, cnt, lists, srcs, hist);
  scan_prep<<<4, 256, 0, stream>>>(hist, cursor, b_ih, b_hh, bias_gx);
  perm_scatter<<<NN / 256, 256, 0, stream>>>(cnt, cursor, perm);

  // gx[n] = bf16( nf[n] @ w_ih^T + b_ih (+ b_hh R/Z) )   [NN,768], K=128
  gemm_bf16<0, 0, 2, 0><<<dim3(12, NN / 64), 256, 0, stream>>>(
      nf_b, nullptr, wihb, bias_gx, nullptr, gx, nullptr, NN, 768, IND);
  gru_reg<<<NN / GNPB, 512, 0, stream>>>(perm, cnt, srcs, gx, whhb, b_hh, x, xb);

  for (int l = 0; l < NL; l++) {
    gemm_bf16<0, 0, 2, 1><<<dim3(12, 64), 256, 0, stream>>>(
        xb, nullptr, ainb + (size_t)l * 196608, ain_b + l * 768, nullptr, qkvb, vtb, NN, 768, HDM);
    flash_part<<<dim3(64, 4, NS), 256, 0, stream>>>(qkvb, vtb, Op, lp);
    attn_combine<<<NN / 4, 256, 0, stream>>>(Op, lp, abuf_b);
    gemm_bf16<0, 0, 0, 0><<<dim3(4, 64), 256, 0, stream>>>(
        abuf_b, nullptr, aoutb + (size_t)l * 65536, aout_b + l * 256, fbuf, nullptr, nullptr, NN, 256, HDM);
    ln_residual<<<NN / 4, 256, 0, stream>>>(x, fbuf, ln1g + l * 256, ln1b + l * 256, xb);
    gemm_bf16<1, 0, 2, 0><<<dim3(16, 64), 256, 0, stream>>>(
        xb, nullptr, f1b_ + (size_t)l * 262144, f1b + l * 1024, nullptr, fbuf_b, nullptr, NN, 1024, HDM);
    gemm_bf16<0, 0, 0, 0><<<dim3(4, 64), 256, 0, stream>>>(
        fbuf_b, nullptr, f2b_ + (size_t)l * 262144, f2b + l * 256, abuf, nullptr, nullptr, NN, 256, 1024);
    ln_residual<<<NN / 4, 256, 0, stream>>>(x, abuf, ln2g + l * 256, ln2b + l * 256, xb);
  }

  gemm_bf16<1, 0, 1, 0><<<dim3(4, 64), 256, 0, stream>>>(
      xb, nullptr, s1b_, s1b, abuf, abuf_b, nullptr, NN, 256, HDM);
  gemm_bf16<0, 0, 0, 0><<<dim3(4, 64), 256, 0, stream>>>(
      abuf_b, nullptr, s2b_, s2b, refined, nullptr, nullptr, NN, 256, HDM);
  ep_fused<<<NCAND, 256, 0, stream>>>(refined, cand, e1w, e1b, e2w, e2b, out);
}

// Round 8
// 355.885 us; speedup vs baseline: 15.2328x; 1.0076x over previous
//
#include <hip/hip_runtime.h>
#include <math.h>

#define NN     4096
#define NE     32768
#define NCAND  64
#define IND    128
#define HDM    256
#define NL     2
#define MAXD   64
#define GNPB   16   // GRU nodes per block
#define NS     4    // attention KV splits

typedef __attribute__((ext_vector_type(8))) short short8;
typedef __attribute__((ext_vector_type(4))) short short4b;
typedef __attribute__((ext_vector_type(4))) float f32x4;

__device__ __forceinline__ float sigf(float x) { return 1.0f / (1.0f + __expf(-x)); }
__device__ __forceinline__ float tanh_fast(float x) {
  float e = __expf(-2.0f * fabsf(x));
  float r = (1.0f - e) / (1.0f + e);
  return x < 0.0f ? -r : r;
}
__device__ __forceinline__ unsigned short f2bf(float f) {
  unsigned int x = __float_as_uint(f);
  x += 0x7fffu + ((x >> 16) & 1u);   // RNE
  return (unsigned short)(x >> 16);
}
__device__ __forceinline__ float bf2f(unsigned short u) {
  return __uint_as_float(((unsigned int)u) << 16);
}

// ================= weight/feature fp32->bf16 conversion (one launch) =================
// segments (elem offsets): nf 0 | wih 524288 | ain 622592 | aout 1015808 | f1 1146880
// | f2 1671168 | s1 2195456 | s2 2260992 | whh 2326528 (196608) -> total 2523136
#define CVT_TOT 2523136
__global__ __launch_bounds__(256) void cvt_weights(
    const float* __restrict__ nf, const float* __restrict__ wih,
    const float* __restrict__ ain, const float* __restrict__ aout,
    const float* __restrict__ f1, const float* __restrict__ f2,
    const float* __restrict__ s1, const float* __restrict__ s2,
    const float* __restrict__ whh, unsigned short* __restrict__ dst) {
  const size_t e = ((size_t)blockIdx.x * 256 + threadIdx.x) * 4;
  if (e >= CVT_TOT) return;
  const float* src;
  if (e < 524288)       src = nf   + e;
  else if (e < 622592)  src = wih  + (e - 524288);
  else if (e < 1015808) src = ain  + (e - 622592);
  else if (e < 1146880) src = aout + (e - 1015808);
  else if (e < 1671168) src = f1   + (e - 1146880);
  else if (e < 2195456) src = f2   + (e - 1671168);
  else if (e < 2260992) src = s1   + (e - 2195456);
  else if (e < 2326528) src = s2   + (e - 2260992);
  else                  src = whh  + (e - 2326528);
  const float4 v = *(const float4*)src;
  dst[e + 0] = f2bf(v.x); dst[e + 1] = f2bf(v.y);
  dst[e + 2] = f2bf(v.z); dst[e + 3] = f2bf(v.w);
}

// ================= GRU preprocessing =================
__global__ __launch_bounds__(256) void build_pos(const int* __restrict__ edges,
                                                 int* __restrict__ cnt, int* __restrict__ lists) {
  const int e = blockIdx.x * 256 + threadIdx.x;
  const int d = edges[2 * e + 1];
  const int slot = atomicAdd(&cnt[d], 1);
  if (slot < MAXD) lists[(size_t)d * MAXD + slot] = e;
}

// LDS-staged per-node sort (edge-id order) + emit srcs + degree histogram
__global__ __launch_bounds__(256) void sort_srcs(const int* __restrict__ edges,
                                                 int* __restrict__ cnt,
                                                 const int* __restrict__ lists,
                                                 int* __restrict__ srcs,
                                                 int* __restrict__ hist) {
  __shared__ int Ls[256][65];
  const int t = threadIdx.x;
  const int d = blockIdx.x * 256 + t;
  int c = cnt[d]; if (c > MAXD) c = MAXD;
  for (int i = 0; i < c; ++i) Ls[t][i] = lists[(size_t)d * MAXD + i];
  for (int i = 1; i < c; ++i) {
    const int key = Ls[t][i];
    int j = i - 1;
    while (j >= 0 && Ls[t][j] > key) { Ls[t][j + 1] = Ls[t][j]; --j; }
    Ls[t][j + 1] = key;
  }
  for (int i = 0; i < c; ++i) srcs[(size_t)d * MAXD + i] = edges[2 * Ls[t][i]];
  cnt[d] = c;
  atomicAdd(&hist[c], 1);
}

// block 3: rank cursor prefix; blocks 0-2: gx bias (b_ih + b_hh for R/Z)
__global__ __launch_bounds__(256) void scan_prep(const int* __restrict__ hist,
                                                 int* __restrict__ cursor,
                                                 const float* __restrict__ b_ih,
                                                 const float* __restrict__ b_hh,
                                                 float* __restrict__ bias_gx) {
  if (blockIdx.x == 3) {
    const int t = threadIdx.x;
    if (t <= MAXD) {
      int ss = 0;
      for (int dd = t + 1; dd <= MAXD; ++dd) ss += hist[dd];
      cursor[t] = ss;
    }
  } else {
    const int gt = blockIdx.x * 256 + threadIdx.x;
    if (gt < 768) bias_gx[gt] = b_ih[gt] + (gt < 512 ? b_hh[gt] : 0.0f);
  }
}

__global__ __launch_bounds__(256) void perm_scatter(const int* __restrict__ cnt,
                                                    int* __restrict__ cursor, int* __restrict__ perm) {
  const int d = blockIdx.x * 256 + threadIdx.x;
  const int rank = atomicAdd(&cursor[cnt[d]], 1);
  perm[rank] = d;
}

// ================= generic bf16 MFMA GEMM =================
// C[M,N] = act(A[M,K] @ W[N,K]^T + bias); 64x64 tile, 256 thr, 4 waves (2m x 2n of 32x32)
// OMODE: 0 fp32, 1 fp32+bf16, 2 bf16 only. VT=1: blocks with bn>=512 also write
// transposed bf16 into Vt[(col-512)][row] (fused V-transpose for attention).
template <int ACT, int GS, int OMODE, int VT>
__global__ __launch_bounds__(256) void gemm_bf16(
    const unsigned short* __restrict__ A, const int* __restrict__ gidx,
    const unsigned short* __restrict__ W, const float* __restrict__ bias,
    float* __restrict__ C, unsigned short* __restrict__ Cb,
    unsigned short* __restrict__ Vt, int M, int N, int K) {
  __shared__ unsigned short As[64 * 64];
  __shared__ unsigned short Ws[64 * 64];
  __shared__ int ridx[64];
  const int bm = blockIdx.y * 64, bn = blockIdx.x * 64;
  const int tid = threadIdx.x;
  const int ln = tid & 63, w = tid >> 6;
  const int jc = ln & 15, kq = ln >> 4;
  const int srow = tid >> 2, q = tid & 3;

  if constexpr (GS > 0) {
    if (tid < 64) ridx[tid] = gidx[(size_t)(bm + tid) * GS];
    __syncthreads();
  }
  const size_t arow = (GS > 0) ? (size_t)ridx[srow] : (size_t)(bm + srow);
  const unsigned short* Asrc = A + arow * K + q * 16;
  const unsigned short* Wsrc = W + (size_t)(bn + srow) * K + q * 16;

  f32x4 acc[2][2];
#pragma unroll
  for (int i = 0; i < 2; ++i)
#pragma unroll
    for (int j = 0; j < 2; ++j) acc[i][j] = (f32x4){0.f, 0.f, 0.f, 0.f};
  const int mrow = (w >> 1) * 32, ncol = (w & 1) * 32;
  const int sb0 = (q * 32) ^ ((srow & 7) << 4);
  const int sb1 = (q * 32 + 16) ^ ((srow & 7) << 4);

  for (int k0 = 0; k0 < K; k0 += 64) {
    __syncthreads();
    {
      const short8 a0 = *(const short8*)(Asrc + k0);
      const short8 a1 = *(const short8*)(Asrc + k0 + 8);
      const short8 w0 = *(const short8*)(Wsrc + k0);
      const short8 w1 = *(const short8*)(Wsrc + k0 + 8);
      *(short8*)((char*)As + srow * 128 + sb0) = a0;
      *(short8*)((char*)As + srow * 128 + sb1) = a1;
      *(short8*)((char*)Ws + srow * 128 + sb0) = w0;
      *(short8*)((char*)Ws + srow * 128 + sb1) = w1;
    }
    __syncthreads();
#pragma unroll
    for (int kt = 0; kt < 2; ++kt) {
      const int kb = kt * 64 + kq * 16;
      short8 a[2], bb[2];
#pragma unroll
      for (int i = 0; i < 2; ++i) {
        const int ra = mrow + i * 16 + jc;
        a[i] = *(const short8*)((const char*)As + ra * 128 + (kb ^ ((ra & 7) << 4)));
        const int rb = ncol + i * 16 + jc;
        bb[i] = *(const short8*)((const char*)Ws + rb * 128 + (kb ^ ((rb & 7) << 4)));
      }
#pragma unroll
      for (int mi = 0; mi < 2; ++mi)
#pragma unroll
        for (int ni = 0; ni < 2; ++ni)
          acc[mi][ni] = __builtin_amdgcn_mfma_f32_16x16x32_bf16(a[mi], bb[ni], acc[mi][ni], 0, 0, 0);
    }
  }
#pragma unroll
  for (int mi = 0; mi < 2; ++mi)
#pragma unroll
    for (int ni = 0; ni < 2; ++ni) {
      const int col = bn + ncol + ni * 16 + jc;
      const float bs = bias[col];
      float vals[4];
#pragma unroll
      for (int v = 0; v < 4; ++v) {
        float val = acc[mi][ni][v] + bs;
        if (ACT == 1) val = fmaxf(val, 0.0f);
        vals[v] = val;
      }
#pragma unroll
      for (int v = 0; v < 4; ++v) {
        const int row = bm + mrow + mi * 16 + kq * 4 + v;
        if constexpr (OMODE != 2) C[(size_t)row * N + col] = vals[v];
        if constexpr (OMODE >= 1) Cb[(size_t)row * N + col] = f2bf(vals[v]);
      }
      if constexpr (VT == 1) {
        if (bn >= 512) {
          short4b p;
#pragma unroll
          for (int v = 0; v < 4; ++v) p[v] = (short)f2bf(vals[v]);
          *(short4b*)(Vt + (size_t)(col - 512) * NN + bm + mrow + mi * 16 + kq * 4) = p;
        }
      }
    }
}

// ================= per-block independent GRU, register-resident weights, pipelined =================
// 256 blocks x 512 thr (8 waves). Wave w owns hidden cols [32w,32w+32) x 3 gates:
// 48 short8 = 192 VGPRs. waves_per_eu(2,2) pins the 256-VGPR budget (1 block/CU) so
// W does NOT spill (round-7 bug: compiler chose 128 regs -> scratch spill, 20MB writes).
__global__ __launch_bounds__(512) __attribute__((amdgpu_waves_per_eu(2, 2))) void gru_reg(
    const int* __restrict__ perm, const int* __restrict__ cnt,
    const int* __restrict__ srcs, const unsigned short* __restrict__ gx,
    const unsigned short* __restrict__ whhb, const float* __restrict__ b_hh,
    float* __restrict__ x, unsigned short* __restrict__ xb) {
  const int tid = threadIdx.x;
  const int w = tid >> 6;
  const int ln = tid & 63;
  const int jc = ln & 15, kq = ln >> 4;
  const int grow = tid >> 5, gpart = tid & 31;

  __shared__ unsigned short Ah[GNPB * 256];   // [node][col] bf16, stride 512B, swz
  __shared__ unsigned short Gi[GNPB * 776];   // staged gx rows, stride 1552B
  __shared__ int srcs_s[GNPB][MAXD];
  __shared__ int node_s[GNPB], cnt_s[GNPB];
  __shared__ int Rb_s;

  if (tid < GNPB) {
    const int node = perm[blockIdx.x * GNPB + tid];
    node_s[tid] = node;
    cnt_s[tid] = cnt[node];
  }
  for (int i = tid; i < GNPB * 256; i += 512) Ah[i] = 0;
  __syncthreads();
  for (int i = tid; i < GNPB * MAXD; i += 512)
    srcs_s[i >> 6][i & 63] = srcs[(size_t)node_s[i >> 6] * MAXD + (i & 63)];
  if (tid == 0) {
    int mx = 0;
    for (int i = 0; i < GNPB; ++i) mx = mx > cnt_s[i] ? mx : cnt_s[i];
    Rb_s = mx;
  }

  short8 W[48];
#pragma unroll
  for (int g = 0; g < 3; ++g)
#pragma unroll
    for (int ct = 0; ct < 2; ++ct) {
      const unsigned short* src =
          whhb + (size_t)(g * 256 + w * 32 + ct * 16 + jc) * 256 + kq * 8;
#pragma unroll
      for (int kt = 0; kt < 8; ++kt)
        W[(g * 2 + ct) * 8 + kt] = *(const short8*)(src + kt * 32);
    }
  float bhN[2];
  bhN[0] = b_hh[512 + w * 32 + jc];
  bhN[1] = b_hh[512 + w * 32 + 16 + jc];

  float h[8];
#pragma unroll
  for (int i = 0; i < 8; ++i) h[i] = 0.f;

  __syncthreads();
  const int Rb = Rb_s;
  const int myc = cnt_s[grow];

  // prologue: prefetch round 0's gx rows into registers
  short8 gv0, gv1, gv2;
  {
    const int sn = (0 < myc) ? srcs_s[grow][0] : 0;
    const unsigned short* gs = gx + (size_t)sn * 768 + gpart * 24;
    gv0 = *(const short8*)gs; gv1 = *(const short8*)(gs + 8); gv2 = *(const short8*)(gs + 16);
  }

  for (int r = 0; r < Rb; ++r) {
    // (a) write this round's Gi from prefetched regs (prev barrier ended all readers)
    {
      unsigned short* gdst = Gi + grow * 776 + gpart * 24;
      *(short8*)gdst = gv0;
      *(short8*)(gdst + 8) = gv1;
      *(short8*)(gdst + 16) = gv2;
    }
    // (b) issue next round's gather (hidden under MFMA + barriers + elementwise)
    {
      const int rn = r + 1;
      const int sn = (rn < myc) ? srcs_s[grow][rn] : 0;
      const unsigned short* gs = gx + (size_t)sn * 768 + gpart * 24;
      gv0 = *(const short8*)gs; gv1 = *(const short8*)(gs + 8); gv2 = *(const short8*)(gs + 16);
    }
    // (c) hidden-gate MFMA: Ah @ W^T
    f32x4 acc[6];
#pragma unroll
    for (int i = 0; i < 6; ++i) acc[i] = (f32x4){0.f, 0.f, 0.f, 0.f};
#pragma unroll
    for (int kt = 0; kt < 8; ++kt) {
      const short8 a = *(const short8*)((const char*)Ah + jc * 512 +
                                        ((kt * 64 + kq * 16) ^ ((jc & 7) << 4)));
#pragma unroll
      for (int t = 0; t < 6; ++t)
        acc[t] = __builtin_amdgcn_mfma_f32_16x16x32_bf16(a, W[t * 8 + kt], acc[t], 0, 0, 0);
    }
    __syncthreads();   // Gi visible; all MFMA Ah reads done
    // (e) fused GRU elementwise; thread owns (node=kq*4+v, col=32w+ct*16+jc)
#pragma unroll
    for (int ct = 0; ct < 2; ++ct) {
      const int col = w * 32 + ct * 16 + jc;
#pragma unroll
      for (int v = 0; v < 4; ++v) {
        const int nd = kq * 4 + v;
        if (r < cnt_s[nd]) {
          const float giR = bf2f(Gi[nd * 776 + col]);
          const float giZ = bf2f(Gi[nd * 776 + 256 + col]);
          const float giN = bf2f(Gi[nd * 776 + 512 + col]);
          const float rr = sigf(giR + acc[ct][v]);
          const float zz = sigf(giZ + acc[2 + ct][v]);
          const float nn2 = tanh_fast(giN + rr * (acc[4 + ct][v] + bhN[ct]));
          const float hn = (1.0f - zz) * nn2 + zz * h[ct * 4 + v];
          h[ct * 4 + v] = hn;
          *(unsigned short*)((char*)Ah + nd * 512 + ((col * 2) ^ ((nd & 7) << 4))) = f2bf(hn);
        }
      }
    }
    __syncthreads();   // Ah updates visible before next round's MFMA / Gi rewrite
  }
#pragma unroll
  for (int ct = 0; ct < 2; ++ct) {
    const int col = w * 32 + ct * 16 + jc;
#pragma unroll
    for (int v = 0; v < 4; ++v) {
      const int gnode = node_s[kq * 4 + v];
      x[(size_t)gnode * HDM + col] = h[ct * 4 + v];
      xb[(size_t)gnode * HDM + col] = f2bf(h[ct * 4 + v]);
    }
  }
}

// ================= bf16 MFMA flash attention, KV-split, fixed-max softmax =================
__global__ __launch_bounds__(256) void flash_part(
    const unsigned short* __restrict__ qkvb, const unsigned short* __restrict__ vtb,
    float* __restrict__ Op, float* __restrict__ lp) {
  const int h = blockIdx.y;
  const int qb = blockIdx.x * 64;
  const int z = blockIdx.z;
  const int tid = threadIdx.x;
  const int ln = tid & 63, w = tid >> 6;
  const int jc = ln & 15, kq = ln >> 4;
  __shared__ unsigned short Ks[2][64 * 64];
  __shared__ unsigned short Vts[2][64 * 64];
  __shared__ unsigned short Ps[4][16 * 64];   // per-wave private

  short8 aq[2];
  {
    const unsigned short* qsrc = qkvb + (size_t)(qb + w * 16 + jc) * 768 + h * 64 + kq * 8;
    aq[0] = *(const short8*)qsrc;
    aq[1] = *(const short8*)(qsrc + 32);
  }
  f32x4 accO[4];
#pragma unroll
  for (int nf = 0; nf < 4; ++nf) accO[nf] = (f32x4){0.f, 0.f, 0.f, 0.f};
  float psum[4] = {0.f, 0.f, 0.f, 0.f};

  const int srow = tid >> 2, sc = tid & 3;
  const int swb0 = (sc * 32) ^ ((srow & 7) << 4);
  const int swb1 = (sc * 32 + 16) ^ ((srow & 7) << 4);
  const int k0 = z * 1024;
  unsigned short* Pw = Ps[w];

  short8 kr0, kr1, vr0, vr1;
  {
    const unsigned short* ksrc = qkvb + (size_t)(k0 + srow) * 768 + 256 + h * 64 + sc * 16;
    kr0 = *(const short8*)ksrc; kr1 = *(const short8*)(ksrc + 8);
    const unsigned short* vsrc = vtb + (size_t)(h * 64 + srow) * 4096 + k0 + sc * 16;
    vr0 = *(const short8*)vsrc; vr1 = *(const short8*)(vsrc + 8);
  }

  for (int t = 0; t < 16; ++t) {
    const int cur = t & 1;
    *(short8*)((char*)Ks[cur] + srow * 128 + swb0) = kr0;
    *(short8*)((char*)Ks[cur] + srow * 128 + swb1) = kr1;
    *(short8*)((char*)Vts[cur] + srow * 128 + swb0) = vr0;
    *(short8*)((char*)Vts[cur] + srow * 128 + swb1) = vr1;
    {
      const int tn = t < 15 ? t + 1 : 15;
      const unsigned short* ksrc =
          qkvb + (size_t)(k0 + tn * 64 + srow) * 768 + 256 + h * 64 + sc * 16;
      kr0 = *(const short8*)ksrc; kr1 = *(const short8*)(ksrc + 8);
      const unsigned short* vsrc =
          vtb + (size_t)(h * 64 + srow) * 4096 + k0 + tn * 64 + sc * 16;
      vr0 = *(const short8*)vsrc; vr1 = *(const short8*)(vsrc + 8);
    }
    __syncthreads();
    // ---- S = Q @ K^T ----
    f32x4 s[4];
#pragma unroll
    for (int kt = 0; kt < 4; ++kt) s[kt] = (f32x4){0.f, 0.f, 0.f, 0.f};
    __builtin_amdgcn_s_setprio(1);
#pragma unroll
    for (int ks = 0; ks < 2; ++ks) {
#pragma unroll
      for (int kt = 0; kt < 4; ++kt) {
        const int brow = kt * 16 + jc;
        const short8 bk = *(const short8*)((const char*)Ks[cur] + brow * 128 +
                                           ((ks * 64 + kq * 16) ^ ((brow & 7) << 4)));
        s[kt] = __builtin_amdgcn_mfma_f32_16x16x32_bf16(aq[ks], bk, s[kt], 0, 0, 0);
      }
    }
    __builtin_amdgcn_s_setprio(0);
    // ---- P = exp(S/8 - 8), local psum accumulate, wave-private store ----
#pragma unroll
    for (int kt = 0; kt < 4; ++kt) {
#pragma unroll
      for (int v = 0; v < 4; ++v) {
        const float pv = __expf(s[kt][v] * 0.125f - 8.0f);
        psum[v] += pv;
        const int pr = kq * 4 + v;
        const int cb = kt * 32 + jc * 2;
        *(unsigned short*)((char*)Pw + pr * 128 + (cb ^ ((pr & 7) << 4))) = f2bf(pv);
      }
    }
    asm volatile("s_waitcnt lgkmcnt(0)" ::: "memory");
    __builtin_amdgcn_sched_barrier(0);
    // ---- O += P @ V ----
    __builtin_amdgcn_s_setprio(1);
#pragma unroll
    for (int ks = 0; ks < 2; ++ks) {
      const short8 ap = *(const short8*)((const char*)Pw + jc * 128 +
                                         ((ks * 64 + kq * 16) ^ ((jc & 7) << 4)));
#pragma unroll
      for (int nf = 0; nf < 4; ++nf) {
        const int brow = nf * 16 + jc;
        const short8 bv = *(const short8*)((const char*)Vts[cur] + brow * 128 +
                                           ((ks * 64 + kq * 16) ^ ((brow & 7) << 4)));
        accO[nf] = __builtin_amdgcn_mfma_f32_16x16x32_bf16(ap, bv, accO[nf], 0, 0, 0);
      }
    }
    __builtin_amdgcn_s_setprio(0);
  }
#pragma unroll
  for (int v = 0; v < 4; ++v) {
    float ps = psum[v];
    ps += __shfl_xor(ps, 1);
    ps += __shfl_xor(ps, 2);
    ps += __shfl_xor(ps, 4);
    ps += __shfl_xor(ps, 8);
    psum[v] = ps;
  }
  float* opb = Op + ((size_t)z * NN + qb + w * 16 + kq * 4) * HDM + h * 64 + jc;
#pragma unroll
  for (int nf = 0; nf < 4; ++nf)
#pragma unroll
    for (int v = 0; v < 4; ++v)
      opb[(size_t)v * HDM + nf * 16] = accO[nf][v];
  if (jc == 0) {
#pragma unroll
    for (int v = 0; v < 4; ++v)
      lp[((size_t)z * 4 + h) * NN + qb + w * 16 + kq * 4 + v] = psum[v];
  }
}

// combine: out = (sum_z Op) / (sum_z l)  -> bf16
__global__ __launch_bounds__(256) void attn_combine(const float* __restrict__ Op,
                                                    const float* __restrict__ lp,
                                                    unsigned short* __restrict__ outb) {
  const int row = blockIdx.x * 4 + (threadIdx.x >> 6);
  const int lane = threadIdx.x & 63;
  const int col = lane * 4;
  const int h = col >> 6;
  float l = 0.f;
  float4 o = {0.f, 0.f, 0.f, 0.f};
#pragma unroll
  for (int z = 0; z < NS; ++z) {
    l += lp[((size_t)z * 4 + h) * NN + row];
    const float4 p = *(const float4*)(Op + ((size_t)z * NN + row) * HDM + col);
    o.x += p.x; o.y += p.y; o.z += p.z; o.w += p.w;
  }
  const float inv = 1.0f / l;
  unsigned short* d = outb + (size_t)row * HDM + col;
  d[0] = f2bf(o.x * inv); d[1] = f2bf(o.y * inv);
  d[2] = f2bf(o.z * inv); d[3] = f2bf(o.w * inv);
}

// ================= x = LN(x + a); emits fp32 x and bf16 xb =================
__global__ __launch_bounds__(256) void ln_residual(float* __restrict__ x,
                                                   const float* __restrict__ a,
                                                   const float* __restrict__ g,
                                                   const float* __restrict__ b,
                                                   unsigned short* __restrict__ xb) {
  const int lane = threadIdx.x & 63;
  const int row = blockIdx.x * 4 + (threadIdx.x >> 6);
  float v[4];
  float s = 0.0f;
#pragma unroll
  for (int j = 0; j < 4; j++) {
    const int col = j * 64 + lane;
    v[j] = x[(size_t)row * HDM + col] + a[(size_t)row * HDM + col];
    s += v[j];
  }
#pragma unroll
  for (int off = 32; off > 0; off >>= 1) s += __shfl_xor(s, off);
  const float mu = s * (1.0f / HDM);
  float vs = 0.0f;
#pragma unroll
  for (int j = 0; j < 4; j++) {
    const float d = v[j] - mu;
    vs += d * d;
  }
#pragma unroll
  for (int off = 32; off > 0; off >>= 1) vs += __shfl_xor(vs, off);
  const float rinv = 1.0f / sqrtf(vs * (1.0f / HDM) + 1e-5f);
#pragma unroll
  for (int j = 0; j < 4; j++) {
    const int col = j * 64 + lane;
    const float val = g[col] * (v[j] - mu) * rinv + b[col];
    x[(size_t)row * HDM + col] = val;
    xb[(size_t)row * HDM + col] = f2bf(val);
  }
}

// ================= fused edge predictor: gather-cat + MLP + sigmoid =================
// 1 block per candidate, 256 threads.
__global__ __launch_bounds__(256) void ep_fused(const float* __restrict__ refined,
                                                const int* __restrict__ cand,
                                                const float* __restrict__ e1w,
                                                const float* __restrict__ e1b,
                                                const float* __restrict__ e2w,
                                                const float* __restrict__ e2b,
                                                float* __restrict__ out) {
  const int c = blockIdx.x;
  const int t = threadIdx.x;
  __shared__ float hrow[512];
  __shared__ float eph_s[256];
  const int n0 = cand[2 * c], n1 = cand[2 * c + 1];
  hrow[t] = refined[(size_t)n0 * HDM + t];
  hrow[256 + t] = refined[(size_t)n1 * HDM + t];
  __syncthreads();
  const float4* wrow = (const float4*)(e1w + (size_t)t * 512);
  float s = 0.f;
#pragma unroll 8
  for (int k = 0; k < 128; ++k) {
    const float4 w4 = wrow[k];
    const float4 h4 = *(const float4*)(hrow + k * 4);
    s += w4.x * h4.x + w4.y * h4.y + w4.z * h4.z + w4.w * h4.w;
  }
  eph_s[t] = fmaxf(s + e1b[t], 0.0f);
  __syncthreads();
  if (t < 64) {
    float p = 0.f;
#pragma unroll
    for (int j = 0; j < 4; ++j) p += eph_s[j * 64 + t] * e2w[j * 64 + t];
#pragma unroll
    for (int off = 32; off > 0; off >>= 1) p += __shfl_xor(p, off);
    if (t == 0) out[c] = 1.0f / (1.0f + __expf(-(p + e2b[0])));
  }
}

extern "C" void kernel_launch(void* const* d_in, const int* in_sizes, int n_in,
                              void* d_out, int out_size, void* d_ws, size_t ws_size,
                              hipStream_t stream) {
  (void)in_sizes; (void)n_in; (void)out_size; (void)ws_size;
  const float* nf    = (const float*)d_in[0];
  const int*   edges = (const int*)d_in[1];
  const int*   cand  = (const int*)d_in[2];
  const float* w_ih  = (const float*)d_in[3];
  const float* w_hh  = (const float*)d_in[4];
  const float* b_ih  = (const float*)d_in[5];
  const float* b_hh  = (const float*)d_in[6];
  const float* ain_w = (const float*)d_in[7];
  const float* ain_b = (const float*)d_in[8];
  const float* aout_w = (const float*)d_in[9];
  const float* aout_b = (const float*)d_in[10];
  const float* ln1g = (const float*)d_in[11];
  const float* ln1b = (const float*)d_in[12];
  const float* f1w  = (const float*)d_in[13];
  const float* f1b  = (const float*)d_in[14];
  const float* f2w  = (const float*)d_in[15];
  const float* f2b  = (const float*)d_in[16];
  const float* ln2g = (const float*)d_in[17];
  const float* ln2b = (const float*)d_in[18];
  const float* s1w  = (const float*)d_in[19];
  const float* s1b  = (const float*)d_in[20];
  const float* s2w  = (const float*)d_in[21];
  const float* s2b  = (const float*)d_in[22];
  const float* e1w  = (const float*)d_in[23];
  const float* e1b  = (const float*)d_in[24];
  const float* e2w  = (const float*)d_in[25];
  const float* e2b  = (const float*)d_in[26];
  float* out = (float*)d_out;

  char* wp = (char*)d_ws;
  float* x        = (float*)wp; wp += (size_t)NN * HDM * 4;            // 4 MB
  unsigned short* xb = (unsigned short*)wp; wp += (size_t)NN * HDM * 2; // 2 MB
  unsigned short* wseg = (unsigned short*)wp; wp += (size_t)CVT_TOT * 2; // 5.05 MB
  int* cnt        = (int*)wp;  wp += (size_t)NN * 4;
  int* lists      = (int*)wp;  wp += (size_t)NN * MAXD * 4;            // 1 MB
  int* srcs       = (int*)wp;  wp += (size_t)NN * MAXD * 4;            // 1 MB
  int* meta       = (int*)wp;  wp += 256 * 4;
  float* bias_gx  = (float*)wp; wp += 1024 * 4;
  int* perm       = (int*)wp;  wp += (size_t)NN * 4;
  unsigned short* gx = (unsigned short*)wp; wp += (size_t)NN * 768 * 2; // 6 MB
  char* uni       = wp;        // transformer buffers
  unsigned short* qkvb   = (unsigned short*)uni;                      // 6 MB
  unsigned short* vtb    = (unsigned short*)(uni + 6291456);          // 2 MB
  float* abuf    = (float*)(uni + 8388608);                           // 4 MB
  unsigned short* abuf_b = (unsigned short*)(uni + 12582912);         // 2 MB
  float* fbuf    = (float*)(uni + 14680064);                          // 16 MB (also attn Op)
  float* Op      = fbuf;
  unsigned short* fbuf_b = (unsigned short*)(uni + 31457280);         // 8 MB (also attn lp)
  float* lp      = (float*)(uni + 31457280);                          // 256 KB
  float* refined = (float*)(uni + 39845888);                          // 4 MB

  unsigned short* nf_b  = wseg;
  unsigned short* wihb  = wseg + 524288;
  unsigned short* ainb  = wseg + 622592;
  unsigned short* aoutb = wseg + 1015808;
  unsigned short* f1b_  = wseg + 1146880;
  unsigned short* f2b_  = wseg + 1671168;
  unsigned short* s1b_  = wseg + 2195456;
  unsigned short* s2b_  = wseg + 2260992;
  unsigned short* whhb  = wseg + 2326528;

  int* hist   = meta;
  int* cursor = meta + 128;

  hipMemsetAsync(cnt, 0, (size_t)NN * 4, stream);
  hipMemsetAsync(meta, 0, 256 * 4, stream);

  cvt_weights<<<2464, 256, 0, stream>>>(nf, w_ih, ain_w, aout_w, f1w, f2w, s1w, s2w, w_hh, wseg);
  build_pos<<<NE / 256, 256, 0, stream>>>(edges, cnt, lists);
  sort_srcs<<<NN / 256, 256, 0, stream>>>(edges, cnt, lists, srcs, hist);
  scan_prep<<<4, 256, 0, stream>>>(hist, cursor, b_ih, b_hh, bias_gx);
  perm_scatter<<<NN / 256, 256, 0, stream>>>(cnt, cursor, perm);

  // gx[n] = bf16( nf[n] @ w_ih^T + b_ih (+ b_hh R/Z) )   [NN,768], K=128
  gemm_bf16<0, 0, 2, 0><<<dim3(12, NN / 64), 256, 0, stream>>>(
      nf_b, nullptr, wihb, bias_gx, nullptr, gx, nullptr, NN, 768, IND);
  gru_reg<<<NN / GNPB, 512, 0, stream>>>(perm, cnt, srcs, gx, whhb, b_hh, x, xb);

  for (int l = 0; l < NL; l++) {
    gemm_bf16<0, 0, 2, 1><<<dim3(12, 64), 256, 0, stream>>>(
        xb, nullptr, ainb + (size_t)l * 196608, ain_b + l * 768, nullptr, qkvb, vtb, NN, 768, HDM);
    flash_part<<<dim3(64, 4, NS), 256, 0, stream>>>(qkvb, vtb, Op, lp);
    attn_combine<<<NN / 4, 256, 0, stream>>>(Op, lp, abuf_b);
    gemm_bf16<0, 0, 0, 0><<<dim3(4, 64), 256, 0, stream>>>(
        abuf_b, nullptr, aoutb + (size_t)l * 65536, aout_b + l * 256, fbuf, nullptr, nullptr, NN, 256, HDM);
    ln_residual<<<NN / 4, 256, 0, stream>>>(x, fbuf, ln1g + l * 256, ln1b + l * 256, xb);
    gemm_bf16<1, 0, 2, 0><<<dim3(16, 64), 256, 0, stream>>>(
        xb, nullptr, f1b_ + (size_t)l * 262144, f1b + l * 1024, nullptr, fbuf_b, nullptr, NN, 1024, HDM);
    gemm_bf16<0, 0, 0, 0><<<dim3(4, 64), 256, 0, stream>>>(
        fbuf_b, nullptr, f2b_ + (size_t)l * 262144, f2b + l * 256, abuf, nullptr, nullptr, NN, 256, 1024);
    ln_residual<<<NN / 4, 256, 0, stream>>>(x, abuf, ln2g + l * 256, ln2b + l * 256, xb);
  }

  gemm_bf16<1, 0, 2, 0><<<dim3(4, 64), 256, 0, stream>>>(
      xb, nullptr, s1b_, s1b, nullptr, abuf_b, nullptr, NN, 256, HDM);
  gemm_bf16<0, 0, 0, 0><<<dim3(4, 64), 256, 0, stream>>>(
      abuf_b, nullptr, s2b_, s2b, refined, nullptr, nullptr, NN, 256, HDM);
  ep_fused<<<NCAND, 256, 0, stream>>>(refined, cand, e1w, e1b, e2w, e2b, out);
}